// Round 4
// baseline (1469.231 us; speedup 1.0000x reference)
//
#include <hip/hip_runtime.h>
#include <hip/hip_bf16.h>
#include <math.h>

#define B_    8
#define LP_   1024
#define CIN_  64
#define DM_   1024
#define DI_   2048
#define NS_   16
#define PH_   64
#define NH_   32
#define NL_   4
#define GG_   8
#define KH_   2048
#define DIN_  4160
#define CONVD_ 2080
#define L_    128
#define R_    1024
#define OUTL_ 512
#define COUT_ 64

typedef __bf16 bf16x8 __attribute__((ext_vector_type(8)));
typedef float f32x4 __attribute__((ext_vector_type(4)));
typedef unsigned short ushort;

__device__ __forceinline__ float silu_f(float x) { return x / (1.0f + expf(-x)); }

__device__ __forceinline__ ushort f2bu(float x) {
    __hip_bfloat16 h = __float2bfloat16(x);
    union { __hip_bfloat16 h; ushort u; } c; c.h = h; return c.u;
}

__device__ __forceinline__ void gload_lds16(const void* g, void* l) {
    __builtin_amdgcn_global_load_lds((const __attribute__((address_space(1))) unsigned int*)g,
                                     (__attribute__((address_space(3))) unsigned int*)l, 16, 0, 0);
}

// pair-merge reduce: 8 accumulators x 64 lanes -> lane (l&7) holds full sum of acc[l&7]
__device__ __forceinline__ float merge2(float a, float b, int mask, int lane) {
    float x = (lane & mask) ? b : a;
    float y = (lane & mask) ? a : b;
    return x + __shfl_xor(y, mask);
}
__device__ __forceinline__ float reduce8(float* a, int lane) {
    float c0 = merge2(a[0], a[1], 1, lane);
    float c1 = merge2(a[2], a[3], 1, lane);
    float c2 = merge2(a[4], a[5], 1, lane);
    float c3 = merge2(a[6], a[7], 1, lane);
    float d0 = merge2(c0, c1, 2, lane);
    float d1 = merge2(c2, c3, 2, lane);
    float e  = merge2(d0, d1, 4, lane);
    e += __shfl_xor(e, 8);
    e += __shfl_xor(e, 16);
    e += __shfl_xor(e, 32);
    return e;
}

// ---------------- im2col / weight transposes ----------------
__global__ __launch_bounds__(256) void k_pre_im2col(const float* __restrict__ xp, __hip_bfloat16* __restrict__ out) {
    size_t idx = (size_t)blockIdx.x * 256 + threadIdx.x;
    if (idx >= (size_t)8192 * 320) return;
    int kk = (int)(idx % 320); size_t r = idx / 320;
    int l = (int)(r & 1023); int b = (int)(r >> 10);
    int kp = kk >> 6, c = kk & 63;
    int lp = l + kp - 2;
    float v = 0.f;
    if (lp >= 0 && lp < LP_) v = xp[((size_t)b * LP_ + lp) * CIN_ + c];
    out[idx] = __float2bfloat16(v);
}

__global__ __launch_bounds__(256) void k_wpre_T(const float* __restrict__ w, __hip_bfloat16* __restrict__ out) {
    int idx = blockIdx.x * 256 + threadIdx.x;
    if (idx >= DM_ * 320) return;
    int d = idx / 320, kk = idx % 320;
    int kp = kk >> 6, c = kk & 63;
    out[idx] = __float2bfloat16(w[(d * CIN_ + c) * 5 + kp]);
}

__global__ __launch_bounds__(256) void k_wpatch_T(const float* __restrict__ w, __hip_bfloat16* __restrict__ out) {
    size_t idx = (size_t)blockIdx.x * 256 + threadIdx.x;
    if (idx >= (size_t)DM_ * 8192) return;
    int d = (int)(idx >> 13); int kk = (int)(idx & 8191);
    int kp = kk >> 10, din = kk & 1023;
    out[idx] = __float2bfloat16(w[((size_t)d << 13) + din * 8 + kp]);
}

// ---------------- bf16 MFMA GEMM ----------------
// C[M,Nstore] = A[M,K] @ B[N,K]^T (+bias)(+resid)(silu). 4 waves, 16x16x32 MFMA, BK=32.
// BF32B: B supplied as fp32 (Bf0/Bf1 per blockIdx.z), converted during LDS staging (rows >= Nb -> 0).
// else: B = Bb (bf16, shared across z). A via global_load_lds. Cf2: extra store at row^127 (patch reverse).
template<int BM, int BN, int BF32B>
__global__ __launch_bounds__(256) void k_gemm_mfma(
    const ushort* __restrict__ A, const ushort* __restrict__ Bb,
    const float* __restrict__ Bf0, const float* __restrict__ Bf1,
    const float* __restrict__ bias, const float* __restrict__ resid,
    float* __restrict__ Cf, float* __restrict__ Cf2, __hip_bfloat16* __restrict__ Cb,
    int M, int K, int ldc, int Nstore, int act, int Nb, long sA, long sC)
{
    constexpr int BK = 32;
    constexpr int WM = BM / 2, WN = BN / 2;
    constexpr int MR = WM / 16, NR = WN / 16;
    constexpr int ACH = BM * 4;         // 16B chunks in A tile
    __shared__ ushort sAs[BM * BK];
    __shared__ ushort sBs[BN * BK];
    int tid = threadIdx.x;
    int lane = tid & 63, w = tid >> 6;
    int wr = w >> 1, wc = w & 1;
    int z = blockIdx.z;
    int m0 = blockIdx.y * BM, n0 = blockIdx.x * BN;
    const ushort* Az = A + (size_t)z * sA;
    const float* Bf = z ? Bf1 : Bf0;

    f32x4 acc[MR][NR] = {};
    for (int k0 = 0; k0 < K; k0 += BK) {
        __syncthreads();
        #pragma unroll
        for (int c = tid; c < ACH; c += 256) {
            int row = c >> 2, col = (c & 3) * 8;
            gload_lds16(Az + (size_t)(m0 + row) * K + k0 + col, (char*)sAs + c * 16);
        }
        if (BF32B) {
            #pragma unroll
            for (int c = tid; c < BN * 8; c += 256) {
                int row = c >> 3, kc = (c & 7) * 4;
                int rg = n0 + row;
                float4 v = {0.f, 0.f, 0.f, 0.f};
                if (rg < Nb) v = *(const float4*)(Bf + (size_t)rg * K + k0 + kc);
                ushort4 p;
                p.x = f2bu(v.x); p.y = f2bu(v.y); p.z = f2bu(v.z); p.w = f2bu(v.w);
                *(ushort4*)&sBs[row * BK + kc] = p;
            }
        } else {
            #pragma unroll
            for (int c = tid; c < BN * 4; c += 256) {
                int row = c >> 2, col = (c & 3) * 8;
                gload_lds16(Bb + (size_t)(n0 + row) * K + k0 + col, (char*)sBs + c * 16);
            }
        }
        __syncthreads();
        bf16x8 af[MR], bfr[NR];
        #pragma unroll
        for (int m = 0; m < MR; ++m)
            af[m] = *(const bf16x8*)&sAs[(wr * WM + m * 16 + (lane & 15)) * BK + (lane >> 4) * 8];
        #pragma unroll
        for (int n = 0; n < NR; ++n)
            bfr[n] = *(const bf16x8*)&sBs[(wc * WN + n * 16 + (lane & 15)) * BK + (lane >> 4) * 8];
        #pragma unroll
        for (int m = 0; m < MR; ++m)
            #pragma unroll
            for (int n = 0; n < NR; ++n)
                acc[m][n] = __builtin_amdgcn_mfma_f32_16x16x32_bf16(af[m], bfr[n], acc[m][n], 0, 0, 0);
    }
    const float* residz = resid ? resid + (size_t)z * sC : nullptr;
    float* Cfz = Cf ? Cf + (size_t)z * sC : nullptr;
    #pragma unroll
    for (int m = 0; m < MR; ++m) {
        int row = m0 + wr * WM + m * 16 + (lane >> 4) * 4;
        #pragma unroll
        for (int n = 0; n < NR; ++n) {
            int col = n0 + wc * WN + n * 16 + (lane & 15);
            if (col < Nstore) {
                float bv = bias ? bias[col] : 0.f;
                #pragma unroll
                for (int j = 0; j < 4; ++j) {
                    float v = acc[m][n][j] + bv;
                    if (residz) v += residz[(size_t)(row + j) * ldc + col];
                    if (act) v = silu_f(v);
                    if (Cb) Cb[(size_t)(row + j) * ldc + col] = __float2bfloat16(v);
                    else {
                        Cfz[(size_t)(row + j) * ldc + col] = v;
                        if (Cf2) Cf2[(size_t)((row + j) ^ 127) * ldc + col] = v;
                    }
                }
            }
        }
    }
}

// ---------------- rmsnorm: 2048 rows (fwd rows 0..1023, bwd 1024..2047) ----------------
__global__ __launch_bounds__(256) void k_rmsnorm(const float* __restrict__ h, const float* __restrict__ w0,
                                                 const float* __restrict__ w1, __hip_bfloat16* __restrict__ u) {
    int r = blockIdx.x; int t = threadIdx.x;
    const float* w = (r >> 10) ? w1 : w0;
    const float* row = h + (size_t)r * DM_;
    float v[4]; float ss = 0.f;
    #pragma unroll
    for (int i = 0; i < 4; ++i) { v[i] = row[t + 256 * i]; ss += v[i] * v[i]; }
    #pragma unroll
    for (int o = 32; o; o >>= 1) ss += __shfl_xor(ss, o);
    __shared__ float sred[4];
    if ((t & 63) == 0) sred[t >> 6] = ss;
    __syncthreads();
    float tot = sred[0] + sred[1] + sred[2] + sred[3];
    float scale = rsqrtf(tot * (1.0f / DM_) + 1e-5f);
    #pragma unroll
    for (int i = 0; i < 4; ++i)
        u[(size_t)r * DM_ + t + 256 * i] = __float2bfloat16(v[i] * scale * w[t + 256 * i]);
}

// ---------------- depthwise conv, float4 over channels, both dirs ----------------
__global__ __launch_bounds__(256) void k_dwconv(const float* __restrict__ zx,
                                                const float* __restrict__ cw0, const float* __restrict__ cw1,
                                                const float* __restrict__ cb0, const float* __restrict__ cb1,
                                                float* __restrict__ xbc) {
    int idx = blockIdx.x * 256 + threadIdx.x;       // over 2048 * 520
    if (idx >= 2048 * 520) return;
    int c4 = idx % 520; int r = idx / 520;
    int dir = r >> 10, rl = r & 1023, l = rl & 127;
    const float* cw = (dir ? cw1 : cw0) + c4 * 16;
    const float* cb = (dir ? cb1 : cb0) + c4 * 4;
    const float* zxd = zx + (size_t)dir * 1024 * DIN_;
    float4 acc = *(const float4*)cb;
    #pragma unroll
    for (int k = 0; k < 4; ++k) {
        int lp = l - 3 + k;
        if (lp >= 0) {
            float4 xv = *(const float4*)(zxd + (size_t)(rl - l + lp) * DIN_ + DI_ + c4 * 4);
            acc.x += xv.x * cw[0 * 4 + k];
            acc.y += xv.y * cw[1 * 4 + k];
            acc.z += xv.z * cw[2 * 4 + k];
            acc.w += xv.w * cw[3 * 4 + k];
        }
    }
    float4 o;
    o.x = silu_f(acc.x); o.y = silu_f(acc.y); o.z = silu_f(acc.z); o.w = silu_f(acc.w);
    *(float4*)(xbc + (size_t)dir * 1024 * CONVD_ + (size_t)rl * CONVD_ + c4 * 4) = o;
}

// ---------------- SSM scan: one block per (dir,b,h) ----------------
__global__ __launch_bounds__(256) void k_scan(const float* __restrict__ xbc, const float* __restrict__ zx,
                                              const float* __restrict__ dtb0, const float* __restrict__ dtb1,
                                              const float* __restrict__ al0, const float* __restrict__ al1,
                                              const float* __restrict__ D0, const float* __restrict__ D1,
                                              __hip_bfloat16* __restrict__ ys) {
    __shared__ float xs[L_ * PH_];
    __shared__ float Bsh[L_ * NS_];
    __shared__ float Csh[L_ * NS_];
    __shared__ float dts[L_];
    __shared__ float dAs[L_];
    int bx = blockIdx.x;
    int dir = bx >> 8, b = (bx >> 5) & 7, h = bx & 31;
    const float* xbcd = xbc + (size_t)dir * 1024 * CONVD_;
    const float* zxd  = zx  + (size_t)dir * 1024 * DIN_;
    const float* dt_bias = dir ? dtb1 : dtb0;
    const float* A_log   = dir ? al1 : al0;
    const float* Dh      = dir ? D1 : D0;
    __hip_bfloat16* ysd  = ys + (size_t)dir * 1024 * DI_;
    int t = threadIdx.x;
    for (int i = t; i < L_ * PH_; i += 256) {
        int l = i >> 6, p = i & 63;
        xs[i] = xbcd[((size_t)(b * L_ + l)) * CONVD_ + h * PH_ + p];
    }
    for (int i = t; i < L_ * NS_; i += 256) {
        int l = i >> 4, n = i & 15;
        Bsh[i] = xbcd[((size_t)(b * L_ + l)) * CONVD_ + DI_ + n];
        Csh[i] = xbcd[((size_t)(b * L_ + l)) * CONVD_ + DI_ + NS_ + n];
    }
    if (t < L_) {
        float v = zxd[((size_t)(b * L_ + t)) * DIN_ + 4128 + h] + dt_bias[h];
        float sp = v > 20.f ? v : log1pf(expf(v));
        dts[t] = sp;
        dAs[t] = expf(-expf(A_log[h]) * sp);
    }
    __syncthreads();
    int p = t >> 2, n0 = (t & 3) * 4;
    float Dv = Dh[h];
    float s0 = 0.f, s1 = 0.f, s2 = 0.f, s3 = 0.f;
    for (int l = 0; l < L_; ++l) {
        float x = xs[l * 64 + p];
        float dAv = dAs[l];
        float xdt = x * dts[l];
        s0 = s0 * dAv + xdt * Bsh[l * 16 + n0 + 0];
        s1 = s1 * dAv + xdt * Bsh[l * 16 + n0 + 1];
        s2 = s2 * dAv + xdt * Bsh[l * 16 + n0 + 2];
        s3 = s3 * dAv + xdt * Bsh[l * 16 + n0 + 3];
        float cp = s0 * Csh[l * 16 + n0 + 0] + s1 * Csh[l * 16 + n0 + 1]
                 + s2 * Csh[l * 16 + n0 + 2] + s3 * Csh[l * 16 + n0 + 3];
        cp += __shfl_xor(cp, 1);
        cp += __shfl_xor(cp, 2);
        if ((t & 3) == 0) xs[l * 64 + p] = cp + x * Dv;
    }
    __syncthreads();
    for (int i = t; i < L_ * PH_; i += 256) {
        int l = i >> 6, pp = i & 63;
        float z = zxd[((size_t)(b * L_ + l)) * DIN_ + h * PH_ + pp];
        ysd[((size_t)(b * L_ + l)) * DI_ + h * PH_ + pp] = __float2bfloat16(xs[i] * silu_f(z));
    }
}

// ---------------- tail ----------------
__global__ __launch_bounds__(256) void k_meanctx(const float* __restrict__ hf, const float* __restrict__ hb,
                                                 float* __restrict__ fused) {
    int b = blockIdx.x, t = threadIdx.x;
    int d = t * 4;
    float4 sf = {0,0,0,0}, sb = {0,0,0,0};
    for (int l = 0; l < L_; ++l) {
        float4 a = *(const float4*)(hf + ((size_t)b * L_ + l) * DM_ + d);
        float4 c = *(const float4*)(hb + ((size_t)b * L_ + l) * DM_ + d);
        sf.x += a.x; sf.y += a.y; sf.z += a.z; sf.w += a.w;
        sb.x += c.x; sb.y += c.y; sb.z += c.z; sb.w += c.w;
    }
    const float s = 1.f / L_;
    float4 o1 = {sf.x*s, sf.y*s, sf.z*s, sf.w*s};
    float4 o2 = {sb.x*s, sb.y*s, sb.z*s, sb.w*s};
    *(float4*)(fused + b * 3072 + d) = o1;
    *(float4*)(fused + b * 3072 + DM_ + d) = o2;
}

__global__ __launch_bounds__(256) void k_aux(const float* __restrict__ y_aux, const float* __restrict__ aux_w,
                                             const float* __restrict__ aux_b, float* __restrict__ fused) {
    int j = blockIdx.x * 256 + threadIdx.x;
    if (j >= DM_) return;
    for (int b = 0; b < B_; ++b) {
        float acc = aux_b[j];
        for (int a = 0; a < 32; ++a) acc += y_aux[b * 32 + a] * aux_w[j * 32 + a];
        fused[b * 3072 + 2 * DM_ + j] = silu_f(acc);
    }
}

__global__ __launch_bounds__(256) void k_basis(const float* __restrict__ x, const float* __restrict__ log_bw,
                                               float* __restrict__ basis, int Din) {
    int idx = blockIdx.x * 256 + threadIdx.x;
    if (idx >= 8 * Din) return;
    int d = idx % Din;
    float xv = x[idx];
    float bw = expf(log_bw[d]) + 1e-6f;
    float inv = 1.0f / (2.0f * bw * bw);
    #pragma unroll
    for (int g = 0; g < GG_; ++g) {
        float gg = -2.0f + g * (4.0f / 7.0f);
        float df = xv - gg;
        basis[(size_t)idx * GG_ + g] = expf(-df * df * inv);
    }
}

// ---------------- LDS-staged batched dot ----------------
// W[Dout][K] vs X[8][K] (ldx row stride). Block: stage X[8][1024] slice; 4 waves x 8 rows.
// MODE 0: partial[row*nch + chOff+ch][8]; MODE 1: final+bias+silu, out[b*Dout+row];
// MODE 2: heads final+bias, out[(b*512 + l)*64 + c], row = c*512+l.
template<int MODE>
__global__ __launch_bounds__(256) void k_dotl(const float* __restrict__ W, const float* __restrict__ X,
                                              const float* __restrict__ bias, float* __restrict__ out,
                                              int K, int Dout, int ldx, int nch, int chOff) {
    __shared__ float sX[8][1024];
    int ch = blockIdx.y;
    int k0 = ch * 1024;
    int tid = threadIdx.x;
    for (int i = tid; i < 2048; i += 256) {
        int b = i >> 8, kk = (i & 255) * 4;
        *(float4*)&sX[b][kk] = *(const float4*)(X + (size_t)b * ldx + k0 + kk);
    }
    __syncthreads();
    int wv = tid >> 6, lane = tid & 63;
    int rowBase = blockIdx.x * 32 + wv * 8;
    for (int j = 0; j < 8; ++j) {
        int row = rowBase + j;
        const float* wr = W + (size_t)row * K + k0;
        float acc[8] = {};
        #pragma unroll
        for (int it = 0; it < 4; ++it) {
            int k = it * 256 + lane * 4;
            float4 wvv = *(const float4*)(wr + k);
            #pragma unroll
            for (int b = 0; b < 8; ++b) {
                float4 xv = *(const float4*)&sX[b][k];
                acc[b] += wvv.x * xv.x + wvv.y * xv.y + wvv.z * xv.z + wvv.w * xv.w;
            }
        }
        float e = reduce8(acc, lane);
        if (lane < 8) {
            if (MODE == 0) {
                out[((size_t)row * nch + chOff + ch) * 8 + lane] = e;
            } else if (MODE == 1) {
                out[(size_t)lane * Dout + row] = silu_f(e + bias[row]);
            } else {
                int c = row >> 9, l = row & 511;
                out[((size_t)lane * OUTL_ + l) * COUT_ + c] = e + bias[row];
            }
        }
    }
}

template<int NCH>
__global__ __launch_bounds__(256) void k_dot_fin(const float* __restrict__ partial, const float* __restrict__ base_b,
                                                 float* __restrict__ out, int Dout) {
    int row = blockIdx.x * 256 + threadIdx.x;
    if (row >= Dout) return;
    float bb = base_b[row];
    #pragma unroll
    for (int b = 0; b < 8; ++b) {
        float s = bb;
        #pragma unroll
        for (int c = 0; c < NCH; ++c) s += partial[((size_t)row * NCH + c) * 8 + b];
        out[(size_t)b * Dout + row] = silu_f(s);
    }
}

// ---------------- launch ----------------
extern "C" void kernel_launch(void* const* d_in, const int* in_sizes, int n_in,
                              void* d_out, int out_size, void* d_ws, size_t ws_size,
                              hipStream_t stream) {
    const float* x_prefix = (const float*)d_in[0];
    const float* y_aux    = (const float*)d_in[1];
    const float* pre_w    = (const float*)d_in[2];
    const float* pre_b    = (const float*)d_in[3];
    const float* patch_w  = (const float*)d_in[4];
    const float* patch_b  = (const float*)d_in[5];
    const float* norm_w[2] = {(const float*)d_in[6],  (const float*)d_in[14]};
    const float* in_w[2]   = {(const float*)d_in[7],  (const float*)d_in[15]};
    const float* conv_w[2] = {(const float*)d_in[8],  (const float*)d_in[16]};
    const float* conv_b[2] = {(const float*)d_in[9],  (const float*)d_in[17]};
    const float* A_log[2]  = {(const float*)d_in[10], (const float*)d_in[18]};
    const float* Dvec[2]   = {(const float*)d_in[11], (const float*)d_in[19]};
    const float* dt_b[2]   = {(const float*)d_in[12], (const float*)d_in[20]};
    const float* out_w[2]  = {(const float*)d_in[13], (const float*)d_in[21]};
    const float* aux_w = (const float*)d_in[22];
    const float* aux_b = (const float*)d_in[23];
    const float* k1_lbw = (const float*)d_in[24];
    const float* k1_bw  = (const float*)d_in[25];
    const float* k1_bb  = (const float*)d_in[26];
    const float* k1_sw  = (const float*)d_in[27];
    const float* k2_lbw = (const float*)d_in[28];
    const float* k2_bw  = (const float*)d_in[29];
    const float* k2_bb  = (const float*)d_in[30];
    const float* k2_sw  = (const float*)d_in[31];
    const float* sh_w = (const float*)d_in[32];
    const float* sh_b = (const float*)d_in[33];
    const float* hw   = (const float*)d_in[34];
    const float* hbias= (const float*)d_in[35];
    float* ws = (float*)d_ws;
    float* out = (float*)d_out;

    // workspace (float units)
    // stage region: ApreB[0..1,310,720) wpreTB[..1,474,560) x1B[..5,668,864) wpatchTB[..9,863,168)
    const size_t o_ApreB   = 0;
    const size_t o_wpreTB  = 1310720;
    const size_t o_x1B     = 1474560;
    const size_t o_wpatchTB= 5668864;
    // mamba overlay (dir-batched, 2x):
    const size_t o_uB   = 0;              // bf16 2x1024x1024 -> 1,048,576 f
    const size_t o_zx   = 1048576;        // f32 2x1024x4160  -> 8,519,680 f
    const size_t o_xbc  = 9568256;        // f32 2x1024x2080  -> 4,259,840 f
    const size_t o_ysB  = 13828096;       // bf16 2x1024x2048 -> 2,097,152 f
    const size_t o_hf   = 15925248;       // f32 1024x1024
    const size_t o_hb   = 16973824;       // f32 1024x1024 (contiguous after hf)
    const size_t total_f = 18022400;      // 72 MB
    // tail overlay (mamba region dead):
    const size_t o_f1   = 0;              // 8x3072
    const size_t o_bas1 = 24576;          // 8x24576
    const size_t o_k1   = 221184;         // 8x2048
    const size_t o_bas2 = 237568;         // 8x16384
    const size_t o_k2   = 368640;         // 8x1024
    const size_t o_f4   = 376832;         // 8x1024
    const size_t o_part = 385024;         // 2048*27*8 = 442,368
    if (ws_size < total_f * sizeof(float)) return;

    __hip_bfloat16* ApreB   = (__hip_bfloat16*)(ws + o_ApreB);
    __hip_bfloat16* wpreTB  = (__hip_bfloat16*)(ws + o_wpreTB);
    __hip_bfloat16* x1B     = (__hip_bfloat16*)(ws + o_x1B);
    __hip_bfloat16* wpatchTB= (__hip_bfloat16*)(ws + o_wpatchTB);
    __hip_bfloat16* uB      = (__hip_bfloat16*)(ws + o_uB);
    __hip_bfloat16* ysB     = (__hip_bfloat16*)(ws + o_ysB);
    float* hf = ws + o_hf;
    float* hb = ws + o_hb;

    // Stage A: pre-conv im2col GEMM (silu fused) -> x1B bf16
    k_wpre_T<<<1280, 256, 0, stream>>>(pre_w, wpreTB);
    k_wpatch_T<<<32768, 256, 0, stream>>>(patch_w, wpatchTB);
    k_pre_im2col<<<10240, 256, 0, stream>>>(x_prefix, ApreB);
    k_gemm_mfma<128,128,0><<<dim3(8, 64, 1), 256, 0, stream>>>(
        (const ushort*)ApreB, (const ushort*)wpreTB, nullptr, nullptr,
        pre_b, nullptr, nullptr, nullptr, x1B, 8192, 320, 1024, 1024, 1, 1024, 0, 0);
    // Stage B: patch GEMM -> hf, dual store reversed -> hb
    k_gemm_mfma<64,64,0><<<dim3(16, 16, 1), 256, 0, stream>>>(
        (const ushort*)x1B, (const ushort*)wpatchTB, nullptr, nullptr,
        patch_b, nullptr, hf, hb, nullptr, 1024, 8192, 1024, 1024, 0, 1024, 0, 0);

    // Mamba stacks, both directions batched per dispatch
    for (int i = 0; i < NL_; ++i) {
        k_rmsnorm<<<2048, 256, 0, stream>>>(hf, norm_w[0] + (size_t)i * DM_, norm_w[1] + (size_t)i * DM_, uB);
        k_gemm_mfma<128,128,1><<<dim3(33, 8, 2), 256, 0, stream>>>(
            (const ushort*)uB, nullptr, in_w[0] + (size_t)i * DIN_ * DM_, in_w[1] + (size_t)i * DIN_ * DM_,
            nullptr, nullptr, ws + o_zx, nullptr, nullptr,
            1024, 1024, DIN_, DIN_, 0, DIN_, (long)1024 * 1024, (long)1024 * DIN_);
        k_dwconv<<<4160, 256, 0, stream>>>(ws + o_zx,
            conv_w[0] + (size_t)i * CONVD_ * 4, conv_w[1] + (size_t)i * CONVD_ * 4,
            conv_b[0] + (size_t)i * CONVD_, conv_b[1] + (size_t)i * CONVD_, ws + o_xbc);
        k_scan<<<512, 256, 0, stream>>>(ws + o_xbc, ws + o_zx,
            dt_b[0] + i * NH_, dt_b[1] + i * NH_, A_log[0] + i * NH_, A_log[1] + i * NH_,
            Dvec[0] + i * NH_, Dvec[1] + i * NH_, ysB);
        k_gemm_mfma<64,64,1><<<dim3(16, 16, 2), 256, 0, stream>>>(
            (const ushort*)ysB, nullptr, out_w[0] + (size_t)i * DM_ * DI_, out_w[1] + (size_t)i * DM_ * DI_,
            nullptr, hf, hf, nullptr, nullptr,
            1024, 2048, 1024, 1024, 0, 1024, (long)1024 * 2048, (long)1024 * 1024);
    }

    // Tail
    k_meanctx<<<8, 256, 0, stream>>>(hf, hb, ws + o_f1);
    k_aux<<<4, 256, 0, stream>>>(y_aux, aux_w, aux_b, ws + o_f1);
    k_basis<<<96, 256, 0, stream>>>(ws + o_f1, k1_lbw, ws + o_bas1, 3072);
    k_dotl<0><<<dim3(64, 24), 256, 0, stream>>>(k1_sw, ws + o_bas1, nullptr, ws + o_part, 24576, 2048, 24576, 27, 0);
    k_dotl<0><<<dim3(64, 3),  256, 0, stream>>>(k1_bw, ws + o_f1,   nullptr, ws + o_part, 3072,  2048, 3072,  27, 24);
    k_dot_fin<27><<<8, 256, 0, stream>>>(ws + o_part, k1_bb, ws + o_k1, 2048);
    k_basis<<<64, 256, 0, stream>>>(ws + o_k1, k2_lbw, ws + o_bas2, 2048);
    k_dotl<0><<<dim3(32, 16), 256, 0, stream>>>(k2_sw, ws + o_bas2, nullptr, ws + o_part, 16384, 1024, 16384, 18, 0);
    k_dotl<0><<<dim3(32, 2),  256, 0, stream>>>(k2_bw, ws + o_k1,   nullptr, ws + o_part, 2048,  1024, 2048,  18, 16);
    k_dot_fin<18><<<4, 256, 0, stream>>>(ws + o_part, k2_bb, ws + o_k2, 1024);
    k_dotl<1><<<dim3(32, 1), 256, 0, stream>>>(sh_w, ws + o_k2, sh_b, ws + o_f4, 1024, 1024, 1024, 1, 0);
    k_dotl<2><<<dim3(1024, 1), 256, 0, stream>>>(hw, ws + o_f4, hbias, out, 1024, 32768, 1024, 1, 0);
}

// Round 5
// 966.928 us; speedup vs baseline: 1.5195x; 1.5195x over previous
//
#include <hip/hip_runtime.h>
#include <hip/hip_bf16.h>
#include <math.h>

#define B_    8
#define LP_   1024
#define CIN_  64
#define DM_   1024
#define DI_   2048
#define NS_   16
#define PH_   64
#define NH_   32
#define NL_   4
#define GG_   8
#define KH_   2048
#define DIN_  4160
#define NPAD_ 4224
#define CONVD_ 2080
#define L_    128
#define R_    1024
#define OUTL_ 512
#define COUT_ 64

typedef __bf16 bf16x8 __attribute__((ext_vector_type(8)));
typedef float f32x4 __attribute__((ext_vector_type(4)));
typedef unsigned short ushort;

__device__ __forceinline__ float silu_f(float x) { return x / (1.0f + expf(-x)); }

__device__ __forceinline__ ushort f2bu(float x) {
    union { __hip_bfloat16 h; ushort u; } c; c.h = __float2bfloat16(x); return c.u;
}
__device__ __forceinline__ float bu2f(ushort u) {
    union { ushort u; __hip_bfloat16 h; } c; c.u = u; return __bfloat162float(c.h);
}

__device__ __forceinline__ void gload_lds16(const void* g, void* l) {
    __builtin_amdgcn_global_load_lds((const __attribute__((address_space(1))) unsigned int*)g,
                                     (__attribute__((address_space(3))) unsigned int*)l, 16, 0, 0);
}

// pair-merge reduce: 8 accumulators x 64 lanes -> lane (l&7) holds full sum of acc[l&7]
__device__ __forceinline__ float merge2(float a, float b, int mask, int lane) {
    float x = (lane & mask) ? b : a;
    float y = (lane & mask) ? a : b;
    return x + __shfl_xor(y, mask);
}
__device__ __forceinline__ float reduce8(float* a, int lane) {
    float c0 = merge2(a[0], a[1], 1, lane);
    float c1 = merge2(a[2], a[3], 1, lane);
    float c2 = merge2(a[4], a[5], 1, lane);
    float c3 = merge2(a[6], a[7], 1, lane);
    float d0 = merge2(c0, c1, 2, lane);
    float d1 = merge2(c2, c3, 2, lane);
    float e  = merge2(d0, d1, 4, lane);
    e += __shfl_xor(e, 8);
    e += __shfl_xor(e, 16);
    e += __shfl_xor(e, 32);
    return e;
}

// ---------------- im2col / weight transposes ----------------
__global__ __launch_bounds__(256) void k_pre_im2col(const float* __restrict__ xp, __hip_bfloat16* __restrict__ out) {
    size_t idx = (size_t)blockIdx.x * 256 + threadIdx.x;
    if (idx >= (size_t)8192 * 320) return;
    int kk = (int)(idx % 320); size_t r = idx / 320;
    int l = (int)(r & 1023); int b = (int)(r >> 10);
    int kp = kk >> 6, c = kk & 63;
    int lp = l + kp - 2;
    float v = 0.f;
    if (lp >= 0 && lp < LP_) v = xp[((size_t)b * LP_ + lp) * CIN_ + c];
    out[idx] = __float2bfloat16(v);
}

__global__ __launch_bounds__(256) void k_wpre_T(const float* __restrict__ w, __hip_bfloat16* __restrict__ out) {
    int idx = blockIdx.x * 256 + threadIdx.x;
    if (idx >= DM_ * 320) return;
    int d = idx / 320, kk = idx % 320;
    int kp = kk >> 6, c = kk & 63;
    out[idx] = __float2bfloat16(w[(d * CIN_ + c) * 5 + kp]);
}

__global__ __launch_bounds__(256) void k_wpatch_T(const float* __restrict__ w, __hip_bfloat16* __restrict__ out) {
    size_t idx = (size_t)blockIdx.x * 256 + threadIdx.x;
    if (idx >= (size_t)DM_ * 8192) return;
    int d = (int)(idx >> 13); int kk = (int)(idx & 8191);
    int kp = kk >> 10, din = kk & 1023;
    out[idx] = __float2bfloat16(w[((size_t)d << 13) + din * 8 + kp]);
}

// per-layer both dirs: in_w [4160][1024] -> wBB[dir][4224][1024] bf16 ; out_w [1024][2048] -> wOB[dir]
#define CVT_IN_T4  1081344   // 4224*1024/4
#define CVT_OUT_T4 524288    // 1024*2048/4
__global__ __launch_bounds__(256) void k_cvt_layer(const float* __restrict__ in0, const float* __restrict__ in1,
                                                   const float* __restrict__ o0, const float* __restrict__ o1,
                                                   __hip_bfloat16* __restrict__ wBB, __hip_bfloat16* __restrict__ wOB) {
    int i = blockIdx.x * 256 + threadIdx.x;
    int dir = 0;
    if (i >= CVT_IN_T4 + CVT_OUT_T4) { dir = 1; i -= CVT_IN_T4 + CVT_OUT_T4; }
    const float* inw = dir ? in1 : in0;
    const float* outw = dir ? o1 : o0;
    if (i < CVT_IN_T4) {
        int idx = i * 4; int row = idx >> 10;
        __hip_bfloat16* dst = wBB + (size_t)dir * NPAD_ * 1024 + idx;
        if (row < DIN_) {
            float4 v = *(const float4*)(inw + idx);
            dst[0] = __float2bfloat16(v.x); dst[1] = __float2bfloat16(v.y);
            dst[2] = __float2bfloat16(v.z); dst[3] = __float2bfloat16(v.w);
        } else {
            dst[0] = __float2bfloat16(0.f); dst[1] = __float2bfloat16(0.f);
            dst[2] = __float2bfloat16(0.f); dst[3] = __float2bfloat16(0.f);
        }
    } else {
        int idx = (i - CVT_IN_T4) * 4;
        __hip_bfloat16* dst = wOB + (size_t)dir * 1024 * 2048 + idx;
        float4 v = *(const float4*)(outw + idx);
        dst[0] = __float2bfloat16(v.x); dst[1] = __float2bfloat16(v.y);
        dst[2] = __float2bfloat16(v.z); dst[3] = __float2bfloat16(v.w);
    }
}

// ---------------- bf16 MFMA GEMM, 2-phase double-buffered (T3 minimum recipe) ----------------
// C = A[.,Kc]@B[.,Kc]^T ; ldk = row stride of A,B. act: 0 none, 1 silu, 2 raw split-K partial
// (act==2: kbase=z*Kc, bias/resid ignored, store Cf+z*sC). Otherwise z strides sA/sB/sC apply.
template<int BM, int BN>
__global__ __launch_bounds__(256) void k_gemm_mfma(
    const ushort* __restrict__ A, const ushort* __restrict__ B,
    const float* __restrict__ bias, const float* __restrict__ resid,
    float* __restrict__ Cf, __hip_bfloat16* __restrict__ Cb,
    int Kc, int ldk, int ldc, int Nstore, int act, long sA, long sB, long sC)
{
    constexpr int BK = 32;
    constexpr int WM = BM / 2, WN = BN / 2;
    constexpr int MR = WM / 16, NR = WN / 16;
    constexpr int ACH = BM * 4, BCH = BN * 4;   // 16B chunks per tile
    __shared__ ushort sAs[2][BM * BK];
    __shared__ ushort sBs[2][BN * BK];
    int tid = threadIdx.x;
    int lane = tid & 63, w = tid >> 6;
    int wr = w >> 1, wc = w & 1;
    int z = blockIdx.z;
    int m0 = blockIdx.y * BM, n0 = blockIdx.x * BN;
    int kbase = (act == 2) ? z * Kc : 0;
    const ushort* Az = A + (size_t)(act == 2 ? 0 : z) * sA + kbase;
    const ushort* Bz = B + (size_t)(act == 2 ? 0 : z) * sB + kbase;

    auto STAGE = [&](int buf, int k0) {
        #pragma unroll
        for (int c = tid; c < ACH; c += 256) {
            int row = c >> 2, col = (c & 3) * 8;
            gload_lds16(Az + (size_t)(m0 + row) * ldk + k0 + col, (char*)&sAs[buf][0] + c * 16);
        }
        #pragma unroll
        for (int c = tid; c < BCH; c += 256) {
            int row = c >> 2, col = (c & 3) * 8;
            gload_lds16(Bz + (size_t)(n0 + row) * ldk + k0 + col, (char*)&sBs[buf][0] + c * 16);
        }
    };

    f32x4 acc[MR][NR] = {};
    const int NT = Kc / BK;
    STAGE(0, 0);
    __syncthreads();
    int cur = 0;
    for (int t = 0; t < NT; ++t) {
        if (t + 1 < NT) STAGE(cur ^ 1, (t + 1) * BK);   // prefetch next tile (in flight during compute)
        bf16x8 af[MR], bfr[NR];
        #pragma unroll
        for (int m = 0; m < MR; ++m)
            af[m] = *(const bf16x8*)&sAs[cur][(wr * WM + m * 16 + (lane & 15)) * BK + (lane >> 4) * 8];
        #pragma unroll
        for (int n = 0; n < NR; ++n)
            bfr[n] = *(const bf16x8*)&sBs[cur][(wc * WN + n * 16 + (lane & 15)) * BK + (lane >> 4) * 8];
        #pragma unroll
        for (int m = 0; m < MR; ++m)
            #pragma unroll
            for (int n = 0; n < NR; ++n)
                acc[m][n] = __builtin_amdgcn_mfma_f32_16x16x32_bf16(af[m], bfr[n], acc[m][n], 0, 0, 0);
        __syncthreads();    // implicit vmcnt(0): next tile landed; all waves done reading cur
        cur ^= 1;
    }
    const float* residz = resid ? resid + (size_t)z * sC : nullptr;
    float* Cfz = Cf ? Cf + (size_t)z * sC : nullptr;
    __hip_bfloat16* Cbz = Cb ? Cb + (size_t)z * sC : nullptr;
    #pragma unroll
    for (int m = 0; m < MR; ++m) {
        int row = m0 + wr * WM + m * 16 + (lane >> 4) * 4;
        #pragma unroll
        for (int n = 0; n < NR; ++n) {
            int col = n0 + wc * WN + n * 16 + (lane & 15);
            if (col < Nstore) {
                float bv = (bias && act != 2) ? bias[col] : 0.f;
                #pragma unroll
                for (int j = 0; j < 4; ++j) {
                    float v = acc[m][n][j] + bv;
                    if (residz) v += residz[(size_t)(row + j) * ldc + col];
                    if (act == 1) v = silu_f(v);
                    if (Cbz) Cbz[(size_t)(row + j) * ldc + col] = __float2bfloat16(v);
                    else     Cfz[(size_t)(row + j) * ldc + col] = v;
                }
            }
        }
    }
}

// ---------------- patch split-K finalize: sum 4 partials + bias -> hf, reversed -> hb ----------------
__global__ __launch_bounds__(256) void k_patch_fin(const float* __restrict__ part, const float* __restrict__ bias,
                                                   float* __restrict__ hf, float* __restrict__ hb) {
    int i4 = blockIdx.x * 256 + threadIdx.x;     // over 1024*1024/4
    int idx = i4 * 4;
    int r = idx >> 10, c = idx & 1023;
    float4 v = *(const float4*)(part + idx);
    float4 v1 = *(const float4*)(part + 1048576 + idx);
    float4 v2 = *(const float4*)(part + 2097152 + idx);
    float4 v3 = *(const float4*)(part + 3145728 + idx);
    float4 bv = *(const float4*)(bias + c);
    float4 o;
    o.x = v.x + v1.x + v2.x + v3.x + bv.x;
    o.y = v.y + v1.y + v2.y + v3.y + bv.y;
    o.z = v.z + v1.z + v2.z + v3.z + bv.z;
    o.w = v.w + v1.w + v2.w + v3.w + bv.w;
    *(float4*)(hf + idx) = o;
    *(float4*)(hb + (((size_t)(r ^ 127)) << 10) + c) = o;
}

// ---------------- rmsnorm: 2048 rows (fwd 0..1023, bwd 1024..2047) ----------------
__global__ __launch_bounds__(256) void k_rmsnorm(const float* __restrict__ h, const float* __restrict__ w0,
                                                 const float* __restrict__ w1, __hip_bfloat16* __restrict__ u) {
    int r = blockIdx.x; int t = threadIdx.x;
    const float* w = (r >> 10) ? w1 : w0;
    const float* row = h + (size_t)r * DM_;
    float v[4]; float ss = 0.f;
    #pragma unroll
    for (int i = 0; i < 4; ++i) { v[i] = row[t + 256 * i]; ss += v[i] * v[i]; }
    #pragma unroll
    for (int o = 32; o; o >>= 1) ss += __shfl_xor(ss, o);
    __shared__ float sred[4];
    if ((t & 63) == 0) sred[t >> 6] = ss;
    __syncthreads();
    float tot = sred[0] + sred[1] + sred[2] + sred[3];
    float scale = rsqrtf(tot * (1.0f / DM_) + 1e-5f);
    #pragma unroll
    for (int i = 0; i < 4; ++i)
        u[(size_t)r * DM_ + t + 256 * i] = __float2bfloat16(v[i] * scale * w[t + 256 * i]);
}

// ---------------- depthwise conv, bf16 in/out, 4 channels per thread ----------------
__global__ __launch_bounds__(256) void k_dwconv(const __hip_bfloat16* __restrict__ zx,
                                                const float* __restrict__ cw0, const float* __restrict__ cw1,
                                                const float* __restrict__ cb0, const float* __restrict__ cb1,
                                                __hip_bfloat16* __restrict__ xbc) {
    int idx = blockIdx.x * 256 + threadIdx.x;       // over 2048 * 520
    if (idx >= 2048 * 520) return;
    int c4 = idx % 520; int r = idx / 520;
    int dir = r >> 10, rl = r & 1023, l = rl & 127;
    const float* cw = (dir ? cw1 : cw0) + c4 * 16;
    const float* cb = (dir ? cb1 : cb0) + c4 * 4;
    const __hip_bfloat16* zxd = zx + (size_t)dir * 1024 * DIN_;
    float4 acc = *(const float4*)cb;
    #pragma unroll
    for (int k = 0; k < 4; ++k) {
        int lp = l - 3 + k;
        if (lp >= 0) {
            ushort4 raw = *(const ushort4*)(zxd + (size_t)(rl - l + lp) * DIN_ + DI_ + c4 * 4);
            acc.x += bu2f(raw.x) * cw[0 * 4 + k];
            acc.y += bu2f(raw.y) * cw[1 * 4 + k];
            acc.z += bu2f(raw.z) * cw[2 * 4 + k];
            acc.w += bu2f(raw.w) * cw[3 * 4 + k];
        }
    }
    ushort4 o;
    o.x = f2bu(silu_f(acc.x)); o.y = f2bu(silu_f(acc.y));
    o.z = f2bu(silu_f(acc.z)); o.w = f2bu(silu_f(acc.w));
    *(ushort4*)(xbc + (size_t)dir * 1024 * CONVD_ + (size_t)rl * CONVD_ + c4 * 4) = o;
}

// ---------------- SSM scan: one block per (dir,b,h) ----------------
__global__ __launch_bounds__(256) void k_scan(const __hip_bfloat16* __restrict__ xbc, const __hip_bfloat16* __restrict__ zx,
                                              const float* __restrict__ dtb0, const float* __restrict__ dtb1,
                                              const float* __restrict__ al0, const float* __restrict__ al1,
                                              const float* __restrict__ D0, const float* __restrict__ D1,
                                              __hip_bfloat16* __restrict__ ys) {
    __shared__ float xs[L_ * PH_];
    __shared__ float Bsh[L_ * NS_];
    __shared__ float Csh[L_ * NS_];
    __shared__ float dts[L_];
    __shared__ float dAs[L_];
    int bx = blockIdx.x;
    int dir = bx >> 8, b = (bx >> 5) & 7, h = bx & 31;
    const __hip_bfloat16* xbcd = xbc + (size_t)dir * 1024 * CONVD_;
    const __hip_bfloat16* zxd  = zx  + (size_t)dir * 1024 * DIN_;
    const float* dt_bias = dir ? dtb1 : dtb0;
    const float* A_log   = dir ? al1 : al0;
    const float* Dh      = dir ? D1 : D0;
    __hip_bfloat16* ysd  = ys + (size_t)dir * 1024 * DI_;
    int t = threadIdx.x;
    for (int i = t; i < L_ * PH_; i += 256) {
        int l = i >> 6, p = i & 63;
        xs[i] = __bfloat162float(xbcd[((size_t)(b * L_ + l)) * CONVD_ + h * PH_ + p]);
    }
    for (int i = t; i < L_ * NS_; i += 256) {
        int l = i >> 4, n = i & 15;
        Bsh[i] = __bfloat162float(xbcd[((size_t)(b * L_ + l)) * CONVD_ + DI_ + n]);
        Csh[i] = __bfloat162float(xbcd[((size_t)(b * L_ + l)) * CONVD_ + DI_ + NS_ + n]);
    }
    if (t < L_) {
        float v = __bfloat162float(zxd[((size_t)(b * L_ + t)) * DIN_ + 4128 + h]) + dt_bias[h];
        float sp = v > 20.f ? v : log1pf(expf(v));
        dts[t] = sp;
        dAs[t] = expf(-expf(A_log[h]) * sp);
    }
    __syncthreads();
    int p = t >> 2, n0 = (t & 3) * 4;
    float Dv = Dh[h];
    float s0 = 0.f, s1 = 0.f, s2 = 0.f, s3 = 0.f;
    for (int l = 0; l < L_; ++l) {
        float x = xs[l * 64 + p];
        float dAv = dAs[l];
        float xdt = x * dts[l];
        s0 = s0 * dAv + xdt * Bsh[l * 16 + n0 + 0];
        s1 = s1 * dAv + xdt * Bsh[l * 16 + n0 + 1];
        s2 = s2 * dAv + xdt * Bsh[l * 16 + n0 + 2];
        s3 = s3 * dAv + xdt * Bsh[l * 16 + n0 + 3];
        float cp = s0 * Csh[l * 16 + n0 + 0] + s1 * Csh[l * 16 + n0 + 1]
                 + s2 * Csh[l * 16 + n0 + 2] + s3 * Csh[l * 16 + n0 + 3];
        cp += __shfl_xor(cp, 1);
        cp += __shfl_xor(cp, 2);
        if ((t & 3) == 0) xs[l * 64 + p] = cp + x * Dv;
    }
    __syncthreads();
    for (int i = t; i < L_ * PH_; i += 256) {
        int l = i >> 6, pp = i & 63;
        float z = __bfloat162float(zxd[((size_t)(b * L_ + l)) * DIN_ + h * PH_ + pp]);
        ysd[((size_t)(b * L_ + l)) * DI_ + h * PH_ + pp] = __float2bfloat16(xs[i] * silu_f(z));
    }
}

// ---------------- tail ----------------
__global__ __launch_bounds__(256) void k_meanctx(const float* __restrict__ hf, const float* __restrict__ hb,
                                                 float* __restrict__ fused) {
    int b = blockIdx.x, t = threadIdx.x;
    int d = t * 4;
    float4 sf = {0,0,0,0}, sb = {0,0,0,0};
    for (int l = 0; l < L_; ++l) {
        float4 a = *(const float4*)(hf + ((size_t)b * L_ + l) * DM_ + d);
        float4 c = *(const float4*)(hb + ((size_t)b * L_ + l) * DM_ + d);
        sf.x += a.x; sf.y += a.y; sf.z += a.z; sf.w += a.w;
        sb.x += c.x; sb.y += c.y; sb.z += c.z; sb.w += c.w;
    }
    const float s = 1.f / L_;
    float4 o1 = {sf.x*s, sf.y*s, sf.z*s, sf.w*s};
    float4 o2 = {sb.x*s, sb.y*s, sb.z*s, sb.w*s};
    *(float4*)(fused + b * 3072 + d) = o1;
    *(float4*)(fused + b * 3072 + DM_ + d) = o2;
}

__global__ __launch_bounds__(256) void k_aux(const float* __restrict__ y_aux, const float* __restrict__ aux_w,
                                             const float* __restrict__ aux_b, float* __restrict__ fused) {
    int j = blockIdx.x * 256 + threadIdx.x;
    if (j >= DM_) return;
    for (int b = 0; b < B_; ++b) {
        float acc = aux_b[j];
        for (int a = 0; a < 32; ++a) acc += y_aux[b * 32 + a] * aux_w[j * 32 + a];
        fused[b * 3072 + 2 * DM_ + j] = silu_f(acc);
    }
}

__global__ __launch_bounds__(256) void k_basis(const float* __restrict__ x, const float* __restrict__ log_bw,
                                               float* __restrict__ basis, int Din) {
    int idx = blockIdx.x * 256 + threadIdx.x;
    if (idx >= 8 * Din) return;
    int d = idx % Din;
    float xv = x[idx];
    float bw = expf(log_bw[d]) + 1e-6f;
    float inv = 1.0f / (2.0f * bw * bw);
    #pragma unroll
    for (int g = 0; g < GG_; ++g) {
        float gg = -2.0f + g * (4.0f / 7.0f);
        float df = xv - gg;
        basis[(size_t)idx * GG_ + g] = expf(-df * df * inv);
    }
}

// ---------------- LDS-staged batched dot (tail GEMV family) ----------------
template<int MODE>
__global__ __launch_bounds__(256) void k_dotl(const float* __restrict__ W, const float* __restrict__ X,
                                              const float* __restrict__ bias, float* __restrict__ out,
                                              int K, int Dout, int ldx, int nch, int chOff) {
    __shared__ float sX[8][1024];
    int ch = blockIdx.y;
    int k0 = ch * 1024;
    int tid = threadIdx.x;
    for (int i = tid; i < 2048; i += 256) {
        int b = i >> 8, kk = (i & 255) * 4;
        *(float4*)&sX[b][kk] = *(const float4*)(X + (size_t)b * ldx + k0 + kk);
    }
    __syncthreads();
    int wv = tid >> 6, lane = tid & 63;
    int rowBase = blockIdx.x * 32 + wv * 8;
    for (int j = 0; j < 8; ++j) {
        int row = rowBase + j;
        const float* wr = W + (size_t)row * K + k0;
        float acc[8] = {};
        #pragma unroll
        for (int it = 0; it < 4; ++it) {
            int k = it * 256 + lane * 4;
            float4 wvv = *(const float4*)(wr + k);
            #pragma unroll
            for (int b = 0; b < 8; ++b) {
                float4 xv = *(const float4*)&sX[b][k];
                acc[b] += wvv.x * xv.x + wvv.y * xv.y + wvv.z * xv.z + wvv.w * xv.w;
            }
        }
        float e = reduce8(acc, lane);
        if (lane < 8) {
            if (MODE == 0) {
                out[((size_t)row * nch + chOff + ch) * 8 + lane] = e;
            } else if (MODE == 1) {
                out[(size_t)lane * Dout + row] = silu_f(e + bias[row]);
            } else {
                int c = row >> 9, l = row & 511;
                out[((size_t)lane * OUTL_ + l) * COUT_ + c] = e + bias[row];
            }
        }
    }
}

template<int NCH>
__global__ __launch_bounds__(256) void k_dot_fin(const float* __restrict__ partial, const float* __restrict__ base_b,
                                                 float* __restrict__ out, int Dout) {
    int row = blockIdx.x * 256 + threadIdx.x;
    if (row >= Dout) return;
    float bb = base_b[row];
    #pragma unroll
    for (int b = 0; b < 8; ++b) {
        float s = bb;
        #pragma unroll
        for (int c = 0; c < NCH; ++c) s += partial[((size_t)row * NCH + c) * 8 + b];
        out[(size_t)b * Dout + row] = silu_f(s);
    }
}

// ---------------- launch ----------------
extern "C" void kernel_launch(void* const* d_in, const int* in_sizes, int n_in,
                              void* d_out, int out_size, void* d_ws, size_t ws_size,
                              hipStream_t stream) {
    const float* x_prefix = (const float*)d_in[0];
    const float* y_aux    = (const float*)d_in[1];
    const float* pre_w    = (const float*)d_in[2];
    const float* pre_b    = (const float*)d_in[3];
    const float* patch_w  = (const float*)d_in[4];
    const float* patch_b  = (const float*)d_in[5];
    const float* norm_w[2] = {(const float*)d_in[6],  (const float*)d_in[14]};
    const float* in_w[2]   = {(const float*)d_in[7],  (const float*)d_in[15]};
    const float* conv_w[2] = {(const float*)d_in[8],  (const float*)d_in[16]};
    const float* conv_b[2] = {(const float*)d_in[9],  (const float*)d_in[17]};
    const float* A_log[2]  = {(const float*)d_in[10], (const float*)d_in[18]};
    const float* Dvec[2]   = {(const float*)d_in[11], (const float*)d_in[19]};
    const float* dt_b[2]   = {(const float*)d_in[12], (const float*)d_in[20]};
    const float* out_w[2]  = {(const float*)d_in[13], (const float*)d_in[21]};
    const float* aux_w = (const float*)d_in[22];
    const float* aux_b = (const float*)d_in[23];
    const float* k1_lbw = (const float*)d_in[24];
    const float* k1_bw  = (const float*)d_in[25];
    const float* k1_bb  = (const float*)d_in[26];
    const float* k1_sw  = (const float*)d_in[27];
    const float* k2_lbw = (const float*)d_in[28];
    const float* k2_bw  = (const float*)d_in[29];
    const float* k2_bb  = (const float*)d_in[30];
    const float* k2_sw  = (const float*)d_in[31];
    const float* sh_w = (const float*)d_in[32];
    const float* sh_b = (const float*)d_in[33];
    const float* hw   = (const float*)d_in[34];
    const float* hbias= (const float*)d_in[35];
    float* ws = (float*)d_ws;
    float* out = (float*)d_out;

    // workspace (float units)
    // stage: ApreB[0,1310720) wpreTB[..1474560) x1B[..5668864) wpatchTB[..9863168) ppart[..14057472)
    const size_t o_ApreB   = 0;
    const size_t o_wpreTB  = 1310720;
    const size_t o_x1B     = 1474560;
    const size_t o_wpatchTB= 5668864;
    const size_t o_ppart   = 9863168;     // f32 4x1024x1024
    // mamba overlay (all bf16 activations):
    const size_t o_uB   = 0;              // bf16 2x1024x1024 -> 1,048,576 f
    const size_t o_zxB  = 1048576;        // bf16 2x1024x4160 -> 4,259,840 f
    const size_t o_xbcB = 5308416;        // bf16 2x1024x2080 -> 2,129,920 f
    const size_t o_ysB  = 7438336;        // bf16 2x1024x2048 -> 2,097,152 f
    const size_t o_wBB  = 9535488;        // bf16 2x4224x1024 -> 4,325,376 f
    const size_t o_wOB  = 13860864;       // bf16 2x1024x2048 -> 2,097,152 f
    const size_t o_hf   = 15958016;       // f32 1024x1024
    const size_t o_hb   = 17006592;       // f32 1024x1024 (contiguous after hf)
    const size_t total_f = 18055168;      // 72.2 MB
    // tail overlay (mamba region dead):
    const size_t o_f1   = 0;
    const size_t o_bas1 = 24576;
    const size_t o_k1   = 221184;
    const size_t o_bas2 = 237568;
    const size_t o_k2   = 368640;
    const size_t o_f4   = 376832;
    const size_t o_part = 385024;         // 2048*27*8 = 442,368
    if (ws_size < total_f * sizeof(float)) return;

    __hip_bfloat16* ApreB   = (__hip_bfloat16*)(ws + o_ApreB);
    __hip_bfloat16* wpreTB  = (__hip_bfloat16*)(ws + o_wpreTB);
    __hip_bfloat16* x1B     = (__hip_bfloat16*)(ws + o_x1B);
    __hip_bfloat16* wpatchTB= (__hip_bfloat16*)(ws + o_wpatchTB);
    __hip_bfloat16* uB      = (__hip_bfloat16*)(ws + o_uB);
    __hip_bfloat16* zxB     = (__hip_bfloat16*)(ws + o_zxB);
    __hip_bfloat16* xbcB    = (__hip_bfloat16*)(ws + o_xbcB);
    __hip_bfloat16* ysB     = (__hip_bfloat16*)(ws + o_ysB);
    __hip_bfloat16* wBB     = (__hip_bfloat16*)(ws + o_wBB);
    __hip_bfloat16* wOB     = (__hip_bfloat16*)(ws + o_wOB);
    float* hf = ws + o_hf;
    float* hb = ws + o_hb;

    // Stage A: pre-conv im2col GEMM (silu fused) -> x1B bf16
    k_wpre_T<<<1280, 256, 0, stream>>>(pre_w, wpreTB);
    k_wpatch_T<<<32768, 256, 0, stream>>>(patch_w, wpatchTB);
    k_pre_im2col<<<10240, 256, 0, stream>>>(x_prefix, ApreB);
    k_gemm_mfma<128,128><<<dim3(8, 64, 1), 256, 0, stream>>>(
        (const ushort*)ApreB, (const ushort*)wpreTB, pre_b, nullptr, nullptr, x1B,
        320, 320, 1024, 1024, 1, 0, 0, 0);
    // Stage B: patch GEMM split-K=4 -> partials, then finalize (bias + dual store hf / reversed hb)
    k_gemm_mfma<64,64><<<dim3(16, 16, 4), 256, 0, stream>>>(
        (const ushort*)x1B, (const ushort*)wpatchTB, nullptr, nullptr, ws + o_ppart, nullptr,
        2048, 8192, 1024, 1024, 2, 0, 0, (long)1024 * 1024);
    k_patch_fin<<<1024, 256, 0, stream>>>(ws + o_ppart, patch_b, hf, hb);

    // Mamba stacks, both directions batched per dispatch
    for (int i = 0; i < NL_; ++i) {
        k_rmsnorm<<<2048, 256, 0, stream>>>(hf, norm_w[0] + (size_t)i * DM_, norm_w[1] + (size_t)i * DM_, uB);
        k_cvt_layer<<<12544, 256, 0, stream>>>(
            in_w[0] + (size_t)i * DIN_ * DM_, in_w[1] + (size_t)i * DIN_ * DM_,
            out_w[0] + (size_t)i * DM_ * DI_, out_w[1] + (size_t)i * DM_ * DI_, wBB, wOB);
        k_gemm_mfma<128,128><<<dim3(33, 8, 2), 256, 0, stream>>>(
            (const ushort*)uB, (const ushort*)wBB, nullptr, nullptr, nullptr, zxB,
            1024, 1024, DIN_, DIN_, 0, (long)1024 * 1024, (long)NPAD_ * 1024, (long)1024 * DIN_);
        k_dwconv<<<4160, 256, 0, stream>>>(zxB,
            conv_w[0] + (size_t)i * CONVD_ * 4, conv_w[1] + (size_t)i * CONVD_ * 4,
            conv_b[0] + (size_t)i * CONVD_, conv_b[1] + (size_t)i * CONVD_, xbcB);
        k_scan<<<512, 256, 0, stream>>>(xbcB, zxB,
            dt_b[0] + i * NH_, dt_b[1] + i * NH_, A_log[0] + i * NH_, A_log[1] + i * NH_,
            Dvec[0] + i * NH_, Dvec[1] + i * NH_, ysB);
        k_gemm_mfma<64,64><<<dim3(16, 16, 2), 256, 0, stream>>>(
            (const ushort*)ysB, (const ushort*)wOB, nullptr, hf, hf, nullptr,
            2048, 2048, 1024, 1024, 0, (long)1024 * 2048, (long)1024 * 2048, (long)1024 * 1024);
    }

    // Tail
    k_meanctx<<<8, 256, 0, stream>>>(hf, hb, ws + o_f1);
    k_aux<<<4, 256, 0, stream>>>(y_aux, aux_w, aux_b, ws + o_f1);
    k_basis<<<96, 256, 0, stream>>>(ws + o_f1, k1_lbw, ws + o_bas1, 3072);
    k_dotl<0><<<dim3(64, 24), 256, 0, stream>>>(k1_sw, ws + o_bas1, nullptr, ws + o_part, 24576, 2048, 24576, 27, 0);
    k_dotl<0><<<dim3(64, 3),  256, 0, stream>>>(k1_bw, ws + o_f1,   nullptr, ws + o_part, 3072,  2048, 3072,  27, 24);
    k_dot_fin<27><<<8, 256, 0, stream>>>(ws + o_part, k1_bb, ws + o_k1, 2048);
    k_basis<<<64, 256, 0, stream>>>(ws + o_k1, k2_lbw, ws + o_bas2, 2048);
    k_dotl<0><<<dim3(32, 16), 256, 0, stream>>>(k2_sw, ws + o_bas2, nullptr, ws + o_part, 16384, 1024, 16384, 18, 0);
    k_dotl<0><<<dim3(32, 2),  256, 0, stream>>>(k2_bw, ws + o_k1,   nullptr, ws + o_part, 2048,  1024, 2048,  18, 16);
    k_dot_fin<18><<<4, 256, 0, stream>>>(ws + o_part, k2_bb, ws + o_k2, 1024);
    k_dotl<1><<<dim3(32, 1), 256, 0, stream>>>(sh_w, ws + o_k2, sh_b, ws + o_f4, 1024, 1024, 1024, 1, 0);
    k_dotl<2><<<dim3(1024, 1), 256, 0, stream>>>(hw, ws + o_f4, hbias, out, 1024, 32768, 1024, 1, 0);
}

// Round 6
// 918.661 us; speedup vs baseline: 1.5993x; 1.0525x over previous
//
#include <hip/hip_runtime.h>
#include <hip/hip_bf16.h>
#include <math.h>

#define B_    8
#define LP_   1024
#define CIN_  64
#define DM_   1024
#define DI_   2048
#define NS_   16
#define PH_   64
#define NH_   32
#define NL_   4
#define GG_   8
#define KH_   2048
#define DIN_  4160
#define NPAD_ 4224
#define CONVD_ 2080
#define L_    128
#define R_    1024
#define OUTL_ 512
#define COUT_ 64

typedef __bf16 bf16x8 __attribute__((ext_vector_type(8)));
typedef float f32x4 __attribute__((ext_vector_type(4)));
typedef unsigned short ushort;

__device__ __forceinline__ float silu_f(float x) { return x / (1.0f + expf(-x)); }

__device__ __forceinline__ ushort f2bu(float x) {
    union { __hip_bfloat16 h; ushort u; } c; c.h = __float2bfloat16(x); return c.u;
}
__device__ __forceinline__ float bu2f(ushort u) {
    union { ushort u; __hip_bfloat16 h; } c; c.u = u; return __bfloat162float(c.h);
}

__device__ __forceinline__ void gload_lds16(const void* g, void* l) {
    __builtin_amdgcn_global_load_lds((const __attribute__((address_space(1))) unsigned int*)g,
                                     (__attribute__((address_space(3))) unsigned int*)l, 16, 0, 0);
}

// pair-merge reduce: 8 accumulators x 64 lanes -> lane (l&7) holds full sum of acc[l&7]
__device__ __forceinline__ float merge2(float a, float b, int mask, int lane) {
    float x = (lane & mask) ? b : a;
    float y = (lane & mask) ? a : b;
    return x + __shfl_xor(y, mask);
}
__device__ __forceinline__ float reduce8(float* a, int lane) {
    float c0 = merge2(a[0], a[1], 1, lane);
    float c1 = merge2(a[2], a[3], 1, lane);
    float c2 = merge2(a[4], a[5], 1, lane);
    float c3 = merge2(a[6], a[7], 1, lane);
    float d0 = merge2(c0, c1, 2, lane);
    float d1 = merge2(c2, c3, 2, lane);
    float e  = merge2(d0, d1, 4, lane);
    e += __shfl_xor(e, 8);
    e += __shfl_xor(e, 16);
    e += __shfl_xor(e, 32);
    return e;
}

// ---------------- im2col / weight transposes ----------------
__global__ __launch_bounds__(256) void k_pre_im2col(const float* __restrict__ xp, __hip_bfloat16* __restrict__ out) {
    size_t idx = (size_t)blockIdx.x * 256 + threadIdx.x;
    if (idx >= (size_t)8192 * 320) return;
    int kk = (int)(idx % 320); size_t r = idx / 320;
    int l = (int)(r & 1023); int b = (int)(r >> 10);
    int kp = kk >> 6, c = kk & 63;
    int lp = l + kp - 2;
    float v = 0.f;
    if (lp >= 0 && lp < LP_) v = xp[((size_t)b * LP_ + lp) * CIN_ + c];
    out[idx] = __float2bfloat16(v);
}

__global__ __launch_bounds__(256) void k_wpre_T(const float* __restrict__ w, __hip_bfloat16* __restrict__ out) {
    int idx = blockIdx.x * 256 + threadIdx.x;
    if (idx >= DM_ * 320) return;
    int d = idx / 320, kk = idx % 320;
    int kp = kk >> 6, c = kk & 63;
    out[idx] = __float2bfloat16(w[(d * CIN_ + c) * 5 + kp]);
}

__global__ __launch_bounds__(256) void k_wpatch_T(const float* __restrict__ w, __hip_bfloat16* __restrict__ out) {
    size_t idx = (size_t)blockIdx.x * 256 + threadIdx.x;
    if (idx >= (size_t)DM_ * 8192) return;
    int d = (int)(idx >> 13); int kk = (int)(idx & 8191);
    int kp = kk >> 10, din = kk & 1023;
    out[idx] = __float2bfloat16(w[((size_t)d << 13) + din * 8 + kp]);
}

// per-layer both dirs: in_w [4160][1024] -> wBB[dir][4224][1024] bf16 ; out_w [1024][2048] -> wOB[dir]
#define CVT_IN_T4  1081344   // 4224*1024/4
#define CVT_OUT_T4 524288    // 1024*2048/4
__global__ __launch_bounds__(256) void k_cvt_layer(const float* __restrict__ in0, const float* __restrict__ in1,
                                                   const float* __restrict__ o0, const float* __restrict__ o1,
                                                   __hip_bfloat16* __restrict__ wBB, __hip_bfloat16* __restrict__ wOB) {
    int i = blockIdx.x * 256 + threadIdx.x;
    int dir = 0;
    if (i >= CVT_IN_T4 + CVT_OUT_T4) { dir = 1; i -= CVT_IN_T4 + CVT_OUT_T4; }
    const float* inw = dir ? in1 : in0;
    const float* outw = dir ? o1 : o0;
    if (i < CVT_IN_T4) {
        int idx = i * 4; int row = idx >> 10;
        __hip_bfloat16* dst = wBB + (size_t)dir * NPAD_ * 1024 + idx;
        if (row < DIN_) {
            float4 v = *(const float4*)(inw + idx);
            dst[0] = __float2bfloat16(v.x); dst[1] = __float2bfloat16(v.y);
            dst[2] = __float2bfloat16(v.z); dst[3] = __float2bfloat16(v.w);
        } else {
            dst[0] = __float2bfloat16(0.f); dst[1] = __float2bfloat16(0.f);
            dst[2] = __float2bfloat16(0.f); dst[3] = __float2bfloat16(0.f);
        }
    } else {
        int idx = (i - CVT_IN_T4) * 4;
        __hip_bfloat16* dst = wOB + (size_t)dir * 1024 * 2048 + idx;
        float4 v = *(const float4*)(outw + idx);
        dst[0] = __float2bfloat16(v.x); dst[1] = __float2bfloat16(v.y);
        dst[2] = __float2bfloat16(v.z); dst[3] = __float2bfloat16(v.w);
    }
}

// ---------------- bf16 MFMA GEMM, 128^2 tile, 2-phase double-buffered, optional split-K ----------------
// z -> (dir = z/nsplit, ks = z%nsplit); kbase = ks*Kc. act: 0 -> bf16 store (+bias), 1 -> bf16 silu(+bias),
// 2 -> raw f32 split-K partial to Cf + z*sC. A,B bf16 row-major with row stride ldk, per-dir strides sA,sB.
template<int BM, int BN>
__global__ __launch_bounds__(256) void k_gemm_mfma(
    const ushort* __restrict__ A, const ushort* __restrict__ B,
    const float* __restrict__ bias,
    float* __restrict__ Cf, __hip_bfloat16* __restrict__ Cb,
    int Kc, int ldk, int ldc, int Nstore, int act, int nsplit,
    long sA, long sB, long sC)
{
    constexpr int BK = 32;
    constexpr int WM = BM / 2, WN = BN / 2;
    constexpr int MR = WM / 16, NR = WN / 16;
    constexpr int ACH = BM * 4, BCH = BN * 4;
    __shared__ ushort sAs[2][BM * BK];
    __shared__ ushort sBs[2][BN * BK];
    int tid = threadIdx.x;
    int lane = tid & 63, w = tid >> 6;
    int wr = w >> 1, wc = w & 1;
    int z = blockIdx.z;
    int dir = z / nsplit, ks = z - dir * nsplit;
    int kbase = ks * Kc;
    int m0 = blockIdx.y * BM, n0 = blockIdx.x * BN;
    const ushort* Az = A + (size_t)dir * sA + kbase;
    const ushort* Bz = B + (size_t)dir * sB + kbase;

    auto STAGE = [&](int buf, int k0) {
        #pragma unroll
        for (int c = tid; c < ACH; c += 256) {
            int row = c >> 2, col = (c & 3) * 8;
            gload_lds16(Az + (size_t)(m0 + row) * ldk + k0 + col, (char*)&sAs[buf][0] + c * 16);
        }
        #pragma unroll
        for (int c = tid; c < BCH; c += 256) {
            int row = c >> 2, col = (c & 3) * 8;
            gload_lds16(Bz + (size_t)(n0 + row) * ldk + k0 + col, (char*)&sBs[buf][0] + c * 16);
        }
    };

    f32x4 acc[MR][NR] = {};
    const int NT = Kc / BK;
    STAGE(0, 0);
    __syncthreads();
    int cur = 0;
    for (int t = 0; t < NT; ++t) {
        if (t + 1 < NT) STAGE(cur ^ 1, (t + 1) * BK);   // in flight during compute
        bf16x8 af[MR], bfr[NR];
        #pragma unroll
        for (int m = 0; m < MR; ++m)
            af[m] = *(const bf16x8*)&sAs[cur][(wr * WM + m * 16 + (lane & 15)) * BK + (lane >> 4) * 8];
        #pragma unroll
        for (int n = 0; n < NR; ++n)
            bfr[n] = *(const bf16x8*)&sBs[cur][(wc * WN + n * 16 + (lane & 15)) * BK + (lane >> 4) * 8];
        #pragma unroll
        for (int m = 0; m < MR; ++m)
            #pragma unroll
            for (int n = 0; n < NR; ++n)
                acc[m][n] = __builtin_amdgcn_mfma_f32_16x16x32_bf16(af[m], bfr[n], acc[m][n], 0, 0, 0);
        __syncthreads();    // implicit vmcnt(0)+lgkmcnt(0): next tile landed, cur fully consumed
        cur ^= 1;
    }
    #pragma unroll
    for (int m = 0; m < MR; ++m) {
        int row = m0 + wr * WM + m * 16 + (lane >> 4) * 4;
        #pragma unroll
        for (int n = 0; n < NR; ++n) {
            int col = n0 + wc * WN + n * 16 + (lane & 15);
            if (col < Nstore) {
                if (act == 2) {
                    float* Cfz = Cf + (size_t)z * sC;
                    #pragma unroll
                    for (int j = 0; j < 4; ++j)
                        Cfz[(size_t)(row + j) * ldc + col] = acc[m][n][j];
                } else {
                    __hip_bfloat16* Cbz = Cb + (size_t)dir * sC;
                    float bv = bias ? bias[col] : 0.f;
                    #pragma unroll
                    for (int j = 0; j < 4; ++j) {
                        float v = acc[m][n][j] + bv;
                        if (act == 1) v = silu_f(v);
                        Cbz[(size_t)(row + j) * ldc + col] = __float2bfloat16(v);
                    }
                }
            }
        }
    }
}

// ---------------- patch split-K=8 finalize: sum + bias -> hf, reversed -> hb ----------------
__global__ __launch_bounds__(256) void k_patch_fin(const float* __restrict__ part, const float* __restrict__ bias,
                                                   float* __restrict__ hf, float* __restrict__ hb) {
    int i4 = blockIdx.x * 256 + threadIdx.x;     // over 1024*1024/4
    int idx = i4 * 4;
    int r = idx >> 10, c = idx & 1023;
    float4 bv = *(const float4*)(bias + c);
    float4 o = bv;
    #pragma unroll
    for (int s = 0; s < 8; ++s) {
        float4 v = *(const float4*)(part + (size_t)s * 1048576 + idx);
        o.x += v.x; o.y += v.y; o.z += v.z; o.w += v.w;
    }
    *(float4*)(hf + idx) = o;
    *(float4*)(hb + (((size_t)(r ^ 127)) << 10) + c) = o;
}

// ---------------- out-proj split-K=4 finalize: h += sum of 4 partials (both dirs) ----------------
__global__ __launch_bounds__(256) void k_oproj_fin(const float* __restrict__ part, float* __restrict__ h) {
    int i4 = blockIdx.x * 256 + threadIdx.x;     // over 2*1024*1024/4
    int idx = i4 * 4;
    int dir = idx >> 20;
    int off = idx & 1048575;
    const float* p = part + (size_t)dir * 4 * 1048576 + off;
    float4 o = *(const float4*)(h + idx);
    #pragma unroll
    for (int s = 0; s < 4; ++s) {
        float4 v = *(const float4*)(p + (size_t)s * 1048576);
        o.x += v.x; o.y += v.y; o.z += v.z; o.w += v.w;
    }
    *(float4*)(h + idx) = o;
}

// ---------------- rmsnorm: 2048 rows (fwd 0..1023, bwd 1024..2047) ----------------
__global__ __launch_bounds__(256) void k_rmsnorm(const float* __restrict__ h, const float* __restrict__ w0,
                                                 const float* __restrict__ w1, __hip_bfloat16* __restrict__ u) {
    int r = blockIdx.x; int t = threadIdx.x;
    const float* w = (r >> 10) ? w1 : w0;
    const float* row = h + (size_t)r * DM_;
    float v[4]; float ss = 0.f;
    #pragma unroll
    for (int i = 0; i < 4; ++i) { v[i] = row[t + 256 * i]; ss += v[i] * v[i]; }
    #pragma unroll
    for (int o = 32; o; o >>= 1) ss += __shfl_xor(ss, o);
    __shared__ float sred[4];
    if ((t & 63) == 0) sred[t >> 6] = ss;
    __syncthreads();
    float tot = sred[0] + sred[1] + sred[2] + sred[3];
    float scale = rsqrtf(tot * (1.0f / DM_) + 1e-5f);
    #pragma unroll
    for (int i = 0; i < 4; ++i)
        u[(size_t)r * DM_ + t + 256 * i] = __float2bfloat16(v[i] * scale * w[t + 256 * i]);
}

// ---------------- SSM scan with fused depthwise conv: one block per (dir,b,h) ----------------
__global__ __launch_bounds__(256) void k_scan(const __hip_bfloat16* __restrict__ zx,
                                              const float* __restrict__ cw0, const float* __restrict__ cw1,
                                              const float* __restrict__ cb0, const float* __restrict__ cb1,
                                              const float* __restrict__ dtb0, const float* __restrict__ dtb1,
                                              const float* __restrict__ al0, const float* __restrict__ al1,
                                              const float* __restrict__ D0, const float* __restrict__ D1,
                                              __hip_bfloat16* __restrict__ ys) {
    __shared__ float xs[L_ * PH_];       // conv+silu x, then y in-place
    __shared__ float Bsh[L_ * NS_];
    __shared__ float Csh[L_ * NS_];
    __shared__ float dts[L_];
    __shared__ float dAs[L_];
    int bx = blockIdx.x;
    int dir = bx >> 8, b = (bx >> 5) & 7, h = bx & 31;
    const __hip_bfloat16* zxd = zx + (size_t)dir * 1024 * DIN_;
    const float* cw = dir ? cw1 : cw0;
    const float* cb = dir ? cb1 : cb0;
    const float* dt_bias = dir ? dtb1 : dtb0;
    const float* A_log   = dir ? al1 : al0;
    const float* Dh      = dir ? D1 : D0;
    __hip_bfloat16* ysd  = ys + (size_t)dir * 1024 * DI_;
    int t = threadIdx.x;
    // x channels of this head: c = h*64 + p4*4 + j ; depthwise conv (4 taps, causal pad) + silu
    for (int i = t; i < 2048; i += 256) {        // (l, p4)
        int l = i >> 4, p4 = i & 15;
        int cc = h * PH_ + p4 * 4;
        float a0 = cb[cc + 0], a1 = cb[cc + 1], a2 = cb[cc + 2], a3 = cb[cc + 3];
        #pragma unroll
        for (int k = 0; k < 4; ++k) {
            int lp = l - 3 + k;
            if (lp >= 0) {
                ushort4 raw = *(const ushort4*)(zxd + (size_t)(b * L_ + lp) * DIN_ + DI_ + cc);
                a0 += bu2f(raw.x) * cw[(cc + 0) * 4 + k];
                a1 += bu2f(raw.y) * cw[(cc + 1) * 4 + k];
                a2 += bu2f(raw.z) * cw[(cc + 2) * 4 + k];
                a3 += bu2f(raw.w) * cw[(cc + 3) * 4 + k];
            }
        }
        float* xp = &xs[l * PH_ + p4 * 4];
        xp[0] = silu_f(a0); xp[1] = silu_f(a1); xp[2] = silu_f(a2); xp[3] = silu_f(a3);
    }
    // B/C channels (2048..2079), conv + silu
    for (int i = t; i < 1024; i += 256) {        // (l, q4)
        int l = i >> 3, q4 = i & 7;
        int cc = DI_ + q4 * 4;
        float a0 = cb[cc + 0], a1 = cb[cc + 1], a2 = cb[cc + 2], a3 = cb[cc + 3];
        #pragma unroll
        for (int k = 0; k < 4; ++k) {
            int lp = l - 3 + k;
            if (lp >= 0) {
                ushort4 raw = *(const ushort4*)(zxd + (size_t)(b * L_ + lp) * DIN_ + DI_ + cc);
                a0 += bu2f(raw.x) * cw[(cc + 0) * 4 + k];
                a1 += bu2f(raw.y) * cw[(cc + 1) * 4 + k];
                a2 += bu2f(raw.z) * cw[(cc + 2) * 4 + k];
                a3 += bu2f(raw.w) * cw[(cc + 3) * 4 + k];
            }
        }
        float r0 = silu_f(a0), r1 = silu_f(a1), r2 = silu_f(a2), r3 = silu_f(a3);
        if (q4 < 4) {
            float* bp = &Bsh[l * NS_ + q4 * 4];
            bp[0] = r0; bp[1] = r1; bp[2] = r2; bp[3] = r3;
        } else {
            float* cp = &Csh[l * NS_ + (q4 - 4) * 4];
            cp[0] = r0; cp[1] = r1; cp[2] = r2; cp[3] = r3;
        }
    }
    if (t < L_) {
        float v = bu2f(*(const ushort*)(zxd + (size_t)(b * L_ + t) * DIN_ + 4128 + h)) + dt_bias[h];
        float sp = v > 20.f ? v : log1pf(expf(v));
        dts[t] = sp;
        dAs[t] = expf(-expf(A_log[h]) * sp);
    }
    __syncthreads();
    int p = t >> 2, n0 = (t & 3) * 4;
    float Dv = Dh[h];
    float s0 = 0.f, s1 = 0.f, s2 = 0.f, s3 = 0.f;
    for (int l = 0; l < L_; ++l) {
        float x = xs[l * 64 + p];
        float dAv = dAs[l];
        float xdt = x * dts[l];
        s0 = s0 * dAv + xdt * Bsh[l * 16 + n0 + 0];
        s1 = s1 * dAv + xdt * Bsh[l * 16 + n0 + 1];
        s2 = s2 * dAv + xdt * Bsh[l * 16 + n0 + 2];
        s3 = s3 * dAv + xdt * Bsh[l * 16 + n0 + 3];
        float cp = s0 * Csh[l * 16 + n0 + 0] + s1 * Csh[l * 16 + n0 + 1]
                 + s2 * Csh[l * 16 + n0 + 2] + s3 * Csh[l * 16 + n0 + 3];
        cp += __shfl_xor(cp, 1);
        cp += __shfl_xor(cp, 2);
        if ((t & 3) == 0) xs[l * 64 + p] = cp + x * Dv;
    }
    __syncthreads();
    for (int i = t; i < L_ * PH_; i += 256) {
        int l = i >> 6, pp = i & 63;
        float z = bu2f(*(const ushort*)(zxd + (size_t)(b * L_ + l) * DIN_ + h * PH_ + pp));
        ysd[((size_t)(b * L_ + l)) * DI_ + h * PH_ + pp] = __float2bfloat16(xs[i] * silu_f(z));
    }
}

// ---------------- tail ----------------
// grid 64: (b, 128-float chunk); LDS-reduced over l
__global__ __launch_bounds__(256) void k_meanctx(const float* __restrict__ hf, const float* __restrict__ hb,
                                                 float* __restrict__ fused) {
    int b = blockIdx.x >> 3, ch = blockIdx.x & 7;
    int t = threadIdx.x;
    int d4 = t & 31, lg = t >> 5;
    int d = ch * 128 + d4 * 4;
    float4 sf = {0,0,0,0}, sb = {0,0,0,0};
    for (int l = lg; l < L_; l += 8) {
        float4 a = *(const float4*)(hf + ((size_t)b * L_ + l) * DM_ + d);
        float4 c = *(const float4*)(hb + ((size_t)b * L_ + l) * DM_ + d);
        sf.x += a.x; sf.y += a.y; sf.z += a.z; sf.w += a.w;
        sb.x += c.x; sb.y += c.y; sb.z += c.z; sb.w += c.w;
    }
    __shared__ float rf[8][128], rb[8][128];
    *(float4*)&rf[lg][d4 * 4] = sf;
    *(float4*)&rb[lg][d4 * 4] = sb;
    __syncthreads();
    if (t < 128) {
        float s1 = 0.f, s2 = 0.f;
        #pragma unroll
        for (int g = 0; g < 8; ++g) { s1 += rf[g][t]; s2 += rb[g][t]; }
        fused[b * 3072 + ch * 128 + t] = s1 * (1.f / L_);
        fused[b * 3072 + DM_ + ch * 128 + t] = s2 * (1.f / L_);
    }
}

__global__ __launch_bounds__(256) void k_aux(const float* __restrict__ y_aux, const float* __restrict__ aux_w,
                                             const float* __restrict__ aux_b, float* __restrict__ fused) {
    int j = blockIdx.x * 256 + threadIdx.x;
    if (j >= DM_) return;
    for (int b = 0; b < B_; ++b) {
        float acc = aux_b[j];
        for (int a = 0; a < 32; ++a) acc += y_aux[b * 32 + a] * aux_w[j * 32 + a];
        fused[b * 3072 + 2 * DM_ + j] = silu_f(acc);
    }
}

__global__ __launch_bounds__(256) void k_basis(const float* __restrict__ x, const float* __restrict__ log_bw,
                                               float* __restrict__ basis, int Din) {
    int idx = blockIdx.x * 256 + threadIdx.x;
    if (idx >= 8 * Din) return;
    int d = idx % Din;
    float xv = x[idx];
    float bw = expf(log_bw[d]) + 1e-6f;
    float inv = 1.0f / (2.0f * bw * bw);
    #pragma unroll
    for (int g = 0; g < GG_; ++g) {
        float gg = -2.0f + g * (4.0f / 7.0f);
        float df = xv - gg;
        basis[(size_t)idx * GG_ + g] = expf(-df * df * inv);
    }
}

// ---------------- LDS-staged batched dot (tail GEMV family) ----------------
template<int MODE>
__global__ __launch_bounds__(256) void k_dotl(const float* __restrict__ W, const float* __restrict__ X,
                                              const float* __restrict__ bias, float* __restrict__ out,
                                              int K, int Dout, int ldx, int nch, int chOff) {
    __shared__ float sX[8][1024];
    int ch = blockIdx.y;
    int k0 = ch * 1024;
    int tid = threadIdx.x;
    for (int i = tid; i < 2048; i += 256) {
        int b = i >> 8, kk = (i & 255) * 4;
        *(float4*)&sX[b][kk] = *(const float4*)(X + (size_t)b * ldx + k0 + kk);
    }
    __syncthreads();
    int wv = tid >> 6, lane = tid & 63;
    int rowBase = blockIdx.x * 32 + wv * 8;
    for (int j = 0; j < 8; ++j) {
        int row = rowBase + j;
        const float* wr = W + (size_t)row * K + k0;
        float acc[8] = {};
        #pragma unroll
        for (int it = 0; it < 4; ++it) {
            int k = it * 256 + lane * 4;
            float4 wvv = *(const float4*)(wr + k);
            #pragma unroll
            for (int b = 0; b < 8; ++b) {
                float4 xv = *(const float4*)&sX[b][k];
                acc[b] += wvv.x * xv.x + wvv.y * xv.y + wvv.z * xv.z + wvv.w * xv.w;
            }
        }
        float e = reduce8(acc, lane);
        if (lane < 8) {
            if (MODE == 0) {
                out[((size_t)row * nch + chOff + ch) * 8 + lane] = e;
            } else if (MODE == 1) {
                out[(size_t)lane * Dout + row] = silu_f(e + bias[row]);
            } else {
                int c = row >> 9, l = row & 511;
                out[((size_t)lane * OUTL_ + l) * COUT_ + c] = e + bias[row];
            }
        }
    }
}

template<int NCH>
__global__ __launch_bounds__(256) void k_dot_fin(const float* __restrict__ partial, const float* __restrict__ base_b,
                                                 float* __restrict__ out, int Dout) {
    int row = blockIdx.x * 256 + threadIdx.x;
    if (row >= Dout) return;
    float bb = base_b[row];
    #pragma unroll
    for (int b = 0; b < 8; ++b) {
        float s = bb;
        #pragma unroll
        for (int c = 0; c < NCH; ++c) s += partial[((size_t)row * NCH + c) * 8 + b];
        out[(size_t)b * Dout + row] = silu_f(s);
    }
}

// ---------------- launch ----------------
extern "C" void kernel_launch(void* const* d_in, const int* in_sizes, int n_in,
                              void* d_out, int out_size, void* d_ws, size_t ws_size,
                              hipStream_t stream) {
    const float* x_prefix = (const float*)d_in[0];
    const float* y_aux    = (const float*)d_in[1];
    const float* pre_w    = (const float*)d_in[2];
    const float* pre_b    = (const float*)d_in[3];
    const float* patch_w  = (const float*)d_in[4];
    const float* patch_b  = (const float*)d_in[5];
    const float* norm_w[2] = {(const float*)d_in[6],  (const float*)d_in[14]};
    const float* in_w[2]   = {(const float*)d_in[7],  (const float*)d_in[15]};
    const float* conv_w[2] = {(const float*)d_in[8],  (const float*)d_in[16]};
    const float* conv_b[2] = {(const float*)d_in[9],  (const float*)d_in[17]};
    const float* A_log[2]  = {(const float*)d_in[10], (const float*)d_in[18]};
    const float* Dvec[2]   = {(const float*)d_in[11], (const float*)d_in[19]};
    const float* dt_b[2]   = {(const float*)d_in[12], (const float*)d_in[20]};
    const float* out_w[2]  = {(const float*)d_in[13], (const float*)d_in[21]};
    const float* aux_w = (const float*)d_in[22];
    const float* aux_b = (const float*)d_in[23];
    const float* k1_lbw = (const float*)d_in[24];
    const float* k1_bw  = (const float*)d_in[25];
    const float* k1_bb  = (const float*)d_in[26];
    const float* k1_sw  = (const float*)d_in[27];
    const float* k2_lbw = (const float*)d_in[28];
    const float* k2_bw  = (const float*)d_in[29];
    const float* k2_bb  = (const float*)d_in[30];
    const float* k2_sw  = (const float*)d_in[31];
    const float* sh_w = (const float*)d_in[32];
    const float* sh_b = (const float*)d_in[33];
    const float* hw   = (const float*)d_in[34];
    const float* hbias= (const float*)d_in[35];
    float* ws = (float*)d_ws;
    float* out = (float*)d_out;

    // workspace (float units)
    // stage overlay: ApreB[0..1310720) wpreTB[..1474560) x1B[..5668864) wpatchTB[..9863168)
    const size_t o_ApreB   = 0;
    const size_t o_wpreTB  = 1310720;
    const size_t o_x1B     = 1474560;
    const size_t o_wpatchTB= 5668864;
    // mamba overlay (same region, stage dead):
    const size_t o_uB   = 0;              // bf16 2x1024x1024
    const size_t o_zxB  = 1048576;        // bf16 2x1024x4160 -> ends 5,308,416
    const size_t o_ysB  = 5308416;        // bf16 2x1024x2048 -> ends 7,405,568
    const size_t o_wBB  = 7405568;        // bf16 2x4224x1024 -> ends 11,730,944
    const size_t o_wOB  = 11730944;       // bf16 2x1024x2048 -> ends 13,828,096
    const size_t o_hf   = 13828096;       // f32 1024x1024
    const size_t o_hb   = 14876672;       // f32 1024x1024 (contiguous after hf)
    const size_t o_spart= 15925248;       // f32 8x1024x1024 split-K partials -> ends 24,313,856
    const size_t total_f = 24313856;      // ~97 MB
    // tail overlay (mamba region dead):
    const size_t o_f1   = 0;
    const size_t o_bas1 = 24576;
    const size_t o_k1   = 221184;
    const size_t o_bas2 = 237568;
    const size_t o_k2   = 368640;
    const size_t o_f4   = 376832;
    const size_t o_part = 385024;         // 2048*27*8 = 442,368 -> ends 827,392
    if (ws_size < total_f * sizeof(float)) return;

    __hip_bfloat16* ApreB   = (__hip_bfloat16*)(ws + o_ApreB);
    __hip_bfloat16* wpreTB  = (__hip_bfloat16*)(ws + o_wpreTB);
    __hip_bfloat16* x1B     = (__hip_bfloat16*)(ws + o_x1B);
    __hip_bfloat16* wpatchTB= (__hip_bfloat16*)(ws + o_wpatchTB);
    __hip_bfloat16* uB      = (__hip_bfloat16*)(ws + o_uB);
    __hip_bfloat16* zxB     = (__hip_bfloat16*)(ws + o_zxB);
    __hip_bfloat16* ysB     = (__hip_bfloat16*)(ws + o_ysB);
    __hip_bfloat16* wBB     = (__hip_bfloat16*)(ws + o_wBB);
    __hip_bfloat16* wOB     = (__hip_bfloat16*)(ws + o_wOB);
    float* hf = ws + o_hf;
    float* hb = ws + o_hb;

    // Stage A: pre-conv im2col GEMM (silu fused) -> x1B bf16
    k_wpre_T<<<1280, 256, 0, stream>>>(pre_w, wpreTB);
    k_wpatch_T<<<32768, 256, 0, stream>>>(patch_w, wpatchTB);
    k_pre_im2col<<<10240, 256, 0, stream>>>(x_prefix, ApreB);
    k_gemm_mfma<128,128><<<dim3(8, 64, 1), 256, 0, stream>>>(
        (const ushort*)ApreB, (const ushort*)wpreTB, pre_b, nullptr, x1B,
        320, 320, 1024, 1024, 1, 1, 0, 0, 0);
    // Stage B: patch GEMM split-K=8 (128^2 tiles) -> partials -> finalize (bias + hf / reversed hb)
    k_gemm_mfma<128,128><<<dim3(8, 8, 8), 256, 0, stream>>>(
        (const ushort*)x1B, (const ushort*)wpatchTB, nullptr, ws + o_spart, nullptr,
        1024, 8192, 1024, 1024, 2, 8, 0, 0, (long)1024 * 1024);
    k_patch_fin<<<1024, 256, 0, stream>>>(ws + o_spart, patch_b, hf, hb);

    // Mamba stacks, both directions batched per dispatch
    for (int i = 0; i < NL_; ++i) {
        k_rmsnorm<<<2048, 256, 0, stream>>>(hf, norm_w[0] + (size_t)i * DM_, norm_w[1] + (size_t)i * DM_, uB);
        k_cvt_layer<<<12544, 256, 0, stream>>>(
            in_w[0] + (size_t)i * DIN_ * DM_, in_w[1] + (size_t)i * DIN_ * DM_,
            out_w[0] + (size_t)i * DM_ * DI_, out_w[1] + (size_t)i * DM_ * DI_, wBB, wOB);
        k_gemm_mfma<128,128><<<dim3(33, 8, 2), 256, 0, stream>>>(
            (const ushort*)uB, (const ushort*)wBB, nullptr, nullptr, zxB,
            1024, 1024, DIN_, DIN_, 0, 1, (long)1024 * 1024, (long)NPAD_ * 1024, (long)1024 * DIN_);
        k_scan<<<512, 256, 0, stream>>>(zxB,
            conv_w[0] + (size_t)i * CONVD_ * 4, conv_w[1] + (size_t)i * CONVD_ * 4,
            conv_b[0] + (size_t)i * CONVD_, conv_b[1] + (size_t)i * CONVD_,
            dt_b[0] + i * NH_, dt_b[1] + i * NH_, A_log[0] + i * NH_, A_log[1] + i * NH_,
            Dvec[0] + i * NH_, Dvec[1] + i * NH_, ysB);
        k_gemm_mfma<128,128><<<dim3(8, 8, 8), 256, 0, stream>>>(
            (const ushort*)ysB, (const ushort*)wOB, nullptr, ws + o_spart, nullptr,
            512, 2048, 1024, 1024, 2, 4, (long)1024 * 2048, (long)1024 * 2048, (long)1024 * 1024);
        k_oproj_fin<<<2048, 256, 0, stream>>>(ws + o_spart, hf);
    }

    // Tail
    k_meanctx<<<64, 256, 0, stream>>>(hf, hb, ws + o_f1);
    k_aux<<<4, 256, 0, stream>>>(y_aux, aux_w, aux_b, ws + o_f1);
    k_basis<<<96, 256, 0, stream>>>(ws + o_f1, k1_lbw, ws + o_bas1, 3072);
    k_dotl<0><<<dim3(64, 24), 256, 0, stream>>>(k1_sw, ws + o_bas1, nullptr, ws + o_part, 24576, 2048, 24576, 27, 0);
    k_dotl<0><<<dim3(64, 3),  256, 0, stream>>>(k1_bw, ws + o_f1,   nullptr, ws + o_part, 3072,  2048, 3072,  27, 24);
    k_dot_fin<27><<<8, 256, 0, stream>>>(ws + o_part, k1_bb, ws + o_k1, 2048);
    k_basis<<<64, 256, 0, stream>>>(ws + o_k1, k2_lbw, ws + o_bas2, 2048);
    k_dotl<0><<<dim3(32, 16), 256, 0, stream>>>(k2_sw, ws + o_bas2, nullptr, ws + o_part, 16384, 1024, 16384, 18, 0);
    k_dotl<0><<<dim3(32, 2),  256, 0, stream>>>(k2_bw, ws + o_k1,   nullptr, ws + o_part, 2048,  1024, 2048,  18, 16);
    k_dot_fin<18><<<4, 256, 0, stream>>>(ws + o_part, k2_bb, ws + o_k2, 1024);
    k_dotl<1><<<dim3(32, 1), 256, 0, stream>>>(sh_w, ws + o_k2, sh_b, ws + o_f4, 1024, 1024, 1024, 1, 0);
    k_dotl<2><<<dim3(1024, 1), 256, 0, stream>>>(hw, ws + o_f4, hbias, out, 1024, 32768, 1024, 1, 0);
}

// Round 7
// 883.048 us; speedup vs baseline: 1.6638x; 1.0403x over previous
//
#include <hip/hip_runtime.h>
#include <hip/hip_bf16.h>
#include <math.h>

#define B_    8
#define LP_   1024
#define CIN_  64
#define DM_   1024
#define DI_   2048
#define NS_   16
#define PH_   64
#define NH_   32
#define NL_   4
#define GG_   8
#define KH_   2048
#define DIN_  4160
#define NPAD_ 4224
#define CONVD_ 2080
#define L_    128
#define R_    1024
#define OUTL_ 512
#define COUT_ 64

typedef __bf16 bf16x8 __attribute__((ext_vector_type(8)));
typedef float f32x4 __attribute__((ext_vector_type(4)));
typedef unsigned short ushort;

__device__ __forceinline__ float silu_f(float x) { return x / (1.0f + expf(-x)); }

__device__ __forceinline__ ushort f2bu(float x) {
    union { __hip_bfloat16 h; ushort u; } c; c.h = __float2bfloat16(x); return c.u;
}
__device__ __forceinline__ float bu2f(ushort u) {
    union { ushort u; __hip_bfloat16 h; } c; c.u = u; return __bfloat162float(c.h);
}

__device__ __forceinline__ void gload_lds16(const void* g, void* l) {
    __builtin_amdgcn_global_load_lds((const __attribute__((address_space(1))) unsigned int*)g,
                                     (__attribute__((address_space(3))) unsigned int*)l, 16, 0, 0);
}

// pair-merge reduce: 8 accumulators x 64 lanes -> lane (l&7) holds full sum of acc[l&7]
__device__ __forceinline__ float merge2(float a, float b, int mask, int lane) {
    float x = (lane & mask) ? b : a;
    float y = (lane & mask) ? a : b;
    return x + __shfl_xor(y, mask);
}
__device__ __forceinline__ float reduce8(float* a, int lane) {
    float c0 = merge2(a[0], a[1], 1, lane);
    float c1 = merge2(a[2], a[3], 1, lane);
    float c2 = merge2(a[4], a[5], 1, lane);
    float c3 = merge2(a[6], a[7], 1, lane);
    float d0 = merge2(c0, c1, 2, lane);
    float d1 = merge2(c2, c3, 2, lane);
    float e  = merge2(d0, d1, 4, lane);
    e += __shfl_xor(e, 8);
    e += __shfl_xor(e, 16);
    e += __shfl_xor(e, 32);
    return e;
}

// ---------------- merged prep: wpre_T + wpatch_T + pre_im2col ----------------
#define PREP_W1 327680      // DM_*320
#define PREP_W2 8388608     // DM_*8192
#define PREP_W3 2621440     // 8192*320
__global__ __launch_bounds__(256) void k_prep(const float* __restrict__ pre_w, const float* __restrict__ patch_w,
                                              const float* __restrict__ xp,
                                              __hip_bfloat16* __restrict__ wpreT, __hip_bfloat16* __restrict__ wpatchT,
                                              __hip_bfloat16* __restrict__ Apre) {
    int idx = blockIdx.x * 256 + threadIdx.x;
    if (idx < PREP_W1) {
        int d = idx / 320, kk = idx % 320;
        int kp = kk >> 6, c = kk & 63;
        wpreT[idx] = __float2bfloat16(pre_w[(d * CIN_ + c) * 5 + kp]);
    } else if (idx < PREP_W1 + PREP_W2) {
        int i = idx - PREP_W1;
        int d = i >> 13, kk = i & 8191;
        int kp = kk >> 10, din = kk & 1023;
        wpatchT[i] = __float2bfloat16(patch_w[((size_t)d << 13) + din * 8 + kp]);
    } else if (idx < PREP_W1 + PREP_W2 + PREP_W3) {
        int i = idx - PREP_W1 - PREP_W2;
        int kk = i % 320; int r = i / 320;
        int l = r & 1023, b = r >> 10;
        int kp = kk >> 6, c = kk & 63;
        int lp = l + kp - 2;
        float v = 0.f;
        if (lp >= 0 && lp < LP_) v = xp[((size_t)b * LP_ + lp) * CIN_ + c];
        Apre[i] = __float2bfloat16(v);
    }
}

// ---------------- all-layers weight convert: in_w -> wBBa (padded), out_w -> wOBa ----------------
#define CVT_IN_T4  1081344   // NPAD_*1024/4
#define CVT_OUT_T4 524288    // 1024*2048/4
#define CVT_PER    1605632   // CVT_IN_T4 + CVT_OUT_T4
__global__ __launch_bounds__(256) void k_cvt_all(const float* __restrict__ in0, const float* __restrict__ in1,
                                                 const float* __restrict__ o0, const float* __restrict__ o1,
                                                 __hip_bfloat16* __restrict__ wBBa, __hip_bfloat16* __restrict__ wOBa) {
    int i = blockIdx.x * 256 + threadIdx.x;
    if (i >= 8 * CVT_PER) return;
    int ld = i / CVT_PER;
    int r = i - ld * CVT_PER;
    int l = ld >> 1, d = ld & 1;
    const float* inw  = (d ? in1 : in0) + (size_t)l * DIN_ * DM_;
    const float* outw = (d ? o1 : o0) + (size_t)l * DM_ * DI_;
    if (r < CVT_IN_T4) {
        int idx = r * 4; int row = idx >> 10;
        __hip_bfloat16* dst = wBBa + (size_t)ld * NPAD_ * 1024 + idx;
        if (row < DIN_) {
            float4 v = *(const float4*)(inw + idx);
            dst[0] = __float2bfloat16(v.x); dst[1] = __float2bfloat16(v.y);
            dst[2] = __float2bfloat16(v.z); dst[3] = __float2bfloat16(v.w);
        } else {
            dst[0] = __float2bfloat16(0.f); dst[1] = __float2bfloat16(0.f);
            dst[2] = __float2bfloat16(0.f); dst[3] = __float2bfloat16(0.f);
        }
    } else {
        int idx = (r - CVT_IN_T4) * 4;
        __hip_bfloat16* dst = wOBa + (size_t)ld * 2048 * 1024 + idx;
        float4 v = *(const float4*)(outw + idx);
        dst[0] = __float2bfloat16(v.x); dst[1] = __float2bfloat16(v.y);
        dst[2] = __float2bfloat16(v.z); dst[3] = __float2bfloat16(v.w);
    }
}

// ---------------- bf16 MFMA GEMM, 128^2 tile, 2-phase double-buffered, optional split-K ----------------
template<int BM, int BN>
__global__ __launch_bounds__(256) void k_gemm_mfma(
    const ushort* __restrict__ A, const ushort* __restrict__ B,
    const float* __restrict__ bias,
    float* __restrict__ Cf, __hip_bfloat16* __restrict__ Cb,
    int Kc, int ldk, int ldc, int Nstore, int act, int nsplit,
    long sA, long sB, long sC)
{
    constexpr int BK = 32;
    constexpr int WM = BM / 2, WN = BN / 2;
    constexpr int MR = WM / 16, NR = WN / 16;
    constexpr int ACH = BM * 4, BCH = BN * 4;
    __shared__ ushort sAs[2][BM * BK];
    __shared__ ushort sBs[2][BN * BK];
    int tid = threadIdx.x;
    int lane = tid & 63, w = tid >> 6;
    int wr = w >> 1, wc = w & 1;
    int z = blockIdx.z;
    int dir = z / nsplit, ks = z - dir * nsplit;
    int kbase = ks * Kc;
    int m0 = blockIdx.y * BM, n0 = blockIdx.x * BN;
    const ushort* Az = A + (size_t)dir * sA + kbase;
    const ushort* Bz = B + (size_t)dir * sB + kbase;

    auto STAGE = [&](int buf, int k0) {
        #pragma unroll
        for (int c = tid; c < ACH; c += 256) {
            int row = c >> 2, col = (c & 3) * 8;
            gload_lds16(Az + (size_t)(m0 + row) * ldk + k0 + col, (char*)&sAs[buf][0] + c * 16);
        }
        #pragma unroll
        for (int c = tid; c < BCH; c += 256) {
            int row = c >> 2, col = (c & 3) * 8;
            gload_lds16(Bz + (size_t)(n0 + row) * ldk + k0 + col, (char*)&sBs[buf][0] + c * 16);
        }
    };

    f32x4 acc[MR][NR] = {};
    const int NT = Kc / BK;
    STAGE(0, 0);
    __syncthreads();
    int cur = 0;
    for (int t = 0; t < NT; ++t) {
        if (t + 1 < NT) STAGE(cur ^ 1, (t + 1) * BK);   // in flight during compute
        bf16x8 af[MR], bfr[NR];
        #pragma unroll
        for (int m = 0; m < MR; ++m)
            af[m] = *(const bf16x8*)&sAs[cur][(wr * WM + m * 16 + (lane & 15)) * BK + (lane >> 4) * 8];
        #pragma unroll
        for (int n = 0; n < NR; ++n)
            bfr[n] = *(const bf16x8*)&sBs[cur][(wc * WN + n * 16 + (lane & 15)) * BK + (lane >> 4) * 8];
        #pragma unroll
        for (int m = 0; m < MR; ++m)
            #pragma unroll
            for (int n = 0; n < NR; ++n)
                acc[m][n] = __builtin_amdgcn_mfma_f32_16x16x32_bf16(af[m], bfr[n], acc[m][n], 0, 0, 0);
        __syncthreads();
        cur ^= 1;
    }
    #pragma unroll
    for (int m = 0; m < MR; ++m) {
        int row = m0 + wr * WM + m * 16 + (lane >> 4) * 4;
        #pragma unroll
        for (int n = 0; n < NR; ++n) {
            int col = n0 + wc * WN + n * 16 + (lane & 15);
            if (col < Nstore) {
                if (act == 2) {
                    float* Cfz = Cf + (size_t)z * sC;
                    #pragma unroll
                    for (int j = 0; j < 4; ++j)
                        Cfz[(size_t)(row + j) * ldc + col] = acc[m][n][j];
                } else {
                    __hip_bfloat16* Cbz = Cb + (size_t)dir * sC;
                    float bv = bias ? bias[col] : 0.f;
                    #pragma unroll
                    for (int j = 0; j < 4; ++j) {
                        float v = acc[m][n][j] + bv;
                        if (act == 1) v = silu_f(v);
                        Cbz[(size_t)(row + j) * ldc + col] = __float2bfloat16(v);
                    }
                }
            }
        }
    }
}

// ---------------- patch finalize + first rmsnorm: one block per hf row ----------------
__global__ __launch_bounds__(256) void k_patch_fin_rms(const float* __restrict__ part, const float* __restrict__ bias,
                                                       const float* __restrict__ w0, const float* __restrict__ w1,
                                                       float* __restrict__ hf, float* __restrict__ hb,
                                                       __hip_bfloat16* __restrict__ uB) {
    int r = blockIdx.x;          // 0..1023
    int t = threadIdx.x;
    int c = t * 4;
    float4 o = *(const float4*)(bias + c);
    #pragma unroll
    for (int s = 0; s < 8; ++s) {
        float4 v = *(const float4*)(part + (size_t)s * 1048576 + ((size_t)r << 10) + c);
        o.x += v.x; o.y += v.y; o.z += v.z; o.w += v.w;
    }
    *(float4*)(hf + ((size_t)r << 10) + c) = o;
    int rb = r ^ 127;
    *(float4*)(hb + ((size_t)rb << 10) + c) = o;
    float ss = o.x * o.x + o.y * o.y + o.z * o.z + o.w * o.w;
    #pragma unroll
    for (int of = 32; of; of >>= 1) ss += __shfl_xor(ss, of);
    __shared__ float sred[4];
    if ((t & 63) == 0) sred[t >> 6] = ss;
    __syncthreads();
    float tot = sred[0] + sred[1] + sred[2] + sred[3];
    float scale = rsqrtf(tot * (1.0f / DM_) + 1e-5f);
    float4 wf = *(const float4*)(w0 + c);
    float4 wb = *(const float4*)(w1 + c);
    __hip_bfloat16* uf = uB + ((size_t)r << 10) + c;
    __hip_bfloat16* ub = uB + ((size_t)(1024 + rb) << 10) + c;
    uf[0] = __float2bfloat16(o.x * scale * wf.x); uf[1] = __float2bfloat16(o.y * scale * wf.y);
    uf[2] = __float2bfloat16(o.z * scale * wf.z); uf[3] = __float2bfloat16(o.w * scale * wf.w);
    ub[0] = __float2bfloat16(o.x * scale * wb.x); ub[1] = __float2bfloat16(o.y * scale * wb.y);
    ub[2] = __float2bfloat16(o.z * scale * wb.z); ub[3] = __float2bfloat16(o.w * scale * wb.w);
}

// ---------------- out-proj finalize (+residual) + next rmsnorm: one block per h row (2048) ----------------
template<bool DO_RMS>
__global__ __launch_bounds__(256) void k_oproj_fin_rms(const float* __restrict__ part,
                                                       const float* __restrict__ w0, const float* __restrict__ w1,
                                                       float* __restrict__ h, __hip_bfloat16* __restrict__ uB) {
    int row = blockIdx.x;        // 0..2047 (dir = row>>10)
    int t = threadIdx.x;
    int c = t * 4;
    const float* p = part + (size_t)(row >> 10) * 4194304 + (size_t)(row & 1023) * 1024 + c;
    float4 o = *(const float4*)(h + ((size_t)row << 10) + c);
    #pragma unroll
    for (int s = 0; s < 4; ++s) {
        float4 v = *(const float4*)(p + (size_t)s * 1048576);
        o.x += v.x; o.y += v.y; o.z += v.z; o.w += v.w;
    }
    *(float4*)(h + ((size_t)row << 10) + c) = o;
    if (DO_RMS) {
        float ss = o.x * o.x + o.y * o.y + o.z * o.z + o.w * o.w;
        #pragma unroll
        for (int of = 32; of; of >>= 1) ss += __shfl_xor(ss, of);
        __shared__ float sred[4];
        if ((t & 63) == 0) sred[t >> 6] = ss;
        __syncthreads();
        float tot = sred[0] + sred[1] + sred[2] + sred[3];
        float scale = rsqrtf(tot * (1.0f / DM_) + 1e-5f);
        const float* w = (row >> 10) ? w1 : w0;
        float4 wv = *(const float4*)(w + c);
        __hip_bfloat16* u = uB + ((size_t)row << 10) + c;
        u[0] = __float2bfloat16(o.x * scale * wv.x); u[1] = __float2bfloat16(o.y * scale * wv.y);
        u[2] = __float2bfloat16(o.z * scale * wv.z); u[3] = __float2bfloat16(o.w * scale * wv.w);
    }
}

// ---------------- SSM scan with fused depthwise conv: one block per (dir,b,h) ----------------
__global__ __launch_bounds__(256) void k_scan(const __hip_bfloat16* __restrict__ zx,
                                              const float* __restrict__ cw0, const float* __restrict__ cw1,
                                              const float* __restrict__ cb0, const float* __restrict__ cb1,
                                              const float* __restrict__ dtb0, const float* __restrict__ dtb1,
                                              const float* __restrict__ al0, const float* __restrict__ al1,
                                              const float* __restrict__ D0, const float* __restrict__ D1,
                                              __hip_bfloat16* __restrict__ ys) {
    __shared__ float xs[L_ * PH_];
    __shared__ float Bsh[L_ * NS_];
    __shared__ float Csh[L_ * NS_];
    __shared__ float dts[L_];
    __shared__ float dAs[L_];
    int bx = blockIdx.x;
    int dir = bx >> 8, b = (bx >> 5) & 7, h = bx & 31;
    const __hip_bfloat16* zxd = zx + (size_t)dir * 1024 * DIN_;
    const float* cw = dir ? cw1 : cw0;
    const float* cb = dir ? cb1 : cb0;
    const float* dt_bias = dir ? dtb1 : dtb0;
    const float* A_log   = dir ? al1 : al0;
    const float* Dh      = dir ? D1 : D0;
    __hip_bfloat16* ysd  = ys + (size_t)dir * 1024 * DI_;
    int t = threadIdx.x;
    for (int i = t; i < 2048; i += 256) {
        int l = i >> 4, p4 = i & 15;
        int cc = h * PH_ + p4 * 4;
        float a0 = cb[cc + 0], a1 = cb[cc + 1], a2 = cb[cc + 2], a3 = cb[cc + 3];
        #pragma unroll
        for (int k = 0; k < 4; ++k) {
            int lp = l - 3 + k;
            if (lp >= 0) {
                ushort4 raw = *(const ushort4*)(zxd + (size_t)(b * L_ + lp) * DIN_ + DI_ + cc);
                a0 += bu2f(raw.x) * cw[(cc + 0) * 4 + k];
                a1 += bu2f(raw.y) * cw[(cc + 1) * 4 + k];
                a2 += bu2f(raw.z) * cw[(cc + 2) * 4 + k];
                a3 += bu2f(raw.w) * cw[(cc + 3) * 4 + k];
            }
        }
        float* xp = &xs[l * PH_ + p4 * 4];
        xp[0] = silu_f(a0); xp[1] = silu_f(a1); xp[2] = silu_f(a2); xp[3] = silu_f(a3);
    }
    for (int i = t; i < 1024; i += 256) {
        int l = i >> 3, q4 = i & 7;
        int cc = DI_ + q4 * 4;
        float a0 = cb[cc + 0], a1 = cb[cc + 1], a2 = cb[cc + 2], a3 = cb[cc + 3];
        #pragma unroll
        for (int k = 0; k < 4; ++k) {
            int lp = l - 3 + k;
            if (lp >= 0) {
                ushort4 raw = *(const ushort4*)(zxd + (size_t)(b * L_ + lp) * DIN_ + DI_ + cc);
                a0 += bu2f(raw.x) * cw[(cc + 0) * 4 + k];
                a1 += bu2f(raw.y) * cw[(cc + 1) * 4 + k];
                a2 += bu2f(raw.z) * cw[(cc + 2) * 4 + k];
                a3 += bu2f(raw.w) * cw[(cc + 3) * 4 + k];
            }
        }
        float r0 = silu_f(a0), r1 = silu_f(a1), r2 = silu_f(a2), r3 = silu_f(a3);
        if (q4 < 4) {
            float* bp = &Bsh[l * NS_ + q4 * 4];
            bp[0] = r0; bp[1] = r1; bp[2] = r2; bp[3] = r3;
        } else {
            float* cp = &Csh[l * NS_ + (q4 - 4) * 4];
            cp[0] = r0; cp[1] = r1; cp[2] = r2; cp[3] = r3;
        }
    }
    if (t < L_) {
        float v = bu2f(*(const ushort*)(zxd + (size_t)(b * L_ + t) * DIN_ + 4128 + h)) + dt_bias[h];
        float sp = v > 20.f ? v : log1pf(expf(v));
        dts[t] = sp;
        dAs[t] = expf(-expf(A_log[h]) * sp);
    }
    __syncthreads();
    int p = t >> 2, n0 = (t & 3) * 4;
    float Dv = Dh[h];
    float s0 = 0.f, s1 = 0.f, s2 = 0.f, s3 = 0.f;
    for (int l = 0; l < L_; ++l) {
        float x = xs[l * 64 + p];
        float dAv = dAs[l];
        float xdt = x * dts[l];
        s0 = s0 * dAv + xdt * Bsh[l * 16 + n0 + 0];
        s1 = s1 * dAv + xdt * Bsh[l * 16 + n0 + 1];
        s2 = s2 * dAv + xdt * Bsh[l * 16 + n0 + 2];
        s3 = s3 * dAv + xdt * Bsh[l * 16 + n0 + 3];
        float cp = s0 * Csh[l * 16 + n0 + 0] + s1 * Csh[l * 16 + n0 + 1]
                 + s2 * Csh[l * 16 + n0 + 2] + s3 * Csh[l * 16 + n0 + 3];
        cp += __shfl_xor(cp, 1);
        cp += __shfl_xor(cp, 2);
        if ((t & 3) == 0) xs[l * 64 + p] = cp + x * Dv;
    }
    __syncthreads();
    for (int i = t; i < L_ * PH_; i += 256) {
        int l = i >> 6, pp = i & 63;
        float z = bu2f(*(const ushort*)(zxd + (size_t)(b * L_ + l) * DIN_ + h * PH_ + pp));
        ysd[((size_t)(b * L_ + l)) * DI_ + h * PH_ + pp] = __float2bfloat16(xs[i] * silu_f(z));
    }
}

// ---------------- tail ----------------
// blocks 0..63: meanctx (b, 128-chunk); blocks 64..67: aux
__global__ __launch_bounds__(256) void k_meanctx_aux(const float* __restrict__ hf, const float* __restrict__ hb,
                                                     const float* __restrict__ y_aux, const float* __restrict__ aux_w,
                                                     const float* __restrict__ aux_b, float* __restrict__ fused) {
    int bx = blockIdx.x;
    int t = threadIdx.x;
    if (bx < 64) {
        int b = bx >> 3, ch = bx & 7;
        int d4 = t & 31, lg = t >> 5;
        int d = ch * 128 + d4 * 4;
        float4 sf = {0,0,0,0}, sb = {0,0,0,0};
        for (int l = lg; l < L_; l += 8) {
            float4 a = *(const float4*)(hf + ((size_t)b * L_ + l) * DM_ + d);
            float4 c = *(const float4*)(hb + ((size_t)b * L_ + l) * DM_ + d);
            sf.x += a.x; sf.y += a.y; sf.z += a.z; sf.w += a.w;
            sb.x += c.x; sb.y += c.y; sb.z += c.z; sb.w += c.w;
        }
        __shared__ float rf[8][128], rb[8][128];
        *(float4*)&rf[lg][d4 * 4] = sf;
        *(float4*)&rb[lg][d4 * 4] = sb;
        __syncthreads();
        if (t < 128) {
            float s1 = 0.f, s2 = 0.f;
            #pragma unroll
            for (int g = 0; g < 8; ++g) { s1 += rf[g][t]; s2 += rb[g][t]; }
            fused[b * 3072 + ch * 128 + t] = s1 * (1.f / L_);
            fused[b * 3072 + DM_ + ch * 128 + t] = s2 * (1.f / L_);
        }
    } else {
        int j = (bx - 64) * 256 + t;
        if (j >= DM_) return;
        for (int b = 0; b < B_; ++b) {
            float acc = aux_b[j];
            for (int a = 0; a < 32; ++a) acc += y_aux[b * 32 + a] * aux_w[j * 32 + a];
            fused[b * 3072 + 2 * DM_ + j] = silu_f(acc);
        }
    }
}

__global__ __launch_bounds__(256) void k_basis(const float* __restrict__ x, const float* __restrict__ log_bw,
                                               float* __restrict__ basis, int Din) {
    int idx = blockIdx.x * 256 + threadIdx.x;
    if (idx >= 8 * Din) return;
    int d = idx % Din;
    float xv = x[idx];
    float bw = expf(log_bw[d]) + 1e-6f;
    float inv = 1.0f / (2.0f * bw * bw);
    #pragma unroll
    for (int g = 0; g < GG_; ++g) {
        float gg = -2.0f + g * (4.0f / 7.0f);
        float df = xv - gg;
        basis[(size_t)idx * GG_ + g] = expf(-df * df * inv);
    }
}

// ---------------- LDS-staged batched dot; y-chunks cover spline (ch<nsp) and base (ch>=nsp) ----------------
template<int MODE>
__global__ __launch_bounds__(256) void k_dotk(const float* __restrict__ Wsp, const float* __restrict__ Xsp, int Ksp,
                                              const float* __restrict__ Wb, const float* __restrict__ Xb, int Kb,
                                              const float* __restrict__ bias, float* __restrict__ out,
                                              int nsp, int nch, int Dout) {
    __shared__ float sX[8][1024];
    int ch = blockIdx.y;
    bool sp = (ch < nsp);
    const float* W = sp ? Wsp : Wb;
    const float* X = sp ? Xsp : Xb;
    int K = sp ? Ksp : Kb;
    int k0 = (sp ? ch : ch - nsp) * 1024;
    int tid = threadIdx.x;
    for (int i = tid; i < 2048; i += 256) {
        int b = i >> 8, kk = (i & 255) * 4;
        *(float4*)&sX[b][kk] = *(const float4*)(X + (size_t)b * K + k0 + kk);
    }
    __syncthreads();
    int wv = tid >> 6, lane = tid & 63;
    int rowBase = blockIdx.x * 32 + wv * 8;
    for (int j = 0; j < 8; ++j) {
        int row = rowBase + j;
        const float* wr = W + (size_t)row * K + k0;
        float acc[8] = {};
        #pragma unroll
        for (int it = 0; it < 4; ++it) {
            int k = it * 256 + lane * 4;
            float4 wvv = *(const float4*)(wr + k);
            #pragma unroll
            for (int b = 0; b < 8; ++b) {
                float4 xv = *(const float4*)&sX[b][k];
                acc[b] += wvv.x * xv.x + wvv.y * xv.y + wvv.z * xv.z + wvv.w * xv.w;
            }
        }
        float e = reduce8(acc, lane);
        if (lane < 8) {
            if (MODE == 0) {
                out[((size_t)row * nch + ch) * 8 + lane] = e;
            } else if (MODE == 1) {
                out[(size_t)lane * Dout + row] = silu_f(e + bias[row]);
            } else {
                int c = row >> 9, l = row & 511;
                out[((size_t)lane * OUTL_ + l) * COUT_ + c] = e + bias[row];
            }
        }
    }
}

// ---------------- KAN1 finalize + basis2 fused ----------------
__global__ __launch_bounds__(256) void k_fin1_basis2(const float* __restrict__ partial, const float* __restrict__ bb,
                                                     const float* __restrict__ k2_lbw,
                                                     float* __restrict__ k1, float* __restrict__ bas2) {
    int row = blockIdx.x * 256 + threadIdx.x;   // 0..2047
    if (row >= 2048) return;
    float bbv = bb[row];
    float lb = expf(k2_lbw[row]) + 1e-6f;
    float inv = 1.0f / (2.0f * lb * lb);
    #pragma unroll
    for (int b = 0; b < 8; ++b) {
        float s = bbv;
        #pragma unroll
        for (int c = 0; c < 27; ++c) s += partial[((size_t)row * 27 + c) * 8 + b];
        float v = silu_f(s);
        k1[(size_t)b * 2048 + row] = v;
        #pragma unroll
        for (int g = 0; g < GG_; ++g) {
            float gg = -2.0f + g * (4.0f / 7.0f);
            float df = v - gg;
            bas2[((size_t)b * 2048 + row) * GG_ + g] = expf(-df * df * inv);
        }
    }
}

template<int NCH>
__global__ __launch_bounds__(256) void k_dot_fin(const float* __restrict__ partial, const float* __restrict__ base_b,
                                                 float* __restrict__ out, int Dout) {
    int row = blockIdx.x * 256 + threadIdx.x;
    if (row >= Dout) return;
    float bb = base_b[row];
    #pragma unroll
    for (int b = 0; b < 8; ++b) {
        float s = bb;
        #pragma unroll
        for (int c = 0; c < NCH; ++c) s += partial[((size_t)row * NCH + c) * 8 + b];
        out[(size_t)b * Dout + row] = silu_f(s);
    }
}

// ---------------- launch ----------------
extern "C" void kernel_launch(void* const* d_in, const int* in_sizes, int n_in,
                              void* d_out, int out_size, void* d_ws, size_t ws_size,
                              hipStream_t stream) {
    const float* x_prefix = (const float*)d_in[0];
    const float* y_aux    = (const float*)d_in[1];
    const float* pre_w    = (const float*)d_in[2];
    const float* pre_b    = (const float*)d_in[3];
    const float* patch_w  = (const float*)d_in[4];
    const float* patch_b  = (const float*)d_in[5];
    const float* norm_w[2] = {(const float*)d_in[6],  (const float*)d_in[14]};
    const float* in_w[2]   = {(const float*)d_in[7],  (const float*)d_in[15]};
    const float* conv_w[2] = {(const float*)d_in[8],  (const float*)d_in[16]};
    const float* conv_b[2] = {(const float*)d_in[9],  (const float*)d_in[17]};
    const float* A_log[2]  = {(const float*)d_in[10], (const float*)d_in[18]};
    const float* Dvec[2]   = {(const float*)d_in[11], (const float*)d_in[19]};
    const float* dt_b[2]   = {(const float*)d_in[12], (const float*)d_in[20]};
    const float* out_w[2]  = {(const float*)d_in[13], (const float*)d_in[21]};
    const float* aux_w = (const float*)d_in[22];
    const float* aux_b = (const float*)d_in[23];
    const float* k1_lbw = (const float*)d_in[24];
    const float* k1_bw  = (const float*)d_in[25];
    const float* k1_bb  = (const float*)d_in[26];
    const float* k1_sw  = (const float*)d_in[27];
    const float* k2_lbw = (const float*)d_in[28];
    const float* k2_bw  = (const float*)d_in[29];
    const float* k2_bb  = (const float*)d_in[30];
    const float* k2_sw  = (const float*)d_in[31];
    const float* sh_w = (const float*)d_in[32];
    const float* sh_b = (const float*)d_in[33];
    const float* hw   = (const float*)d_in[34];
    const float* hbias= (const float*)d_in[35];
    float* ws = (float*)d_ws;
    float* out = (float*)d_out;

    // workspace (float units)
    // stage overlay [0 .. 9,863,168): ApreB / wpreTB / x1B / wpatchTB; mamba overlay reuses it.
    const size_t o_ApreB   = 0;
    const size_t o_wpreTB  = 1310720;
    const size_t o_x1B     = 1474560;
    const size_t o_wpatchTB= 5668864;
    const size_t o_uB   = 0;              // bf16 2x1024x1024
    const size_t o_zxB  = 1048576;        // bf16 2x1024x4160 -> ends 5,308,416
    const size_t o_ysB  = 5308416;        // bf16 2x1024x2048 -> ends 7,405,568
    // persistent:
    const size_t o_hf   = 9863168;        // f32 1024x1024
    const size_t o_hb   = 10911744;       // f32 1024x1024 (contiguous)
    const size_t o_wBBa = 11960320;       // bf16 4x2x4224x1024 -> 17,301,504 f -> ends 29,261,824
    const size_t o_wOBa = 29261824;       // bf16 4x2x2048x1024 -> 8,388,608 f -> ends 37,650,432
    const size_t o_spart= 37650432;       // f32 8x1024x1024 -> ends 46,039,040
    const size_t total_f = 46039040;      // ~184 MB
    // tail overlay (in the dead mamba region):
    const size_t o_f1   = 0;
    const size_t o_bas1 = 24576;
    const size_t o_k1   = 221184;
    const size_t o_bas2 = 237568;
    const size_t o_k2   = 368640;
    const size_t o_f4   = 376832;
    const size_t o_part = 385024;         // 2048*27*8 -> ends 827,392
    if (ws_size < total_f * sizeof(float)) return;

    __hip_bfloat16* ApreB   = (__hip_bfloat16*)(ws + o_ApreB);
    __hip_bfloat16* wpreTB  = (__hip_bfloat16*)(ws + o_wpreTB);
    __hip_bfloat16* x1B     = (__hip_bfloat16*)(ws + o_x1B);
    __hip_bfloat16* wpatchTB= (__hip_bfloat16*)(ws + o_wpatchTB);
    __hip_bfloat16* uB      = (__hip_bfloat16*)(ws + o_uB);
    __hip_bfloat16* zxB     = (__hip_bfloat16*)(ws + o_zxB);
    __hip_bfloat16* ysB     = (__hip_bfloat16*)(ws + o_ysB);
    __hip_bfloat16* wBBa    = (__hip_bfloat16*)(ws + o_wBBa);
    __hip_bfloat16* wOBa    = (__hip_bfloat16*)(ws + o_wOBa);
    float* hf = ws + o_hf;
    float* hb = ws + o_hb;

    // All-layer weight conversion (one dispatch) + merged stage prep
    k_cvt_all<<<50176, 256, 0, stream>>>(in_w[0], in_w[1], out_w[0], out_w[1], wBBa, wOBa);
    k_prep<<<44288, 256, 0, stream>>>(pre_w, patch_w, x_prefix, wpreTB, wpatchTB, ApreB);
    // pre-conv GEMM (silu) -> x1B
    k_gemm_mfma<128,128><<<dim3(8, 64, 1), 256, 0, stream>>>(
        (const ushort*)ApreB, (const ushort*)wpreTB, pre_b, nullptr, x1B,
        320, 320, 1024, 1024, 1, 1, 0, 0, 0);
    // patch GEMM split-K=8 -> partials -> finalize + first rmsnorm
    k_gemm_mfma<128,128><<<dim3(8, 8, 8), 256, 0, stream>>>(
        (const ushort*)x1B, (const ushort*)wpatchTB, nullptr, ws + o_spart, nullptr,
        1024, 8192, 1024, 1024, 2, 8, 0, 0, (long)1024 * 1024);
    k_patch_fin_rms<<<1024, 256, 0, stream>>>(ws + o_spart, patch_b, norm_w[0], norm_w[1], hf, hb, uB);

    // Mamba stacks (both dirs batched)
    for (int i = 0; i < NL_; ++i) {
        k_gemm_mfma<128,128><<<dim3(33, 8, 2), 256, 0, stream>>>(
            (const ushort*)uB, (const ushort*)(wBBa + (size_t)i * 2 * NPAD_ * 1024), nullptr, nullptr, zxB,
            1024, 1024, DIN_, DIN_, 0, 1, (long)1024 * 1024, (long)NPAD_ * 1024, (long)1024 * DIN_);
        k_scan<<<512, 256, 0, stream>>>(zxB,
            conv_w[0] + (size_t)i * CONVD_ * 4, conv_w[1] + (size_t)i * CONVD_ * 4,
            conv_b[0] + (size_t)i * CONVD_, conv_b[1] + (size_t)i * CONVD_,
            dt_b[0] + i * NH_, dt_b[1] + i * NH_, A_log[0] + i * NH_, A_log[1] + i * NH_,
            Dvec[0] + i * NH_, Dvec[1] + i * NH_, ysB);
        k_gemm_mfma<128,128><<<dim3(8, 8, 8), 256, 0, stream>>>(
            (const ushort*)ysB, (const ushort*)(wOBa + (size_t)i * 2 * 2048 * 1024), nullptr, ws + o_spart, nullptr,
            512, 2048, 1024, 1024, 2, 4, (long)1024 * 2048, (long)2048 * 1024, (long)1024 * 1024);
        if (i + 1 < NL_) {
            k_oproj_fin_rms<true><<<2048, 256, 0, stream>>>(ws + o_spart,
                norm_w[0] + (size_t)(i + 1) * DM_, norm_w[1] + (size_t)(i + 1) * DM_, hf, uB);
        } else {
            k_oproj_fin_rms<false><<<2048, 256, 0, stream>>>(ws + o_spart, nullptr, nullptr, hf, nullptr);
        }
    }

    // Tail
    k_meanctx_aux<<<68, 256, 0, stream>>>(hf, hb, y_aux, aux_w, aux_b, ws + o_f1);
    k_basis<<<96, 256, 0, stream>>>(ws + o_f1, k1_lbw, ws + o_bas1, 3072);
    k_dotk<0><<<dim3(64, 27), 256, 0, stream>>>(k1_sw, ws + o_bas1, 24576, k1_bw, ws + o_f1, 3072,
                                                nullptr, ws + o_part, 24, 27, 2048);
    k_fin1_basis2<<<8, 256, 0, stream>>>(ws + o_part, k1_bb, k2_lbw, ws + o_k1, ws + o_bas2);
    k_dotk<0><<<dim3(32, 18), 256, 0, stream>>>(k2_sw, ws + o_bas2, 16384, k2_bw, ws + o_k1, 2048,
                                                nullptr, ws + o_part, 16, 18, 1024);
    k_dot_fin<18><<<4, 256, 0, stream>>>(ws + o_part, k2_bb, ws + o_k2, 1024);
    k_dotk<1><<<dim3(32, 1), 256, 0, stream>>>(nullptr, nullptr, 0, sh_w, ws + o_k2, 1024,
                                               sh_b, ws + o_f4, 0, 1, 1024);
    k_dotk<2><<<dim3(1024, 1), 256, 0, stream>>>(nullptr, nullptr, 0, hw, ws + o_f4, 1024,
                                                 hbias, out, 0, 1, 32768);
}

// Round 8
// 856.401 us; speedup vs baseline: 1.7156x; 1.0311x over previous
//
#include <hip/hip_runtime.h>
#include <hip/hip_bf16.h>
#include <math.h>

#define B_    8
#define LP_   1024
#define CIN_  64
#define DM_   1024
#define DI_   2048
#define NS_   16
#define PH_   64
#define NH_   32
#define NL_   4
#define GG_   8
#define KH_   2048
#define DIN_  4160
#define NPAD_ 4224
#define CONVD_ 2080
#define L_    128
#define R_    1024
#define OUTL_ 512
#define COUT_ 64

typedef __bf16 bf16x8 __attribute__((ext_vector_type(8)));
typedef float f32x4 __attribute__((ext_vector_type(4)));
typedef unsigned short ushort;

__device__ __forceinline__ float silu_f(float x) { return x / (1.0f + expf(-x)); }

__device__ __forceinline__ ushort f2bu(float x) {
    union { __hip_bfloat16 h; ushort u; } c; c.h = __float2bfloat16(x); return c.u;
}
__device__ __forceinline__ float bu2f(ushort u) {
    union { ushort u; __hip_bfloat16 h; } c; c.u = u; return __bfloat162float(c.h);
}

__device__ __forceinline__ void gload_lds16(const void* g, void* l) {
    __builtin_amdgcn_global_load_lds((const __attribute__((address_space(1))) unsigned int*)g,
                                     (__attribute__((address_space(3))) unsigned int*)l, 16, 0, 0);
}

// pair-merge reduce: 8 accumulators x 64 lanes -> lane (l&7) holds full sum of acc[l&7]
__device__ __forceinline__ float merge2(float a, float b, int mask, int lane) {
    float x = (lane & mask) ? b : a;
    float y = (lane & mask) ? a : b;
    return x + __shfl_xor(y, mask);
}
__device__ __forceinline__ float reduce8(float* a, int lane) {
    float c0 = merge2(a[0], a[1], 1, lane);
    float c1 = merge2(a[2], a[3], 1, lane);
    float c2 = merge2(a[4], a[5], 1, lane);
    float c3 = merge2(a[6], a[7], 1, lane);
    float d0 = merge2(c0, c1, 2, lane);
    float d1 = merge2(c2, c3, 2, lane);
    float e  = merge2(d0, d1, 4, lane);
    e += __shfl_xor(e, 8);
    e += __shfl_xor(e, 16);
    e += __shfl_xor(e, 32);
    return e;
}

// ---------------- merged conversion + prep (one dispatch) ----------------
#define CVT_IN_T4  1081344   // NPAD_*1024/4
#define CVT_OUT_T4 524288    // 1024*2048/4
#define CVT_PER    1605632
#define CVT_TOT    12845056  // 8*CVT_PER
#define PREP_W1 327680       // DM_*320
#define PREP_W2 8388608      // DM_*8192
#define PREP_W3 2621440      // 8192*320
#define PREP_TOT 11337728
__global__ __launch_bounds__(256) void k_cvt_prep(
    const float* __restrict__ in0, const float* __restrict__ in1,
    const float* __restrict__ o0, const float* __restrict__ o1,
    __hip_bfloat16* __restrict__ wBBa, __hip_bfloat16* __restrict__ wOBa,
    const float* __restrict__ pre_w, const float* __restrict__ patch_w, const float* __restrict__ xp,
    __hip_bfloat16* __restrict__ wpreT, __hip_bfloat16* __restrict__ wpatchT, __hip_bfloat16* __restrict__ Apre)
{
    int gi = blockIdx.x * 256 + threadIdx.x;
    if (gi < CVT_TOT) {
        int ld = gi / CVT_PER;
        int r = gi - ld * CVT_PER;
        int l = ld >> 1, d = ld & 1;
        const float* inw  = (d ? in1 : in0) + (size_t)l * DIN_ * DM_;
        const float* outw = (d ? o1 : o0) + (size_t)l * DM_ * DI_;
        if (r < CVT_IN_T4) {
            int idx = r * 4; int row = idx >> 10;
            __hip_bfloat16* dst = wBBa + (size_t)ld * NPAD_ * 1024 + idx;
            if (row < DIN_) {
                float4 v = *(const float4*)(inw + idx);
                dst[0] = __float2bfloat16(v.x); dst[1] = __float2bfloat16(v.y);
                dst[2] = __float2bfloat16(v.z); dst[3] = __float2bfloat16(v.w);
            } else {
                dst[0] = __float2bfloat16(0.f); dst[1] = __float2bfloat16(0.f);
                dst[2] = __float2bfloat16(0.f); dst[3] = __float2bfloat16(0.f);
            }
        } else {
            int idx = (r - CVT_IN_T4) * 4;
            __hip_bfloat16* dst = wOBa + (size_t)ld * 2048 * 1024 + idx;
            float4 v = *(const float4*)(outw + idx);
            dst[0] = __float2bfloat16(v.x); dst[1] = __float2bfloat16(v.y);
            dst[2] = __float2bfloat16(v.z); dst[3] = __float2bfloat16(v.w);
        }
        return;
    }
    int idx = gi - CVT_TOT;
    if (idx < PREP_W1) {
        int d = idx / 320, kk = idx % 320;
        int kp = kk >> 6, c = kk & 63;
        wpreT[idx] = __float2bfloat16(pre_w[(d * CIN_ + c) * 5 + kp]);
    } else if (idx < PREP_W1 + PREP_W2) {
        int i = idx - PREP_W1;
        int d = i >> 13, kk = i & 8191;
        int kp = kk >> 10, din = kk & 1023;
        wpatchT[i] = __float2bfloat16(patch_w[((size_t)d << 13) + din * 8 + kp]);
    } else if (idx < PREP_TOT) {
        int i = idx - PREP_W1 - PREP_W2;
        int kk = i % 320; int r = i / 320;
        int l = r & 1023, b = r >> 10;
        int kp = kk >> 6, c = kk & 63;
        int lp = l + kp - 2;
        float v = 0.f;
        if (lp >= 0 && lp < LP_) v = xp[((size_t)b * LP_ + lp) * CIN_ + c];
        Apre[i] = __float2bfloat16(v);
    }
}

// ---------------- bf16 MFMA GEMM, 128^2 tile, 8 waves (512 thr), 2-phase dbuf, optional split-K ----------------
// z -> (dir = z/nsplit, ks = z%nsplit); kbase = ks*Kc. act: 0 bf16 store(+bias), 1 bf16 silu(+bias),
// 2 raw f32 split-K partial to Cf + z*sC.
template<int BM, int BN>
__global__ __launch_bounds__(512) void k_gemm_mfma(
    const ushort* __restrict__ A, const ushort* __restrict__ B,
    const float* __restrict__ bias,
    float* __restrict__ Cf, __hip_bfloat16* __restrict__ Cb,
    int Kc, int ldk, int ldc, int Nstore, int act, int nsplit,
    long sA, long sB, long sC)
{
    constexpr int BK = 32;
    constexpr int WM = 64, WN = 32;           // 2x4 waves cover 128x128
    constexpr int MR = WM / 16, NR = WN / 16; // 4 x 2
    constexpr int ACH = BM * 4, BCH = BN * 4;
    __shared__ ushort sAs[2][BM * BK];
    __shared__ ushort sBs[2][BN * BK];
    int tid = threadIdx.x;
    int lane = tid & 63, w = tid >> 6;        // 8 waves
    int wr = w >> 2, wc = w & 3;
    int z = blockIdx.z;
    int dir = z / nsplit, ks = z - dir * nsplit;
    int kbase = ks * Kc;
    int m0 = blockIdx.y * BM, n0 = blockIdx.x * BN;
    const ushort* Az = A + (size_t)dir * sA + kbase;
    const ushort* Bz = B + (size_t)dir * sB + kbase;

    auto STAGE = [&](int buf, int k0) {
        #pragma unroll
        for (int c = tid; c < ACH; c += 512) {
            int row = c >> 2, col = (c & 3) * 8;
            gload_lds16(Az + (size_t)(m0 + row) * ldk + k0 + col, (char*)&sAs[buf][0] + c * 16);
        }
        #pragma unroll
        for (int c = tid; c < BCH; c += 512) {
            int row = c >> 2, col = (c & 3) * 8;
            gload_lds16(Bz + (size_t)(n0 + row) * ldk + k0 + col, (char*)&sBs[buf][0] + c * 16);
        }
    };

    f32x4 acc[MR][NR] = {};
    const int NT = Kc / BK;
    STAGE(0, 0);
    __syncthreads();
    int cur = 0;
    for (int t = 0; t < NT; ++t) {
        if (t + 1 < NT) STAGE(cur ^ 1, (t + 1) * BK);   // in flight during compute
        bf16x8 af[MR], bfr[NR];
        #pragma unroll
        for (int m = 0; m < MR; ++m)
            af[m] = *(const bf16x8*)&sAs[cur][(wr * WM + m * 16 + (lane & 15)) * BK + (lane >> 4) * 8];
        #pragma unroll
        for (int n = 0; n < NR; ++n)
            bfr[n] = *(const bf16x8*)&sBs[cur][(wc * WN + n * 16 + (lane & 15)) * BK + (lane >> 4) * 8];
        #pragma unroll
        for (int m = 0; m < MR; ++m)
            #pragma unroll
            for (int n = 0; n < NR; ++n)
                acc[m][n] = __builtin_amdgcn_mfma_f32_16x16x32_bf16(af[m], bfr[n], acc[m][n], 0, 0, 0);
        __syncthreads();    // implicit vmcnt(0): next tile landed, cur fully consumed
        cur ^= 1;
    }
    #pragma unroll
    for (int m = 0; m < MR; ++m) {
        int row = m0 + wr * WM + m * 16 + (lane >> 4) * 4;
        #pragma unroll
        for (int n = 0; n < NR; ++n) {
            int col = n0 + wc * WN + n * 16 + (lane & 15);
            if (col < Nstore) {
                if (act == 2) {
                    float* Cfz = Cf + (size_t)z * sC;
                    #pragma unroll
                    for (int j = 0; j < 4; ++j)
                        Cfz[(size_t)(row + j) * ldc + col] = acc[m][n][j];
                } else {
                    __hip_bfloat16* Cbz = Cb + (size_t)dir * sC;
                    float bv = bias ? bias[col] : 0.f;
                    #pragma unroll
                    for (int j = 0; j < 4; ++j) {
                        float v = acc[m][n][j] + bv;
                        if (act == 1) v = silu_f(v);
                        Cbz[(size_t)(row + j) * ldc + col] = __float2bfloat16(v);
                    }
                }
            }
        }
    }
}

// ---------------- patch finalize + first rmsnorm: one block per hf row ----------------
__global__ __launch_bounds__(256) void k_patch_fin_rms(const float* __restrict__ part, const float* __restrict__ bias,
                                                       const float* __restrict__ w0, const float* __restrict__ w1,
                                                       float* __restrict__ hf, float* __restrict__ hb,
                                                       __hip_bfloat16* __restrict__ uB) {
    int r = blockIdx.x;          // 0..1023
    int t = threadIdx.x;
    int c = t * 4;
    float4 o = *(const float4*)(bias + c);
    #pragma unroll
    for (int s = 0; s < 8; ++s) {
        float4 v = *(const float4*)(part + (size_t)s * 1048576 + ((size_t)r << 10) + c);
        o.x += v.x; o.y += v.y; o.z += v.z; o.w += v.w;
    }
    *(float4*)(hf + ((size_t)r << 10) + c) = o;
    int rb = r ^ 127;
    *(float4*)(hb + ((size_t)rb << 10) + c) = o;
    float ss = o.x * o.x + o.y * o.y + o.z * o.z + o.w * o.w;
    #pragma unroll
    for (int of = 32; of; of >>= 1) ss += __shfl_xor(ss, of);
    __shared__ float sred[4];
    if ((t & 63) == 0) sred[t >> 6] = ss;
    __syncthreads();
    float tot = sred[0] + sred[1] + sred[2] + sred[3];
    float scale = rsqrtf(tot * (1.0f / DM_) + 1e-5f);
    float4 wf = *(const float4*)(w0 + c);
    float4 wb = *(const float4*)(w1 + c);
    __hip_bfloat16* uf = uB + ((size_t)r << 10) + c;
    __hip_bfloat16* ub = uB + ((size_t)(1024 + rb) << 10) + c;
    uf[0] = __float2bfloat16(o.x * scale * wf.x); uf[1] = __float2bfloat16(o.y * scale * wf.y);
    uf[2] = __float2bfloat16(o.z * scale * wf.z); uf[3] = __float2bfloat16(o.w * scale * wf.w);
    ub[0] = __float2bfloat16(o.x * scale * wb.x); ub[1] = __float2bfloat16(o.y * scale * wb.y);
    ub[2] = __float2bfloat16(o.z * scale * wb.z); ub[3] = __float2bfloat16(o.w * scale * wb.w);
}

// ---------------- out-proj finalize (+residual) + next rmsnorm: one block per h row (2048) ----------------
template<bool DO_RMS>
__global__ __launch_bounds__(256) void k_oproj_fin_rms(const float* __restrict__ part,
                                                       const float* __restrict__ w0, const float* __restrict__ w1,
                                                       float* __restrict__ h, __hip_bfloat16* __restrict__ uB) {
    int row = blockIdx.x;        // 0..2047 (dir = row>>10)
    int t = threadIdx.x;
    int c = t * 4;
    const float* p = part + (size_t)(row >> 10) * 4194304 + (size_t)(row & 1023) * 1024 + c;
    float4 o = *(const float4*)(h + ((size_t)row << 10) + c);
    #pragma unroll
    for (int s = 0; s < 4; ++s) {
        float4 v = *(const float4*)(p + (size_t)s * 1048576);
        o.x += v.x; o.y += v.y; o.z += v.z; o.w += v.w;
    }
    *(float4*)(h + ((size_t)row << 10) + c) = o;
    if (DO_RMS) {
        float ss = o.x * o.x + o.y * o.y + o.z * o.z + o.w * o.w;
        #pragma unroll
        for (int of = 32; of; of >>= 1) ss += __shfl_xor(ss, of);
        __shared__ float sred[4];
        if ((t & 63) == 0) sred[t >> 6] = ss;
        __syncthreads();
        float tot = sred[0] + sred[1] + sred[2] + sred[3];
        float scale = rsqrtf(tot * (1.0f / DM_) + 1e-5f);
        const float* w = (row >> 10) ? w1 : w0;
        float4 wv = *(const float4*)(w + c);
        __hip_bfloat16* u = uB + ((size_t)row << 10) + c;
        u[0] = __float2bfloat16(o.x * scale * wv.x); u[1] = __float2bfloat16(o.y * scale * wv.y);
        u[2] = __float2bfloat16(o.z * scale * wv.z); u[3] = __float2bfloat16(o.w * scale * wv.w);
    }
}

// ---------------- SSM scan with fused depthwise conv: one block per (dir,b,h) ----------------
__global__ __launch_bounds__(256) void k_scan(const __hip_bfloat16* __restrict__ zx,
                                              const float* __restrict__ cw0, const float* __restrict__ cw1,
                                              const float* __restrict__ cb0, const float* __restrict__ cb1,
                                              const float* __restrict__ dtb0, const float* __restrict__ dtb1,
                                              const float* __restrict__ al0, const float* __restrict__ al1,
                                              const float* __restrict__ D0, const float* __restrict__ D1,
                                              __hip_bfloat16* __restrict__ ys) {
    __shared__ float xs[L_ * PH_];
    __shared__ float Bsh[L_ * NS_];
    __shared__ float Csh[L_ * NS_];
    __shared__ float dts[L_];
    __shared__ float dAs[L_];
    int bx = blockIdx.x;
    int dir = bx >> 8, b = (bx >> 5) & 7, h = bx & 31;
    const __hip_bfloat16* zxd = zx + (size_t)dir * 1024 * DIN_;
    const float* cw = dir ? cw1 : cw0;
    const float* cb = dir ? cb1 : cb0;
    const float* dt_bias = dir ? dtb1 : dtb0;
    const float* A_log   = dir ? al1 : al0;
    const float* Dh      = dir ? D1 : D0;
    __hip_bfloat16* ysd  = ys + (size_t)dir * 1024 * DI_;
    int t = threadIdx.x;
    for (int i = t; i < 2048; i += 256) {
        int l = i >> 4, p4 = i & 15;
        int cc = h * PH_ + p4 * 4;
        float a0 = cb[cc + 0], a1 = cb[cc + 1], a2 = cb[cc + 2], a3 = cb[cc + 3];
        #pragma unroll
        for (int k = 0; k < 4; ++k) {
            int lp = l - 3 + k;
            if (lp >= 0) {
                ushort4 raw = *(const ushort4*)(zxd + (size_t)(b * L_ + lp) * DIN_ + DI_ + cc);
                a0 += bu2f(raw.x) * cw[(cc + 0) * 4 + k];
                a1 += bu2f(raw.y) * cw[(cc + 1) * 4 + k];
                a2 += bu2f(raw.z) * cw[(cc + 2) * 4 + k];
                a3 += bu2f(raw.w) * cw[(cc + 3) * 4 + k];
            }
        }
        float* xp = &xs[l * PH_ + p4 * 4];
        xp[0] = silu_f(a0); xp[1] = silu_f(a1); xp[2] = silu_f(a2); xp[3] = silu_f(a3);
    }
    for (int i = t; i < 1024; i += 256) {
        int l = i >> 3, q4 = i & 7;
        int cc = DI_ + q4 * 4;
        float a0 = cb[cc + 0], a1 = cb[cc + 1], a2 = cb[cc + 2], a3 = cb[cc + 3];
        #pragma unroll
        for (int k = 0; k < 4; ++k) {
            int lp = l - 3 + k;
            if (lp >= 0) {
                ushort4 raw = *(const ushort4*)(zxd + (size_t)(b * L_ + lp) * DIN_ + DI_ + cc);
                a0 += bu2f(raw.x) * cw[(cc + 0) * 4 + k];
                a1 += bu2f(raw.y) * cw[(cc + 1) * 4 + k];
                a2 += bu2f(raw.z) * cw[(cc + 2) * 4 + k];
                a3 += bu2f(raw.w) * cw[(cc + 3) * 4 + k];
            }
        }
        float r0 = silu_f(a0), r1 = silu_f(a1), r2 = silu_f(a2), r3 = silu_f(a3);
        if (q4 < 4) {
            float* bp = &Bsh[l * NS_ + q4 * 4];
            bp[0] = r0; bp[1] = r1; bp[2] = r2; bp[3] = r3;
        } else {
            float* cp = &Csh[l * NS_ + (q4 - 4) * 4];
            cp[0] = r0; cp[1] = r1; cp[2] = r2; cp[3] = r3;
        }
    }
    if (t < L_) {
        float v = bu2f(*(const ushort*)(zxd + (size_t)(b * L_ + t) * DIN_ + 4128 + h)) + dt_bias[h];
        float sp = v > 20.f ? v : log1pf(expf(v));
        dts[t] = sp;
        dAs[t] = expf(-expf(A_log[h]) * sp);
    }
    __syncthreads();
    int p = t >> 2, n0 = (t & 3) * 4;
    float Dv = Dh[h];
    float s0 = 0.f, s1 = 0.f, s2 = 0.f, s3 = 0.f;
    for (int l = 0; l < L_; ++l) {
        float x = xs[l * 64 + p];
        float dAv = dAs[l];
        float xdt = x * dts[l];
        s0 = s0 * dAv + xdt * Bsh[l * 16 + n0 + 0];
        s1 = s1 * dAv + xdt * Bsh[l * 16 + n0 + 1];
        s2 = s2 * dAv + xdt * Bsh[l * 16 + n0 + 2];
        s3 = s3 * dAv + xdt * Bsh[l * 16 + n0 + 3];
        float cp = s0 * Csh[l * 16 + n0 + 0] + s1 * Csh[l * 16 + n0 + 1]
                 + s2 * Csh[l * 16 + n0 + 2] + s3 * Csh[l * 16 + n0 + 3];
        cp += __shfl_xor(cp, 1);
        cp += __shfl_xor(cp, 2);
        if ((t & 3) == 0) xs[l * 64 + p] = cp + x * Dv;
    }
    __syncthreads();
    for (int i = t; i < L_ * PH_; i += 256) {
        int l = i >> 6, pp = i & 63;
        float z = bu2f(*(const ushort*)(zxd + (size_t)(b * L_ + l) * DIN_ + h * PH_ + pp));
        ysd[((size_t)(b * L_ + l)) * DI_ + h * PH_ + pp] = __float2bfloat16(xs[i] * silu_f(z));
    }
}

// ---------------- tail ----------------
__global__ __launch_bounds__(256) void k_meanctx_aux(const float* __restrict__ hf, const float* __restrict__ hb,
                                                     const float* __restrict__ y_aux, const float* __restrict__ aux_w,
                                                     const float* __restrict__ aux_b, float* __restrict__ fused) {
    int bx = blockIdx.x;
    int t = threadIdx.x;
    if (bx < 64) {
        int b = bx >> 3, ch = bx & 7;
        int d4 = t & 31, lg = t >> 5;
        int d = ch * 128 + d4 * 4;
        float4 sf = {0,0,0,0}, sb = {0,0,0,0};
        for (int l = lg; l < L_; l += 8) {
            float4 a = *(const float4*)(hf + ((size_t)b * L_ + l) * DM_ + d);
            float4 c = *(const float4*)(hb + ((size_t)b * L_ + l) * DM_ + d);
            sf.x += a.x; sf.y += a.y; sf.z += a.z; sf.w += a.w;
            sb.x += c.x; sb.y += c.y; sb.z += c.z; sb.w += c.w;
        }
        __shared__ float rf[8][128], rb[8][128];
        *(float4*)&rf[lg][d4 * 4] = sf;
        *(float4*)&rb[lg][d4 * 4] = sb;
        __syncthreads();
        if (t < 128) {
            float s1 = 0.f, s2 = 0.f;
            #pragma unroll
            for (int g = 0; g < 8; ++g) { s1 += rf[g][t]; s2 += rb[g][t]; }
            fused[b * 3072 + ch * 128 + t] = s1 * (1.f / L_);
            fused[b * 3072 + DM_ + ch * 128 + t] = s2 * (1.f / L_);
        }
    } else {
        int j = (bx - 64) * 256 + t;
        if (j >= DM_) return;
        for (int b = 0; b < B_; ++b) {
            float acc = aux_b[j];
            for (int a = 0; a < 32; ++a) acc += y_aux[b * 32 + a] * aux_w[j * 32 + a];
            fused[b * 3072 + 2 * DM_ + j] = silu_f(acc);
        }
    }
}

__global__ __launch_bounds__(256) void k_basis(const float* __restrict__ x, const float* __restrict__ log_bw,
                                               float* __restrict__ basis, int Din) {
    int idx = blockIdx.x * 256 + threadIdx.x;
    if (idx >= 8 * Din) return;
    int d = idx % Din;
    float xv = x[idx];
    float bw = expf(log_bw[d]) + 1e-6f;
    float inv = 1.0f / (2.0f * bw * bw);
    #pragma unroll
    for (int g = 0; g < GG_; ++g) {
        float gg = -2.0f + g * (4.0f / 7.0f);
        float df = xv - gg;
        basis[(size_t)idx * GG_ + g] = expf(-df * df * inv);
    }
}

// ---------------- LDS-staged batched dot; y-chunks cover spline (ch<nsp) and base (ch>=nsp) ----------------
template<int MODE>
__global__ __launch_bounds__(256) void k_dotk(const float* __restrict__ Wsp, const float* __restrict__ Xsp, int Ksp,
                                              const float* __restrict__ Wb, const float* __restrict__ Xb, int Kb,
                                              const float* __restrict__ bias, float* __restrict__ out,
                                              int nsp, int nch, int Dout) {
    __shared__ float sX[8][1024];
    int ch = blockIdx.y;
    bool sp = (ch < nsp);
    const float* W = sp ? Wsp : Wb;
    const float* X = sp ? Xsp : Xb;
    int K = sp ? Ksp : Kb;
    int k0 = (sp ? ch : ch - nsp) * 1024;
    int tid = threadIdx.x;
    for (int i = tid; i < 2048; i += 256) {
        int b = i >> 8, kk = (i & 255) * 4;
        *(float4*)&sX[b][kk] = *(const float4*)(X + (size_t)b * K + k0 + kk);
    }
    __syncthreads();
    int wv = tid >> 6, lane = tid & 63;
    int rowBase = blockIdx.x * 32 + wv * 8;
    for (int j = 0; j < 8; ++j) {
        int row = rowBase + j;
        const float* wr = W + (size_t)row * K + k0;
        float acc[8] = {};
        #pragma unroll
        for (int it = 0; it < 4; ++it) {
            int k = it * 256 + lane * 4;
            float4 wvv = *(const float4*)(wr + k);
            #pragma unroll
            for (int b = 0; b < 8; ++b) {
                float4 xv = *(const float4*)&sX[b][k];
                acc[b] += wvv.x * xv.x + wvv.y * xv.y + wvv.z * xv.z + wvv.w * xv.w;
            }
        }
        float e = reduce8(acc, lane);
        if (lane < 8) {
            if (MODE == 0) {
                out[((size_t)row * nch + ch) * 8 + lane] = e;
            } else if (MODE == 1) {
                out[(size_t)lane * Dout + row] = silu_f(e + bias[row]);
            } else {
                int c = row >> 9, l = row & 511;
                out[((size_t)lane * OUTL_ + l) * COUT_ + c] = e + bias[row];
            }
        }
    }
}

// ---------------- KAN1 finalize + basis2 fused ----------------
__global__ __launch_bounds__(256) void k_fin1_basis2(const float* __restrict__ partial, const float* __restrict__ bb,
                                                     const float* __restrict__ k2_lbw,
                                                     float* __restrict__ k1, float* __restrict__ bas2) {
    int row = blockIdx.x * 256 + threadIdx.x;   // 0..2047
    if (row >= 2048) return;
    float bbv = bb[row];
    float lb = expf(k2_lbw[row]) + 1e-6f;
    float inv = 1.0f / (2.0f * lb * lb);
    #pragma unroll
    for (int b = 0; b < 8; ++b) {
        float s = bbv;
        #pragma unroll
        for (int c = 0; c < 27; ++c) s += partial[((size_t)row * 27 + c) * 8 + b];
        float v = silu_f(s);
        k1[(size_t)b * 2048 + row] = v;
        #pragma unroll
        for (int g = 0; g < GG_; ++g) {
            float gg = -2.0f + g * (4.0f / 7.0f);
            float df = v - gg;
            bas2[((size_t)b * 2048 + row) * GG_ + g] = expf(-df * df * inv);
        }
    }
}

template<int NCH>
__global__ __launch_bounds__(256) void k_dot_fin(const float* __restrict__ partial, const float* __restrict__ base_b,
                                                 float* __restrict__ out, int Dout) {
    int row = blockIdx.x * 256 + threadIdx.x;
    if (row >= Dout) return;
    float bb = base_b[row];
    #pragma unroll
    for (int b = 0; b < 8; ++b) {
        float s = bb;
        #pragma unroll
        for (int c = 0; c < NCH; ++c) s += partial[((size_t)row * NCH + c) * 8 + b];
        out[(size_t)b * Dout + row] = silu_f(s);
    }
}

// ---------------- launch ----------------
extern "C" void kernel_launch(void* const* d_in, const int* in_sizes, int n_in,
                              void* d_out, int out_size, void* d_ws, size_t ws_size,
                              hipStream_t stream) {
    const float* x_prefix = (const float*)d_in[0];
    const float* y_aux    = (const float*)d_in[1];
    const float* pre_w    = (const float*)d_in[2];
    const float* pre_b    = (const float*)d_in[3];
    const float* patch_w  = (const float*)d_in[4];
    const float* patch_b  = (const float*)d_in[5];
    const float* norm_w[2] = {(const float*)d_in[6],  (const float*)d_in[14]};
    const float* in_w[2]   = {(const float*)d_in[7],  (const float*)d_in[15]};
    const float* conv_w[2] = {(const float*)d_in[8],  (const float*)d_in[16]};
    const float* conv_b[2] = {(const float*)d_in[9],  (const float*)d_in[17]};
    const float* A_log[2]  = {(const float*)d_in[10], (const float*)d_in[18]};
    const float* Dvec[2]   = {(const float*)d_in[11], (const float*)d_in[19]};
    const float* dt_b[2]   = {(const float*)d_in[12], (const float*)d_in[20]};
    const float* out_w[2]  = {(const float*)d_in[13], (const float*)d_in[21]};
    const float* aux_w = (const float*)d_in[22];
    const float* aux_b = (const float*)d_in[23];
    const float* k1_lbw = (const float*)d_in[24];
    const float* k1_bw  = (const float*)d_in[25];
    const float* k1_bb  = (const float*)d_in[26];
    const float* k1_sw  = (const float*)d_in[27];
    const float* k2_lbw = (const float*)d_in[28];
    const float* k2_bw  = (const float*)d_in[29];
    const float* k2_bb  = (const float*)d_in[30];
    const float* k2_sw  = (const float*)d_in[31];
    const float* sh_w = (const float*)d_in[32];
    const float* sh_b = (const float*)d_in[33];
    const float* hw   = (const float*)d_in[34];
    const float* hbias= (const float*)d_in[35];
    float* ws = (float*)d_ws;
    float* out = (float*)d_out;

    // workspace (float units)
    const size_t o_ApreB   = 0;
    const size_t o_wpreTB  = 1310720;
    const size_t o_x1B     = 1474560;
    const size_t o_wpatchTB= 5668864;
    const size_t o_uB   = 0;              // bf16 2x1024x1024
    const size_t o_zxB  = 1048576;        // bf16 2x1024x4160 -> ends 5,308,416
    const size_t o_ysB  = 5308416;        // bf16 2x1024x2048 -> ends 7,405,568
    const size_t o_hf   = 9863168;        // f32 1024x1024
    const size_t o_hb   = 10911744;       // f32 1024x1024 (contiguous)
    const size_t o_wBBa = 11960320;       // bf16 4x2x4224x1024 -> ends 29,261,824
    const size_t o_wOBa = 29261824;       // bf16 4x2x2048x1024 -> ends 37,650,432
    const size_t o_spart= 37650432;       // f32 8x1024x1024 -> ends 46,039,040
    const size_t total_f = 46039040;      // ~184 MB
    const size_t o_f1   = 0;
    const size_t o_bas1 = 24576;
    const size_t o_k1   = 221184;
    const size_t o_bas2 = 237568;
    const size_t o_k2   = 368640;
    const size_t o_f4   = 376832;
    const size_t o_part = 385024;
    if (ws_size < total_f * sizeof(float)) return;

    __hip_bfloat16* ApreB   = (__hip_bfloat16*)(ws + o_ApreB);
    __hip_bfloat16* wpreTB  = (__hip_bfloat16*)(ws + o_wpreTB);
    __hip_bfloat16* x1B     = (__hip_bfloat16*)(ws + o_x1B);
    __hip_bfloat16* wpatchTB= (__hip_bfloat16*)(ws + o_wpatchTB);
    __hip_bfloat16* uB      = (__hip_bfloat16*)(ws + o_uB);
    __hip_bfloat16* zxB     = (__hip_bfloat16*)(ws + o_zxB);
    __hip_bfloat16* ysB     = (__hip_bfloat16*)(ws + o_ysB);
    __hip_bfloat16* wBBa    = (__hip_bfloat16*)(ws + o_wBBa);
    __hip_bfloat16* wOBa    = (__hip_bfloat16*)(ws + o_wOBa);
    float* hf = ws + o_hf;
    float* hb = ws + o_hb;

    // merged: all-layer weight conversion + pre/patch prep (one dispatch)
    k_cvt_prep<<<(CVT_TOT + PREP_TOT + 255) / 256, 256, 0, stream>>>(
        in_w[0], in_w[1], out_w[0], out_w[1], wBBa, wOBa,
        pre_w, patch_w, x_prefix, wpreTB, wpatchTB, ApreB);
    // pre-conv GEMM (silu) -> x1B
    k_gemm_mfma<128,128><<<dim3(8, 64, 1), 512, 0, stream>>>(
        (const ushort*)ApreB, (const ushort*)wpreTB, pre_b, nullptr, x1B,
        320, 320, 1024, 1024, 1, 1, 0, 0, 0);
    // patch GEMM split-K=8 -> partials -> finalize + first rmsnorm
    k_gemm_mfma<128,128><<<dim3(8, 8, 8), 512, 0, stream>>>(
        (const ushort*)x1B, (const ushort*)wpatchTB, nullptr, ws + o_spart, nullptr,
        1024, 8192, 1024, 1024, 2, 8, 0, 0, (long)1024 * 1024);
    k_patch_fin_rms<<<1024, 256, 0, stream>>>(ws + o_spart, patch_b, norm_w[0], norm_w[1], hf, hb, uB);

    // Mamba stacks (both dirs batched)
    for (int i = 0; i < NL_; ++i) {
        k_gemm_mfma<128,128><<<dim3(33, 8, 2), 512, 0, stream>>>(
            (const ushort*)uB, (const ushort*)(wBBa + (size_t)i * 2 * NPAD_ * 1024), nullptr, nullptr, zxB,
            1024, 1024, DIN_, DIN_, 0, 1, (long)1024 * 1024, (long)NPAD_ * 1024, (long)1024 * DIN_);
        k_scan<<<512, 256, 0, stream>>>(zxB,
            conv_w[0] + (size_t)i * CONVD_ * 4, conv_w[1] + (size_t)i * CONVD_ * 4,
            conv_b[0] + (size_t)i * CONVD_, conv_b[1] + (size_t)i * CONVD_,
            dt_b[0] + i * NH_, dt_b[1] + i * NH_, A_log[0] + i * NH_, A_log[1] + i * NH_,
            Dvec[0] + i * NH_, Dvec[1] + i * NH_, ysB);
        k_gemm_mfma<128,128><<<dim3(8, 8, 8), 512, 0, stream>>>(
            (const ushort*)ysB, (const ushort*)(wOBa + (size_t)i * 2 * 2048 * 1024), nullptr, ws + o_spart, nullptr,
            512, 2048, 1024, 1024, 2, 4, (long)1024 * 2048, (long)2048 * 1024, (long)1024 * 1024);
        if (i + 1 < NL_) {
            k_oproj_fin_rms<true><<<2048, 256, 0, stream>>>(ws + o_spart,
                norm_w[0] + (size_t)(i + 1) * DM_, norm_w[1] + (size_t)(i + 1) * DM_, hf, uB);
        } else {
            k_oproj_fin_rms<false><<<2048, 256, 0, stream>>>(ws + o_spart, nullptr, nullptr, hf, nullptr);
        }
    }

    // Tail
    k_meanctx_aux<<<68, 256, 0, stream>>>(hf, hb, y_aux, aux_w, aux_b, ws + o_f1);
    k_basis<<<96, 256, 0, stream>>>(ws + o_f1, k1_lbw, ws + o_bas1, 3072);
    k_dotk<0><<<dim3(64, 27), 256, 0, stream>>>(k1_sw, ws + o_bas1, 24576, k1_bw, ws + o_f1, 3072,
                                                nullptr, ws + o_part, 24, 27, 2048);
    k_fin1_basis2<<<8, 256, 0, stream>>>(ws + o_part, k1_bb, k2_lbw, ws + o_k1, ws + o_bas2);
    k_dotk<0><<<dim3(32, 18), 256, 0, stream>>>(k2_sw, ws + o_bas2, 16384, k2_bw, ws + o_k1, 2048,
                                                nullptr, ws + o_part, 16, 18, 1024);
    k_dot_fin<18><<<4, 256, 0, stream>>>(ws + o_part, k2_bb, ws + o_k2, 1024);
    k_dotk<1><<<dim3(32, 1), 256, 0, stream>>>(nullptr, nullptr, 0, sh_w, ws + o_k2, 1024,
                                               sh_b, ws + o_f4, 0, 1, 1024);
    k_dotk<2><<<dim3(1024, 1), 256, 0, stream>>>(nullptr, nullptr, 0, hw, ws + o_f4, 1024,
                                                 hbias, out, 0, 1, 32768);
}

// Round 9
// 856.041 us; speedup vs baseline: 1.7163x; 1.0004x over previous
//
#include <hip/hip_runtime.h>
#include <hip/hip_bf16.h>
#include <math.h>

#define B_    8
#define LP_   1024
#define CIN_  64
#define DM_   1024
#define DI_   2048
#define NS_   16
#define PH_   64
#define NH_   32
#define NL_   4
#define GG_   8
#define KH_   2048
#define DIN_  4160
#define NPAD_ 4224
#define CONVD_ 2080
#define L_    128
#define R_    1024
#define OUTL_ 512
#define COUT_ 64

typedef __bf16 bf16x8 __attribute__((ext_vector_type(8)));
typedef float f32x4 __attribute__((ext_vector_type(4)));
typedef unsigned short ushort;

__device__ __forceinline__ float silu_f(float x) { return x / (1.0f + expf(-x)); }

__device__ __forceinline__ ushort f2bu(float x) {
    union { __hip_bfloat16 h; ushort u; } c; c.h = __float2bfloat16(x); return c.u;
}
__device__ __forceinline__ float bu2f(ushort u) {
    union { ushort u; __hip_bfloat16 h; } c; c.u = u; return __bfloat162float(c.h);
}

__device__ __forceinline__ void gload_lds16(const void* g, void* l) {
    __builtin_amdgcn_global_load_lds((const __attribute__((address_space(1))) unsigned int*)g,
                                     (__attribute__((address_space(3))) unsigned int*)l, 16, 0, 0);
}

// pair-merge reduce: 8 accumulators x 64 lanes -> lane (l&7) holds full sum of acc[l&7]
__device__ __forceinline__ float merge2(float a, float b, int mask, int lane) {
    float x = (lane & mask) ? b : a;
    float y = (lane & mask) ? a : b;
    return x + __shfl_xor(y, mask);
}
__device__ __forceinline__ float reduce8(float* a, int lane) {
    float c0 = merge2(a[0], a[1], 1, lane);
    float c1 = merge2(a[2], a[3], 1, lane);
    float c2 = merge2(a[4], a[5], 1, lane);
    float c3 = merge2(a[6], a[7], 1, lane);
    float d0 = merge2(c0, c1, 2, lane);
    float d1 = merge2(c2, c3, 2, lane);
    float e  = merge2(d0, d1, 4, lane);
    e += __shfl_xor(e, 8);
    e += __shfl_xor(e, 16);
    e += __shfl_xor(e, 32);
    return e;
}

// ---------------- merged conversion + prep (one dispatch) ----------------
#define CVT_IN_T4  1081344   // NPAD_*1024/4
#define CVT_OUT_T4 524288    // 1024*2048/4
#define CVT_PER    1605632
#define CVT_TOT    12845056  // 8*CVT_PER
#define PREP_W1 327680       // DM_*320
#define PREP_W2 8388608      // DM_*8192
#define PREP_W3 2621440      // 8192*320
#define PREP_TOT 11337728
__global__ __launch_bounds__(256) void k_cvt_prep(
    const float* __restrict__ in0, const float* __restrict__ in1,
    const float* __restrict__ o0, const float* __restrict__ o1,
    __hip_bfloat16* __restrict__ wBBa, __hip_bfloat16* __restrict__ wOBa,
    const float* __restrict__ pre_w, const float* __restrict__ patch_w, const float* __restrict__ xp,
    __hip_bfloat16* __restrict__ wpreT, __hip_bfloat16* __restrict__ wpatchT, __hip_bfloat16* __restrict__ Apre)
{
    int gi = blockIdx.x * 256 + threadIdx.x;
    if (gi < CVT_TOT) {
        int ld = gi / CVT_PER;
        int r = gi - ld * CVT_PER;
        int l = ld >> 1, d = ld & 1;
        const float* inw  = (d ? in1 : in0) + (size_t)l * DIN_ * DM_;
        const float* outw = (d ? o1 : o0) + (size_t)l * DM_ * DI_;
        if (r < CVT_IN_T4) {
            int idx = r * 4; int row = idx >> 10;
            __hip_bfloat16* dst = wBBa + (size_t)ld * NPAD_ * 1024 + idx;
            if (row < DIN_) {
                float4 v = *(const float4*)(inw + idx);
                dst[0] = __float2bfloat16(v.x); dst[1] = __float2bfloat16(v.y);
                dst[2] = __float2bfloat16(v.z); dst[3] = __float2bfloat16(v.w);
            } else {
                dst[0] = __float2bfloat16(0.f); dst[1] = __float2bfloat16(0.f);
                dst[2] = __float2bfloat16(0.f); dst[3] = __float2bfloat16(0.f);
            }
        } else {
            int idx = (r - CVT_IN_T4) * 4;
            __hip_bfloat16* dst = wOBa + (size_t)ld * 2048 * 1024 + idx;
            float4 v = *(const float4*)(outw + idx);
            dst[0] = __float2bfloat16(v.x); dst[1] = __float2bfloat16(v.y);
            dst[2] = __float2bfloat16(v.z); dst[3] = __float2bfloat16(v.w);
        }
        return;
    }
    int idx = gi - CVT_TOT;
    if (idx < PREP_W1) {
        int d = idx / 320, kk = idx % 320;
        int kp = kk >> 6, c = kk & 63;
        wpreT[idx] = __float2bfloat16(pre_w[(d * CIN_ + c) * 5 + kp]);
    } else if (idx < PREP_W1 + PREP_W2) {
        int i = idx - PREP_W1;
        int d = i >> 13, kk = i & 8191;
        int kp = kk >> 10, din = kk & 1023;
        wpatchT[i] = __float2bfloat16(patch_w[((size_t)d << 13) + din * 8 + kp]);
    } else if (idx < PREP_TOT) {
        int i = idx - PREP_W1 - PREP_W2;
        int kk = i % 320; int r = i / 320;
        int l = r & 1023, b = r >> 10;
        int kp = kk >> 6, c = kk & 63;
        int lp = l + kp - 2;
        float v = 0.f;
        if (lp >= 0 && lp < LP_) v = xp[((size_t)b * LP_ + lp) * CIN_ + c];
        Apre[i] = __float2bfloat16(v);
    }
}

// ---------------- bf16 MFMA GEMM, 128^2 tile, 8 waves, 2-phase dbuf, T2 granule swizzle ----------------
// LDS tile rows are 64B (BK=32 bf16). Granule swizzle g' = g ^ ((row>>1)&3) (involution; key bits 7-8,
// flipped bits 4-5) applied on BOTH the staging SOURCE (LDS dest stays linear, per rule #21) and the
// fragment-read address: rows 0..15 of a quarter-phase spread over all 8 bank-quads -> 2-way (free)
// instead of 8-way (2.94x).
template<int BM, int BN>
__global__ __launch_bounds__(512) void k_gemm_mfma(
    const ushort* __restrict__ A, const ushort* __restrict__ B,
    const float* __restrict__ bias,
    float* __restrict__ Cf, __hip_bfloat16* __restrict__ Cb,
    int Kc, int ldk, int ldc, int Nstore, int act, int nsplit,
    long sA, long sB, long sC)
{
    constexpr int BK = 32;
    constexpr int WM = 64, WN = 32;           // 2x4 waves cover 128x128
    constexpr int MR = WM / 16, NR = WN / 16; // 4 x 2
    constexpr int ACH = BM * 4, BCH = BN * 4;
    __shared__ ushort sAs[2][BM * BK];
    __shared__ ushort sBs[2][BN * BK];
    int tid = threadIdx.x;
    int lane = tid & 63, w = tid >> 6;        // 8 waves
    int wr = w >> 2, wc = w & 3;
    int z = blockIdx.z;
    int dir = z / nsplit, ks = z - dir * nsplit;
    int kbase = ks * Kc;
    int m0 = blockIdx.y * BM, n0 = blockIdx.x * BN;
    const ushort* Az = A + (size_t)dir * sA + kbase;
    const ushort* Bz = B + (size_t)dir * sB + kbase;

    auto STAGE = [&](int buf, int k0) {
        #pragma unroll
        for (int c = tid; c < ACH; c += 512) {
            int row = c >> 2, gp = c & 3;
            int g = gp ^ ((row >> 1) & 3);            // pre-swizzled source granule
            gload_lds16(Az + (size_t)(m0 + row) * ldk + k0 + g * 8, (char*)&sAs[buf][0] + c * 16);
        }
        #pragma unroll
        for (int c = tid; c < BCH; c += 512) {
            int row = c >> 2, gp = c & 3;
            int g = gp ^ ((row >> 1) & 3);
            gload_lds16(Bz + (size_t)(n0 + row) * ldk + k0 + g * 8, (char*)&sBs[buf][0] + c * 16);
        }
    };

    // swizzled fragment granule (elements): rows base are multiples of 16, so (row>>1)&3 = ((lane&15)>>1)&3
    const int gsw = (((lane >> 4) ^ ((lane >> 1) & 3)) * 8);

    f32x4 acc[MR][NR] = {};
    const int NT = Kc / BK;
    STAGE(0, 0);
    __syncthreads();
    int cur = 0;
    for (int t = 0; t < NT; ++t) {
        if (t + 1 < NT) STAGE(cur ^ 1, (t + 1) * BK);   // in flight during compute
        bf16x8 af[MR], bfr[NR];
        #pragma unroll
        for (int m = 0; m < MR; ++m)
            af[m] = *(const bf16x8*)&sAs[cur][(wr * WM + m * 16 + (lane & 15)) * BK + gsw];
        #pragma unroll
        for (int n = 0; n < NR; ++n)
            bfr[n] = *(const bf16x8*)&sBs[cur][(wc * WN + n * 16 + (lane & 15)) * BK + gsw];
        #pragma unroll
        for (int m = 0; m < MR; ++m)
            #pragma unroll
            for (int n = 0; n < NR; ++n)
                acc[m][n] = __builtin_amdgcn_mfma_f32_16x16x32_bf16(af[m], bfr[n], acc[m][n], 0, 0, 0);
        __syncthreads();    // implicit vmcnt(0): next tile landed, cur fully consumed
        cur ^= 1;
    }
    #pragma unroll
    for (int m = 0; m < MR; ++m) {
        int row = m0 + wr * WM + m * 16 + (lane >> 4) * 4;
        #pragma unroll
        for (int n = 0; n < NR; ++n) {
            int col = n0 + wc * WN + n * 16 + (lane & 15);
            if (col < Nstore) {
                if (act == 2) {
                    float* Cfz = Cf + (size_t)z * sC;
                    #pragma unroll
                    for (int j = 0; j < 4; ++j)
                        Cfz[(size_t)(row + j) * ldc + col] = acc[m][n][j];
                } else {
                    __hip_bfloat16* Cbz = Cb + (size_t)dir * sC;
                    float bv = bias ? bias[col] : 0.f;
                    #pragma unroll
                    for (int j = 0; j < 4; ++j) {
                        float v = acc[m][n][j] + bv;
                        if (act == 1) v = silu_f(v);
                        Cbz[(size_t)(row + j) * ldc + col] = __float2bfloat16(v);
                    }
                }
            }
        }
    }
}

// ---------------- patch finalize + first rmsnorm: one block per hf row ----------------
__global__ __launch_bounds__(256) void k_patch_fin_rms(const float* __restrict__ part, const float* __restrict__ bias,
                                                       const float* __restrict__ w0, const float* __restrict__ w1,
                                                       float* __restrict__ hf, float* __restrict__ hb,
                                                       __hip_bfloat16* __restrict__ uB) {
    int r = blockIdx.x;          // 0..1023
    int t = threadIdx.x;
    int c = t * 4;
    float4 o = *(const float4*)(bias + c);
    #pragma unroll
    for (int s = 0; s < 8; ++s) {
        float4 v = *(const float4*)(part + (size_t)s * 1048576 + ((size_t)r << 10) + c);
        o.x += v.x; o.y += v.y; o.z += v.z; o.w += v.w;
    }
    *(float4*)(hf + ((size_t)r << 10) + c) = o;
    int rb = r ^ 127;
    *(float4*)(hb + ((size_t)rb << 10) + c) = o;
    float ss = o.x * o.x + o.y * o.y + o.z * o.z + o.w * o.w;
    #pragma unroll
    for (int of = 32; of; of >>= 1) ss += __shfl_xor(ss, of);
    __shared__ float sred[4];
    if ((t & 63) == 0) sred[t >> 6] = ss;
    __syncthreads();
    float tot = sred[0] + sred[1] + sred[2] + sred[3];
    float scale = rsqrtf(tot * (1.0f / DM_) + 1e-5f);
    float4 wf = *(const float4*)(w0 + c);
    float4 wb = *(const float4*)(w1 + c);
    __hip_bfloat16* uf = uB + ((size_t)r << 10) + c;
    __hip_bfloat16* ub = uB + ((size_t)(1024 + rb) << 10) + c;
    uf[0] = __float2bfloat16(o.x * scale * wf.x); uf[1] = __float2bfloat16(o.y * scale * wf.y);
    uf[2] = __float2bfloat16(o.z * scale * wf.z); uf[3] = __float2bfloat16(o.w * scale * wf.w);
    ub[0] = __float2bfloat16(o.x * scale * wb.x); ub[1] = __float2bfloat16(o.y * scale * wb.y);
    ub[2] = __float2bfloat16(o.z * scale * wb.z); ub[3] = __float2bfloat16(o.w * scale * wb.w);
}

// ---------------- out-proj finalize (+residual) + next rmsnorm: one block per h row (2048) ----------------
template<bool DO_RMS>
__global__ __launch_bounds__(256) void k_oproj_fin_rms(const float* __restrict__ part,
                                                       const float* __restrict__ w0, const float* __restrict__ w1,
                                                       float* __restrict__ h, __hip_bfloat16* __restrict__ uB) {
    int row = blockIdx.x;        // 0..2047 (dir = row>>10)
    int t = threadIdx.x;
    int c = t * 4;
    const float* p = part + (size_t)(row >> 10) * 4194304 + (size_t)(row & 1023) * 1024 + c;
    float4 o = *(const float4*)(h + ((size_t)row << 10) + c);
    #pragma unroll
    for (int s = 0; s < 4; ++s) {
        float4 v = *(const float4*)(p + (size_t)s * 1048576);
        o.x += v.x; o.y += v.y; o.z += v.z; o.w += v.w;
    }
    *(float4*)(h + ((size_t)row << 10) + c) = o;
    if (DO_RMS) {
        float ss = o.x * o.x + o.y * o.y + o.z * o.z + o.w * o.w;
        #pragma unroll
        for (int of = 32; of; of >>= 1) ss += __shfl_xor(ss, of);
        __shared__ float sred[4];
        if ((t & 63) == 0) sred[t >> 6] = ss;
        __syncthreads();
        float tot = sred[0] + sred[1] + sred[2] + sred[3];
        float scale = rsqrtf(tot * (1.0f / DM_) + 1e-5f);
        const float* w = (row >> 10) ? w1 : w0;
        float4 wv = *(const float4*)(w + c);
        __hip_bfloat16* u = uB + ((size_t)row << 10) + c;
        u[0] = __float2bfloat16(o.x * scale * wv.x); u[1] = __float2bfloat16(o.y * scale * wv.y);
        u[2] = __float2bfloat16(o.z * scale * wv.z); u[3] = __float2bfloat16(o.w * scale * wv.w);
    }
}

// ---------------- SSM scan with fused depthwise conv: one block per (dir,b,h) ----------------
__global__ __launch_bounds__(256) void k_scan(const __hip_bfloat16* __restrict__ zx,
                                              const float* __restrict__ cw0, const float* __restrict__ cw1,
                                              const float* __restrict__ cb0, const float* __restrict__ cb1,
                                              const float* __restrict__ dtb0, const float* __restrict__ dtb1,
                                              const float* __restrict__ al0, const float* __restrict__ al1,
                                              const float* __restrict__ D0, const float* __restrict__ D1,
                                              __hip_bfloat16* __restrict__ ys) {
    __shared__ float xs[L_ * PH_];
    __shared__ float Bsh[L_ * NS_];
    __shared__ float Csh[L_ * NS_];
    __shared__ float dts[L_];
    __shared__ float dAs[L_];
    int bx = blockIdx.x;
    int dir = bx >> 8, b = (bx >> 5) & 7, h = bx & 31;
    const __hip_bfloat16* zxd = zx + (size_t)dir * 1024 * DIN_;
    const float* cw = dir ? cw1 : cw0;
    const float* cb = dir ? cb1 : cb0;
    const float* dt_bias = dir ? dtb1 : dtb0;
    const float* A_log   = dir ? al1 : al0;
    const float* Dh      = dir ? D1 : D0;
    __hip_bfloat16* ysd  = ys + (size_t)dir * 1024 * DI_;
    int t = threadIdx.x;
    for (int i = t; i < 2048; i += 256) {
        int l = i >> 4, p4 = i & 15;
        int cc = h * PH_ + p4 * 4;
        float a0 = cb[cc + 0], a1 = cb[cc + 1], a2 = cb[cc + 2], a3 = cb[cc + 3];
        #pragma unroll
        for (int k = 0; k < 4; ++k) {
            int lp = l - 3 + k;
            if (lp >= 0) {
                ushort4 raw = *(const ushort4*)(zxd + (size_t)(b * L_ + lp) * DIN_ + DI_ + cc);
                a0 += bu2f(raw.x) * cw[(cc + 0) * 4 + k];
                a1 += bu2f(raw.y) * cw[(cc + 1) * 4 + k];
                a2 += bu2f(raw.z) * cw[(cc + 2) * 4 + k];
                a3 += bu2f(raw.w) * cw[(cc + 3) * 4 + k];
            }
        }
        float* xp = &xs[l * PH_ + p4 * 4];
        xp[0] = silu_f(a0); xp[1] = silu_f(a1); xp[2] = silu_f(a2); xp[3] = silu_f(a3);
    }
    for (int i = t; i < 1024; i += 256) {
        int l = i >> 3, q4 = i & 7;
        int cc = DI_ + q4 * 4;
        float a0 = cb[cc + 0], a1 = cb[cc + 1], a2 = cb[cc + 2], a3 = cb[cc + 3];
        #pragma unroll
        for (int k = 0; k < 4; ++k) {
            int lp = l - 3 + k;
            if (lp >= 0) {
                ushort4 raw = *(const ushort4*)(zxd + (size_t)(b * L_ + lp) * DIN_ + DI_ + cc);
                a0 += bu2f(raw.x) * cw[(cc + 0) * 4 + k];
                a1 += bu2f(raw.y) * cw[(cc + 1) * 4 + k];
                a2 += bu2f(raw.z) * cw[(cc + 2) * 4 + k];
                a3 += bu2f(raw.w) * cw[(cc + 3) * 4 + k];
            }
        }
        float r0 = silu_f(a0), r1 = silu_f(a1), r2 = silu_f(a2), r3 = silu_f(a3);
        if (q4 < 4) {
            float* bp = &Bsh[l * NS_ + q4 * 4];
            bp[0] = r0; bp[1] = r1; bp[2] = r2; bp[3] = r3;
        } else {
            float* cp = &Csh[l * NS_ + (q4 - 4) * 4];
            cp[0] = r0; cp[1] = r1; cp[2] = r2; cp[3] = r3;
        }
    }
    if (t < L_) {
        float v = bu2f(*(const ushort*)(zxd + (size_t)(b * L_ + t) * DIN_ + 4128 + h)) + dt_bias[h];
        float sp = v > 20.f ? v : log1pf(expf(v));
        dts[t] = sp;
        dAs[t] = expf(-expf(A_log[h]) * sp);
    }
    __syncthreads();
    int p = t >> 2, n0 = (t & 3) * 4;
    float Dv = Dh[h];
    float s0 = 0.f, s1 = 0.f, s2 = 0.f, s3 = 0.f;
    for (int l = 0; l < L_; ++l) {
        float x = xs[l * 64 + p];
        float dAv = dAs[l];
        float xdt = x * dts[l];
        s0 = s0 * dAv + xdt * Bsh[l * 16 + n0 + 0];
        s1 = s1 * dAv + xdt * Bsh[l * 16 + n0 + 1];
        s2 = s2 * dAv + xdt * Bsh[l * 16 + n0 + 2];
        s3 = s3 * dAv + xdt * Bsh[l * 16 + n0 + 3];
        float cp = s0 * Csh[l * 16 + n0 + 0] + s1 * Csh[l * 16 + n0 + 1]
                 + s2 * Csh[l * 16 + n0 + 2] + s3 * Csh[l * 16 + n0 + 3];
        cp += __shfl_xor(cp, 1);
        cp += __shfl_xor(cp, 2);
        if ((t & 3) == 0) xs[l * 64 + p] = cp + x * Dv;
    }
    __syncthreads();
    for (int i = t; i < L_ * PH_; i += 256) {
        int l = i >> 6, pp = i & 63;
        float z = bu2f(*(const ushort*)(zxd + (size_t)(b * L_ + l) * DIN_ + h * PH_ + pp));
        ysd[((size_t)(b * L_ + l)) * DI_ + h * PH_ + pp] = __float2bfloat16(xs[i] * silu_f(z));
    }
}

// ---------------- tail ----------------
__global__ __launch_bounds__(256) void k_meanctx_aux(const float* __restrict__ hf, const float* __restrict__ hb,
                                                     const float* __restrict__ y_aux, const float* __restrict__ aux_w,
                                                     const float* __restrict__ aux_b, float* __restrict__ fused) {
    int bx = blockIdx.x;
    int t = threadIdx.x;
    if (bx < 64) {
        int b = bx >> 3, ch = bx & 7;
        int d4 = t & 31, lg = t >> 5;
        int d = ch * 128 + d4 * 4;
        float4 sf = {0,0,0,0}, sb = {0,0,0,0};
        for (int l = lg; l < L_; l += 8) {
            float4 a = *(const float4*)(hf + ((size_t)b * L_ + l) * DM_ + d);
            float4 c = *(const float4*)(hb + ((size_t)b * L_ + l) * DM_ + d);
            sf.x += a.x; sf.y += a.y; sf.z += a.z; sf.w += a.w;
            sb.x += c.x; sb.y += c.y; sb.z += c.z; sb.w += c.w;
        }
        __shared__ float rf[8][128], rb[8][128];
        *(float4*)&rf[lg][d4 * 4] = sf;
        *(float4*)&rb[lg][d4 * 4] = sb;
        __syncthreads();
        if (t < 128) {
            float s1 = 0.f, s2 = 0.f;
            #pragma unroll
            for (int g = 0; g < 8; ++g) { s1 += rf[g][t]; s2 += rb[g][t]; }
            fused[b * 3072 + ch * 128 + t] = s1 * (1.f / L_);
            fused[b * 3072 + DM_ + ch * 128 + t] = s2 * (1.f / L_);
        }
    } else {
        int j = (bx - 64) * 256 + t;
        if (j >= DM_) return;
        for (int b = 0; b < B_; ++b) {
            float acc = aux_b[j];
            for (int a = 0; a < 32; ++a) acc += y_aux[b * 32 + a] * aux_w[j * 32 + a];
            fused[b * 3072 + 2 * DM_ + j] = silu_f(acc);
        }
    }
}

__global__ __launch_bounds__(256) void k_basis(const float* __restrict__ x, const float* __restrict__ log_bw,
                                               float* __restrict__ basis, int Din) {
    int idx = blockIdx.x * 256 + threadIdx.x;
    if (idx >= 8 * Din) return;
    int d = idx % Din;
    float xv = x[idx];
    float bw = expf(log_bw[d]) + 1e-6f;
    float inv = 1.0f / (2.0f * bw * bw);
    #pragma unroll
    for (int g = 0; g < GG_; ++g) {
        float gg = -2.0f + g * (4.0f / 7.0f);
        float df = xv - gg;
        basis[(size_t)idx * GG_ + g] = expf(-df * df * inv);
    }
}

// ---------------- LDS-staged batched dot; y-chunks cover spline (ch<nsp) and base (ch>=nsp) ----------------
template<int MODE>
__global__ __launch_bounds__(256) void k_dotk(const float* __restrict__ Wsp, const float* __restrict__ Xsp, int Ksp,
                                              const float* __restrict__ Wb, const float* __restrict__ Xb, int Kb,
                                              const float* __restrict__ bias, float* __restrict__ out,
                                              int nsp, int nch, int Dout) {
    __shared__ float sX[8][1024];
    int ch = blockIdx.y;
    bool sp = (ch < nsp);
    const float* W = sp ? Wsp : Wb;
    const float* X = sp ? Xsp : Xb;
    int K = sp ? Ksp : Kb;
    int k0 = (sp ? ch : ch - nsp) * 1024;
    int tid = threadIdx.x;
    for (int i = tid; i < 2048; i += 256) {
        int b = i >> 8, kk = (i & 255) * 4;
        *(float4*)&sX[b][kk] = *(const float4*)(X + (size_t)b * K + k0 + kk);
    }
    __syncthreads();
    int wv = tid >> 6, lane = tid & 63;
    int rowBase = blockIdx.x * 32 + wv * 8;
    for (int j = 0; j < 8; ++j) {
        int row = rowBase + j;
        const float* wr = W + (size_t)row * K + k0;
        float acc[8] = {};
        #pragma unroll
        for (int it = 0; it < 4; ++it) {
            int k = it * 256 + lane * 4;
            float4 wvv = *(const float4*)(wr + k);
            #pragma unroll
            for (int b = 0; b < 8; ++b) {
                float4 xv = *(const float4*)&sX[b][k];
                acc[b] += wvv.x * xv.x + wvv.y * xv.y + wvv.z * xv.z + wvv.w * xv.w;
            }
        }
        float e = reduce8(acc, lane);
        if (lane < 8) {
            if (MODE == 0) {
                out[((size_t)row * nch + ch) * 8 + lane] = e;
            } else if (MODE == 1) {
                out[(size_t)lane * Dout + row] = silu_f(e + bias[row]);
            } else {
                int c = row >> 9, l = row & 511;
                out[((size_t)lane * OUTL_ + l) * COUT_ + c] = e + bias[row];
            }
        }
    }
}

// ---------------- KAN1 finalize + basis2 fused ----------------
__global__ __launch_bounds__(256) void k_fin1_basis2(const float* __restrict__ partial, const float* __restrict__ bb,
                                                     const float* __restrict__ k2_lbw,
                                                     float* __restrict__ k1, float* __restrict__ bas2) {
    int row = blockIdx.x * 256 + threadIdx.x;   // 0..2047
    if (row >= 2048) return;
    float bbv = bb[row];
    float lb = expf(k2_lbw[row]) + 1e-6f;
    float inv = 1.0f / (2.0f * lb * lb);
    #pragma unroll
    for (int b = 0; b < 8; ++b) {
        float s = bbv;
        #pragma unroll
        for (int c = 0; c < 27; ++c) s += partial[((size_t)row * 27 + c) * 8 + b];
        float v = silu_f(s);
        k1[(size_t)b * 2048 + row] = v;
        #pragma unroll
        for (int g = 0; g < GG_; ++g) {
            float gg = -2.0f + g * (4.0f / 7.0f);
            float df = v - gg;
            bas2[((size_t)b * 2048 + row) * GG_ + g] = expf(-df * df * inv);
        }
    }
}

template<int NCH>
__global__ __launch_bounds__(256) void k_dot_fin(const float* __restrict__ partial, const float* __restrict__ base_b,
                                                 float* __restrict__ out, int Dout) {
    int row = blockIdx.x * 256 + threadIdx.x;
    if (row >= Dout) return;
    float bb = base_b[row];
    #pragma unroll
    for (int b = 0; b < 8; ++b) {
        float s = bb;
        #pragma unroll
        for (int c = 0; c < NCH; ++c) s += partial[((size_t)row * NCH + c) * 8 + b];
        out[(size_t)b * Dout + row] = silu_f(s);
    }
}

// ---------------- launch ----------------
extern "C" void kernel_launch(void* const* d_in, const int* in_sizes, int n_in,
                              void* d_out, int out_size, void* d_ws, size_t ws_size,
                              hipStream_t stream) {
    const float* x_prefix = (const float*)d_in[0];
    const float* y_aux    = (const float*)d_in[1];
    const float* pre_w    = (const float*)d_in[2];
    const float* pre_b    = (const float*)d_in[3];
    const float* patch_w  = (const float*)d_in[4];
    const float* patch_b  = (const float*)d_in[5];
    const float* norm_w[2] = {(const float*)d_in[6],  (const float*)d_in[14]};
    const float* in_w[2]   = {(const float*)d_in[7],  (const float*)d_in[15]};
    const float* conv_w[2] = {(const float*)d_in[8],  (const float*)d_in[16]};
    const float* conv_b[2] = {(const float*)d_in[9],  (const float*)d_in[17]};
    const float* A_log[2]  = {(const float*)d_in[10], (const float*)d_in[18]};
    const float* Dvec[2]   = {(const float*)d_in[11], (const float*)d_in[19]};
    const float* dt_b[2]   = {(const float*)d_in[12], (const float*)d_in[20]};
    const float* out_w[2]  = {(const float*)d_in[13], (const float*)d_in[21]};
    const float* aux_w = (const float*)d_in[22];
    const float* aux_b = (const float*)d_in[23];
    const float* k1_lbw = (const float*)d_in[24];
    const float* k1_bw  = (const float*)d_in[25];
    const float* k1_bb  = (const float*)d_in[26];
    const float* k1_sw  = (const float*)d_in[27];
    const float* k2_lbw = (const float*)d_in[28];
    const float* k2_bw  = (const float*)d_in[29];
    const float* k2_bb  = (const float*)d_in[30];
    const float* k2_sw  = (const float*)d_in[31];
    const float* sh_w = (const float*)d_in[32];
    const float* sh_b = (const float*)d_in[33];
    const float* hw   = (const float*)d_in[34];
    const float* hbias= (const float*)d_in[35];
    float* ws = (float*)d_ws;
    float* out = (float*)d_out;

    // workspace (float units)
    const size_t o_ApreB   = 0;
    const size_t o_wpreTB  = 1310720;
    const size_t o_x1B     = 1474560;
    const size_t o_wpatchTB= 5668864;
    const size_t o_uB   = 0;              // bf16 2x1024x1024
    const size_t o_zxB  = 1048576;        // bf16 2x1024x4160 -> ends 5,308,416
    const size_t o_ysB  = 5308416;        // bf16 2x1024x2048 -> ends 7,405,568
    const size_t o_hf   = 9863168;        // f32 1024x1024
    const size_t o_hb   = 10911744;       // f32 1024x1024 (contiguous)
    const size_t o_wBBa = 11960320;       // bf16 4x2x4224x1024 -> ends 29,261,824
    const size_t o_wOBa = 29261824;       // bf16 4x2x2048x1024 -> ends 37,650,432
    const size_t o_spart= 37650432;       // f32 8x1024x1024 -> ends 46,039,040
    const size_t total_f = 46039040;      // ~184 MB
    const size_t o_f1   = 0;
    const size_t o_bas1 = 24576;
    const size_t o_k1   = 221184;
    const size_t o_bas2 = 237568;
    const size_t o_k2   = 368640;
    const size_t o_f4   = 376832;
    const size_t o_part = 385024;
    if (ws_size < total_f * sizeof(float)) return;

    __hip_bfloat16* ApreB   = (__hip_bfloat16*)(ws + o_ApreB);
    __hip_bfloat16* wpreTB  = (__hip_bfloat16*)(ws + o_wpreTB);
    __hip_bfloat16* x1B     = (__hip_bfloat16*)(ws + o_x1B);
    __hip_bfloat16* wpatchTB= (__hip_bfloat16*)(ws + o_wpatchTB);
    __hip_bfloat16* uB      = (__hip_bfloat16*)(ws + o_uB);
    __hip_bfloat16* zxB     = (__hip_bfloat16*)(ws + o_zxB);
    __hip_bfloat16* ysB     = (__hip_bfloat16*)(ws + o_ysB);
    __hip_bfloat16* wBBa    = (__hip_bfloat16*)(ws + o_wBBa);
    __hip_bfloat16* wOBa    = (__hip_bfloat16*)(ws + o_wOBa);
    float* hf = ws + o_hf;
    float* hb = ws + o_hb;

    // merged: all-layer weight conversion + pre/patch prep (one dispatch)
    k_cvt_prep<<<(CVT_TOT + PREP_TOT + 255) / 256, 256, 0, stream>>>(
        in_w[0], in_w[1], out_w[0], out_w[1], wBBa, wOBa,
        pre_w, patch_w, x_prefix, wpreTB, wpatchTB, ApreB);
    // pre-conv GEMM (silu) -> x1B
    k_gemm_mfma<128,128><<<dim3(8, 64, 1), 512, 0, stream>>>(
        (const ushort*)ApreB, (const ushort*)wpreTB, pre_b, nullptr, x1B,
        320, 320, 1024, 1024, 1, 1, 0, 0, 0);
    // patch GEMM split-K=8 -> partials -> finalize + first rmsnorm
    k_gemm_mfma<128,128><<<dim3(8, 8, 8), 512, 0, stream>>>(
        (const ushort*)x1B, (const ushort*)wpatchTB, nullptr, ws + o_spart, nullptr,
        1024, 8192, 1024, 1024, 2, 8, 0, 0, (long)1024 * 1024);
    k_patch_fin_rms<<<1024, 256, 0, stream>>>(ws + o_spart, patch_b, norm_w[0], norm_w[1], hf, hb, uB);

    // Mamba stacks (both dirs batched)
    for (int i = 0; i < NL_; ++i) {
        k_gemm_mfma<128,128><<<dim3(33, 8, 2), 512, 0, stream>>>(
            (const ushort*)uB, (const ushort*)(wBBa + (size_t)i * 2 * NPAD_ * 1024), nullptr, nullptr, zxB,
            1024, 1024, DIN_, DIN_, 0, 1, (long)1024 * 1024, (long)NPAD_ * 1024, (long)1024 * DIN_);
        k_scan<<<512, 256, 0, stream>>>(zxB,
            conv_w[0] + (size_t)i * CONVD_ * 4, conv_w[1] + (size_t)i * CONVD_ * 4,
            conv_b[0] + (size_t)i * CONVD_, conv_b[1] + (size_t)i * CONVD_,
            dt_b[0] + i * NH_, dt_b[1] + i * NH_, A_log[0] + i * NH_, A_log[1] + i * NH_,
            Dvec[0] + i * NH_, Dvec[1] + i * NH_, ysB);
        k_gemm_mfma<128,128><<<dim3(8, 8, 8), 512, 0, stream>>>(
            (const ushort*)ysB, (const ushort*)(wOBa + (size_t)i * 2 * 2048 * 1024), nullptr, ws + o_spart, nullptr,
            512, 2048, 1024, 1024, 2, 4, (long)1024 * 2048, (long)2048 * 1024, (long)1024 * 1024);
        if (i + 1 < NL_) {
            k_oproj_fin_rms<true><<<2048, 256, 0, stream>>>(ws + o_spart,
                norm_w[0] + (size_t)(i + 1) * DM_, norm_w[1] + (size_t)(i + 1) * DM_, hf, uB);
        } else {
            k_oproj_fin_rms<false><<<2048, 256, 0, stream>>>(ws + o_spart, nullptr, nullptr, hf, nullptr);
        }
    }

    // Tail
    k_meanctx_aux<<<68, 256, 0, stream>>>(hf, hb, y_aux, aux_w, aux_b, ws + o_f1);
    k_basis<<<96, 256, 0, stream>>>(ws + o_f1, k1_lbw, ws + o_bas1, 3072);
    k_dotk<0><<<dim3(64, 27), 256, 0, stream>>>(k1_sw, ws + o_bas1, 24576, k1_bw, ws + o_f1, 3072,
                                                nullptr, ws + o_part, 24, 27, 2048);
    k_fin1_basis2<<<8, 256, 0, stream>>>(ws + o_part, k1_bb, k2_lbw, ws + o_k1, ws + o_bas2);
    k_dotk<0><<<dim3(32, 18), 256, 0, stream>>>(k2_sw, ws + o_bas2, 16384, k2_bw, ws + o_k1, 2048,
                                                nullptr, ws + o_part, 16, 18, 1024);
    k_dot_fin<18><<<4, 256, 0, stream>>>(ws + o_part, k2_bb, ws + o_k2, 1024);
    k_dotk<1><<<dim3(32, 1), 256, 0, stream>>>(nullptr, nullptr, 0, sh_w, ws + o_k2, 1024,
                                               sh_b, ws + o_f4, 0, 1, 1024);
    k_dotk<2><<<dim3(1024, 1), 256, 0, stream>>>(nullptr, nullptr, 0, hw, ws + o_f4, 1024,
                                                 hbias, out, 0, 1, 32768);
}